// Round 10
// baseline (371.624 us; speedup 1.0000x reference)
//
#include <hip/hip_runtime.h>
#include <hip/hip_bf16.h>
#include <math.h>

// DynSMHA: B=4 T=2048 C=1024 H=128 E=16 MIN_E=2, non-causal.
// fused front (weight transposes || fp64 gating w/ in-block sim-norms, emits
// dense bf16 x) -> parallel scan -> ballot-aggregated slot assign ->
// grouped GEMMs (BM=128, indirect A-gather, counted-vmcnt, XOR-swizzled LDS) ->
// flash attention (exp2-domain online softmax, split-s LSE) -> combines.
#define NBATCH 4
#define NT     2048
#define NC     1024
#define NH     128
#define NE     16
#define NTOK   (NBATCH * NT)
#define CAP    18432         // slot capacity (actual ~16384)
#define NT2_MAX 152          // sum ceil(cnt_e/128) + slack; multiple of 8

typedef __bf16 bf16x8 __attribute__((ext_vector_type(8)));
typedef __bf16 bf16x4 __attribute__((ext_vector_type(4)));
typedef float  f32x4  __attribute__((ext_vector_type(4)));

__device__ __forceinline__ __bf16 f2bf(float f) { return (__bf16)f; }

#define BARRIER() __builtin_amdgcn_s_barrier()
#define SFENCE()  __builtin_amdgcn_sched_barrier(0)
#define VMWAIT(n) asm volatile("s_waitcnt vmcnt(" #n ")" ::: "memory")
#define LGKMWAIT0() asm volatile("s_waitcnt lgkmcnt(0)" ::: "memory")

// async global->LDS, 16B per lane; LDS dest = wave-uniform base + lane*16
__device__ __forceinline__ void gl_lds16(const void* g, void* l) {
  __builtin_amdgcn_global_load_lds((const __attribute__((address_space(1))) void*)g,
                                   (__attribute__((address_space(3))) void*)l, 16, 0, 0);
}

// Pre-swizzled global source (swizzle BOTH sides or neither).
// LDS tile is [rows][64] bf16, linear 128B rows; swizzle byte ^= ((row&7)<<4).
__device__ __forceinline__ const __bf16* swz_src(const __bf16* row0, size_t stride,
                                                 int tid, int i) {
  int lin = (tid + 256 * i) * 16;
  int r = lin >> 7, cb = lin & 127;
  return row0 + (size_t)r * stride + ((cb ^ ((r & 7) << 4)) >> 1);
}

// ------- fused front: 512 gating blocks + 8192 weight-transpose blocks -------
// Gating computes sim column-norms in-block (wave 0) from its staged sim tile;
// per-block expert counts go to cntb (no global atomics, no pre-zeroing).
__global__ __launch_bounds__(256, 2) void k_front(
    const float* __restrict__ x, const float* __restrict__ sim,
    const float* __restrict__ gates,
    const float* __restrict__ qp, const float* __restrict__ kp,
    const float* __restrict__ vp, const float* __restrict__ op,
    __bf16* __restrict__ pqt, __bf16* __restrict__ pkt,
    __bf16* __restrict__ pvt, __bf16* __restrict__ pot,
    float* __restrict__ w_all, int* __restrict__ cntb, __bf16* __restrict__ xbf) {
  __shared__ union {
    struct {
      float xs_[16][66];    // [token][col-in-chunk]
      float ss_[16][66];    // [e][col-in-chunk]
    } s;
    double red[8][32][2][17];  // [tkg][cg][t][dot0..15,norm] = 69632 B
    float ttile[32][33];       // transpose path
  } u;
  __shared__ double snred[32][16];
  __shared__ double snorm_lds[16];
  __shared__ double sig_lds[16];
  __shared__ float w_lds[16][16];
  __shared__ int cnt_lds[16];
  int id = blockIdx.x;
  int tid = threadIdx.x;

  if (id < 512) {   // ---------------- gating ----------------
    if (tid < 16) {
      cnt_lds[tid] = 0;
      sig_lds[tid] = 1.0 / (1.0 + exp(-(double)gates[tid]));
    }
    int cg = tid & 31, tkg = tid >> 5;
    int tok0 = id * 16;

    double acc[2][17];
#pragma unroll
    for (int t = 0; t < 2; t++)
#pragma unroll
      for (int i = 0; i < 17; i++) acc[t][i] = 0.0;
    double sn[16];
#pragma unroll
    for (int i = 0; i < 16; i++) sn[i] = 0.0;
    bool dosn = tid < 64;   // wave-uniform: wave 0 accumulates sim norms

    // staging roles
    int xr0 = tid >> 4, xc4 = (tid & 15) * 4;   // x row xr0, 4 cols
    int sr = tid >> 2, se4 = (tid & 3) * 4;     // sim row c0+sr, 4 experts

    float4 xa, sv;
    auto ldchunk = [&](int c0) {
      xa = *(const float4*)(x + (size_t)(tok0 + xr0) * NC + c0 + xc4);
      sv = *(const float4*)(sim + (size_t)(c0 + sr) * NE + se4);
    };
    auto stchunk = [&]() {
      *(float4*)&u.s.xs_[xr0][xc4] = xa;
      u.s.ss_[se4 + 0][sr] = sv.x;
      u.s.ss_[se4 + 1][sr] = sv.y;
      u.s.ss_[se4 + 2][sr] = sv.z;
      u.s.ss_[se4 + 3][sr] = sv.w;
    };
    auto stxbf = [&](int c0) {   // dense bf16 emit (xa still live)
      bf16x4 a;
      a[0]=f2bf(xa.x); a[1]=f2bf(xa.y); a[2]=f2bf(xa.z); a[3]=f2bf(xa.w);
      *(bf16x4*)(xbf + (size_t)(tok0 + xr0) * NC + c0 + xc4) = a;
    };

    ldchunk(0);
    for (int ch = 0; ch < 16; ch++) {
      stchunk();
      stxbf(ch * 64);
      __syncthreads();
      if (ch < 15) ldchunk((ch + 1) * 64);   // prefetch next chunk into regs
      double xd[2][2];
#pragma unroll
      for (int t = 0; t < 2; t++) {
        float2 xv = *(const float2*)&u.s.xs_[tkg * 2 + t][cg * 2];
        xd[t][0] = (double)xv.x;
        xd[t][1] = (double)xv.y;
        acc[t][16] += xd[t][0] * xd[t][0] + xd[t][1] * xd[t][1];
      }
#pragma unroll
      for (int e = 0; e < 16; e++) {
        float2 sv2 = *(const float2*)&u.s.ss_[e][cg * 2];
        double s0 = (double)sv2.x, s1 = (double)sv2.y;
#pragma unroll
        for (int t = 0; t < 2; t++)
          acc[t][e] += xd[t][0] * s0 + xd[t][1] * s1;
        if (dosn) sn[e] += s0 * s0 + s1 * s1;
      }
      __syncthreads();
    }

    // one-shot LDS reduce (xs_/ss_ dead; union'd)
#pragma unroll
    for (int t = 0; t < 2; t++)
#pragma unroll
      for (int i = 0; i < 17; i++)
        u.red[tkg][cg][t][i] = acc[t][i];
    if (tid < 32)
#pragma unroll
      for (int e = 0; e < 16; e++) snred[tid][e] = sn[e];
    __syncthreads();

    if (tid < 16) {   // reduce sim norms (f64 reassociation vs old prep: ulp-only)
      double s = 0.0;
      for (int c = 0; c < 32; c++) s += snred[c][tid];
      snorm_lds[tid] = fmax(sqrt(s), 1e-12);
    }
    __syncthreads();

    if (tid < 16) {
      double dots[17];
      for (int i = 0; i < 17; i++) {
        double s = 0.0;
        for (int c = 0; c < 32; c++) s += u.red[tid >> 1][c][tid & 1][i];
        dots[i] = s;
      }
      double xn = fmax(sqrt(dots[16]), 1e-12);
      double logits[NE];
      unsigned act = 0;
      int cnt = 0;
      for (int ee = 0; ee < NE; ee++) {
        logits[ee] = dots[ee] / (xn * snorm_lds[ee]) - sig_lds[ee];
        if (logits[ee] > 0.0) { act |= 1u << ee; cnt++; }
      }
      if (cnt == 0) {  // top-MIN_E(=2) fallback, lowest-index tie-break
        int i1 = 0; double b1 = logits[0];
        for (int ee = 1; ee < NE; ee++) if (logits[ee] > b1) { b1 = logits[ee]; i1 = ee; }
        int i2 = -1; double b2 = -1e300;
        for (int ee = 0; ee < NE; ee++) if (ee != i1 && logits[ee] > b2) { b2 = logits[ee]; i2 = ee; }
        act = (1u << i1) | (1u << i2);
      }
      double m = -1e300;
      for (int ee = 0; ee < NE; ee++) if ((act >> ee) & 1) m = fmax(m, fmax(logits[ee], 0.0));
      double s = 0.0, wvv[NE];
      for (int ee = 0; ee < NE; ee++) {
        if ((act >> ee) & 1) { wvv[ee] = exp(fmax(logits[ee], 0.0) - m); s += wvv[ee]; }
        else wvv[ee] = 0.0;
      }
      for (int ee = 0; ee < NE; ee++) {
        if ((act >> ee) & 1) {
          w_lds[tid][ee] = (float)(wvv[ee] / s);
          atomicAdd(&cnt_lds[ee], 1);
        } else w_lds[tid][ee] = 0.0f;
      }
    }
    __syncthreads();
    w_all[(size_t)(tok0 + (tid >> 4)) * NE + (tid & 15)] = w_lds[tid >> 4][tid & 15];
    if (tid < 16) cntb[id * 16 + tid] = cnt_lds[tid];
    return;
  }

  // ---------------- weight transpose (fp32 -> bf16) ----------------
  int t2 = id - 512;
  int z = t2 >> 7, xb = t2 & 127;
  const float* in;
  __bf16* out;
  int R, Cd, g, r0, c0;
  if (z < 48) {
    int which = z >> 4; g = z & 15; R = 1024; Cd = 128;
    in = which == 0 ? qp : (which == 1 ? kp : vp);
    out = which == 0 ? pqt : (which == 1 ? pkt : pvt);
    r0 = (xb >> 2) * 32; c0 = (xb & 3) * 32;
  } else {
    g = z - 48; R = 128; Cd = 1024;
    in = op; out = pot;
    r0 = (xb & 3) * 32; c0 = (xb >> 2) * 32;
  }
  int tx = tid & 31, ty0 = tid >> 5;
  const float* src = in + (size_t)g * R * Cd;
  __bf16* dst = out + (size_t)g * R * Cd;
#pragma unroll
  for (int ty = ty0; ty < 32; ty += 8)
    u.ttile[ty][tx] = src[(size_t)(r0 + ty) * Cd + (c0 + tx)];
  __syncthreads();
#pragma unroll
  for (int ty = ty0; ty < 32; ty += 8)
    dst[(size_t)(c0 + ty) * R + (r0 + tx)] = f2bf(u.ttile[tx][ty]);
}

// ---------------- scan: reduce per-block counts -> offsets + 128-row tiles ----------------
__global__ void k_scan(const int* __restrict__ cntb, int* __restrict__ offsets,
                       int2* __restrict__ tile_desc, int* __restrict__ n_tiles,
                       int* __restrict__ cursors) {
  __shared__ int part[16][17];
  int tid = threadIdx.x;
  int e = tid & 15, pp = tid >> 4;
  int s = 0;
  for (int b = pp; b < 512; b += 16) s += cntb[b * 16 + e];
  part[pp][e] = s;
  __syncthreads();
  if (tid >= 16 && tid < 32) cursors[tid - 16] = 0;
  if (tid == 0) {
    int off = 0, nt = 0;
    for (int ee = 0; ee < NE; ee++) {
      int c = 0;
      for (int p = 0; p < 16; p++) c += part[p][ee];
      offsets[ee] = off;
      int tiles = (c + 127) >> 7;
      for (int t = 0; t < tiles; t++) {
        int s0 = off + t * 128;
        if (s0 < CAP && nt < NT2_MAX) { tile_desc[nt].x = ee; tile_desc[nt].y = s0; nt++; }
      }
      off += c;
    }
    offsets[NE] = off;
    *n_tiles = nt;
  }
}

// ------- slot assignment + token->slot inverse map (ballot-aggregated atomics) -------
__global__ void k_assign(const float* __restrict__ w_all, const int* __restrict__ offsets,
                         int* __restrict__ cursors, int* __restrict__ slot_token,
                         float* __restrict__ slot_w, int* __restrict__ tok_slots,
                         int* __restrict__ tok_cnt) {
  int n = blockIdx.x * 256 + threadIdx.x;   // grid exactly covers NTOK
  int lane = threadIdx.x & 63;
  int j = 0;
  for (int e = 0; e < NE; e++) {
    float w = w_all[(size_t)n * NE + e];
    bool a = w > 0.0f;
    unsigned long long mask = __ballot(a);
    if (mask) {
      int leader = (int)__ffsll((long long)mask) - 1;
      int base = 0;
      if (lane == leader) base = atomicAdd(&cursors[e], (int)__popcll(mask));
      base = __shfl(base, leader);
      if (a) {
        int pos = base + (int)__popcll(mask & ((1ULL << lane) - 1ULL));
        int s = offsets[e] + pos;
        slot_token[s] = n;
        slot_w[s] = w;
        tok_slots[n * 16 + j] = s;
        j++;
      }
    }
  }
  tok_cnt[n] = j;
}

// ---------------- MFMA tiles on XOR-swizzled LDS ----------------
// 64x128 (A rows 64): used by flash.
__device__ __forceinline__ void mfma_block(const __bf16* As, const __bf16* Bs,
                                           int lane, int wrow, f32x4 acc[8]) {
  const char* Ab = (const char*)As;
  const char* Bb = (const char*)Bs;
  int arow = wrow + (lane & 15);
  int rb = lane & 15;
#pragma unroll
  for (int ks = 0; ks < 2; ks++) {
    int kb = ks * 64 + (lane >> 4) * 16;   // byte offset within 128B row
    bf16x8 af = *(const bf16x8*)(Ab + arow * 128 + (kb ^ ((arow & 7) << 4)));
#pragma unroll
    for (int nt = 0; nt < 8; nt++) {
      int brow = nt * 16 + rb;
      bf16x8 bv = *(const bf16x8*)(Bb + brow * 128 + (kb ^ ((brow & 7) << 4)));
      acc[nt] = __builtin_amdgcn_mfma_f32_16x16x32_bf16(af, bv, acc[nt], 0, 0, 0);
    }
  }
}

// 128x128 (A rows 128, wave owns 32 A-rows): grouped GEMMs.
__device__ __forceinline__ void mfma_block128(const __bf16* As, const __bf16* Bs,
                                              int lane, int wrow2, f32x4 acc[2][8]) {
  const char* Ab = (const char*)As;
  const char* Bb = (const char*)Bs;
  int rb = lane & 15;
#pragma unroll
  for (int ks = 0; ks < 2; ks++) {
    int kb = ks * 64 + (lane >> 4) * 16;
    int ar = wrow2 + rb;                   // (ar&7) == ((ar+16)&7)
    int sw = kb ^ ((ar & 7) << 4);
    bf16x8 af0 = *(const bf16x8*)(Ab + ar * 128 + sw);
    bf16x8 af1 = *(const bf16x8*)(Ab + (ar + 16) * 128 + sw);
#pragma unroll
    for (int nt = 0; nt < 8; nt++) {
      int brow = nt * 16 + rb;
      bf16x8 bv = *(const bf16x8*)(Bb + brow * 128 + (kb ^ ((brow & 7) << 4)));
      acc[0][nt] = __builtin_amdgcn_mfma_f32_16x16x32_bf16(af0, bv, acc[0][nt], 0, 0, 0);
      acc[1][nt] = __builtin_amdgcn_mfma_f32_16x16x32_bf16(af1, bv, acc[1][nt], 0, 0, 0);
    }
  }
}

// A-operand from registers (Q frags), B from swizzled LDS
__device__ __forceinline__ void mfma_regA(bf16x8 af0, bf16x8 af1, const __bf16* Bs,
                                          int lane, f32x4 acc[8]) {
  const char* Bb = (const char*)Bs;
  int rb = lane & 15;
#pragma unroll
  for (int ks = 0; ks < 2; ks++) {
    int kb = ks * 64 + (lane >> 4) * 16;
    bf16x8 af = ks ? af1 : af0;
#pragma unroll
    for (int nt = 0; nt < 8; nt++) {
      int brow = nt * 16 + rb;
      bf16x8 bv = *(const bf16x8*)(Bb + brow * 128 + (kb ^ ((brow & 7) << 4)));
      acc[nt] = __builtin_amdgcn_mfma_f32_16x16x32_bf16(af, bv, acc[nt], 0, 0, 0);
    }
  }
}

// ------- grouped GEMM: QKV projections, BM=128, indirect A-gather, counted vmcnt -------
__global__ __launch_bounds__(256) void k_moe_qkv2(
    const __bf16* __restrict__ xbf, const int* __restrict__ slot_token,
    const __bf16* __restrict__ pq, const __bf16* __restrict__ pk, const __bf16* __restrict__ pv,
    const int* __restrict__ offsets, const int2* __restrict__ tile_desc,
    const int* __restrict__ n_tiles,
    __bf16* __restrict__ yq, __bf16* __restrict__ yk, __bf16* __restrict__ yv) {
  int id = blockIdx.x;
  int w = (id & 7) * (3 * NT2_MAX / 8) + (id >> 3);  // chunked bijective (456)
  int ti = w / 3, p = w % 3;
  if (ti >= *n_tiles) return;
  int2 td = tile_desc[ti];
  int e = td.x, s0 = td.y;
  int seg_end = offsets[e + 1]; if (seg_end > CAP) seg_end = CAP;
  const __bf16* Bt;
  __bf16* Yd;
  if (p == 0)      { Bt = pq; Yd = yq; }
  else if (p == 1) { Bt = pk; Yd = yk; }
  else             { Bt = pv; Yd = yv; }
  Bt += (size_t)e * NH * NC;

  __shared__ __bf16 As[2][128 * 64];
  __shared__ __bf16 Bs[2][128 * 64];
  int tid = threadIdx.x, lane = tid & 63, wid = tid >> 6, wrow2 = wid * 32;
  // per-lane indirect A source: row r of tile -> token slot_token[s0+r]
  const __bf16* asrc[4];
  const __bf16* bsrc[4];
#pragma unroll
  for (int i = 0; i < 4; i++) {
    int lin = (tid + 256 * i) * 16;
    int r = lin >> 7, cb = lin & 127;
    int tok = slot_token[s0 + r] & (NTOK - 1);   // mask poisoned tails
    asrc[i] = xbf + (size_t)tok * NC + ((cb ^ ((r & 7) << 4)) >> 1);
  }
#pragma unroll
  for (int i = 0; i < 4; i++) bsrc[i] = swz_src(Bt, NC, tid, i);
  auto stage = [&](int buf, int k0) {
#pragma unroll
    for (int i = 0; i < 4; i++)
      gl_lds16(asrc[i] + k0, (char*)As[buf] + tid * 16 + i * 4096);
#pragma unroll
    for (int i = 0; i < 4; i++)
      gl_lds16(bsrc[i] + k0, (char*)Bs[buf] + tid * 16 + i * 4096);
  };

  f32x4 acc[2][8];
#pragma unroll
  for (int rf = 0; rf < 2; rf++)
#pragma unroll
    for (int i = 0; i < 8; i++) { f32x4 z = {0.f, 0.f, 0.f, 0.f}; acc[rf][i] = z; }

  // 16 K-steps, 2 LDS buffers, 2 tiles (16 loads/wave) always in flight.
  stage(0, 0);
  stage(1, 64);
  VMWAIT(8); BARRIER(); SFENCE();        // tile 0 resident everywhere
  int cur = 0;
  for (int t = 0; t <= 13; t++) {        // compute tile t; stage tile t+2
    __builtin_amdgcn_s_setprio(1);
    mfma_block128(As[cur], Bs[cur], lane, wrow2, acc);
    __builtin_amdgcn_s_setprio(0);
    SFENCE();
    BARRIER();                           // all waves done reading buf[cur]
    stage(cur, (t + 2) * 64);            // overwrite buf[cur] with tile t+2
    VMWAIT(8); BARRIER(); SFENCE();      // tile t+1 resident everywhere
    cur ^= 1;
  }
  __builtin_amdgcn_s_setprio(1);
  mfma_block128(As[cur], Bs[cur], lane, wrow2, acc);      // tile 14
  __builtin_amdgcn_s_setprio(0);
  SFENCE();
  VMWAIT(0); BARRIER(); SFENCE();                         // tile 15 resident
  __builtin_amdgcn_s_setprio(1);
  mfma_block128(As[cur ^ 1], Bs[cur ^ 1], lane, wrow2, acc);  // tile 15
  __builtin_amdgcn_s_setprio(0);

  int col = lane & 15, quad = lane >> 4;
#pragma unroll
  for (int rf = 0; rf < 2; rf++)
#pragma unroll
    for (int r = 0; r < 4; r++) {
      int s = s0 + wrow2 + rf * 16 + quad * 4 + r;
      if (s < seg_end) {
#pragma unroll
        for (int nt = 0; nt < 8; nt++)
          Yd[(size_t)s * NH + nt * 16 + col] = f2bf(acc[rf][nt][r]);
      }
    }
}

// ------- combine Y slots -> token-major bf16 q/k + direct V^T (fused transpose) -------
// Q is pre-scaled by scale*log2(e) so flash works in exp2 domain.
__global__ __launch_bounds__(256) void k_combine_qkv(
    const __bf16* __restrict__ yq, const __bf16* __restrict__ yk, const __bf16* __restrict__ yv,
    const int* __restrict__ tok_slots, const int* __restrict__ tok_cnt,
    const float* __restrict__ slot_w,
    __bf16* __restrict__ qb, __bf16* __restrict__ kb, __bf16* __restrict__ vt) {
  __shared__ __bf16 vtile[128][34];
  int tid = threadIdx.x;
  int tok0 = blockIdx.x * 32;
  int tt = tok0 + (tid >> 3);
  int h0 = (tid & 7) * 16;
  const __bf16* Y = blockIdx.y == 0 ? yq : (blockIdx.y == 1 ? yk : yv);
  int cnt = tok_cnt[tt];
  float acc[16];
#pragma unroll
  for (int i = 0; i < 16; i++) acc[i] = 0.f;
  for (int j = 0; j < cnt; j++) {
    int s = tok_slots[tt * 16 + j];
    if (s < CAP) {
      float w = slot_w[s];
      bf16x8 v0 = *(const bf16x8*)(Y + (size_t)s * NH + h0);
      bf16x8 v1 = *(const bf16x8*)(Y + (size_t)s * NH + h0 + 8);
#pragma unroll
      for (int i = 0; i < 8; i++) { acc[i] += w * (float)v0[i]; acc[8 + i] += w * (float)v1[i]; }
    }
  }
  if (blockIdx.y == 2) {
    // V: LDS transpose tile [h][t], write VT [b][h][t] coalesced
#pragma unroll
    for (int i = 0; i < 16; i++) vtile[h0 + i][tid >> 3] = f2bf(acc[i]);
    __syncthreads();
    int h = tid >> 1, tp = (tid & 1) * 16;
    int b = tok0 >> 11, trow = tok0 & 2047;
    __bf16* dst = vt + ((size_t)b * NH + h) * NT + trow + tp;
    bf16x8 o0, o1;
#pragma unroll
    for (int i = 0; i < 8; i++) { o0[i] = vtile[h][tp + i]; o1[i] = vtile[h][tp + 8 + i]; }
    *(bf16x8*)dst = o0;
    *(bf16x8*)(dst + 8) = o1;
  } else {
    float sc = blockIdx.y == 0 ? 0.12751744458115337f : 1.0f;  // (1/sqrt(128))*log2(e)
    __bf16* D = blockIdx.y == 0 ? qb : kb;
    bf16x8 o0, o1;
#pragma unroll
    for (int i = 0; i < 8; i++) { o0[i] = f2bf(acc[i] * sc); o1[i] = f2bf(acc[8 + i] * sc); }
    __bf16* d = D + (size_t)tt * NH + h0;
    *(bf16x8*)d = o0;
    *(bf16x8*)(d + 8) = o1;
  }
}

// ---------------- flash attention: QK^T -> exp2-domain online softmax -> PV ----------------
// grid 512 = 4 b x 4 splits x 32 t-blocks (XCD-chunked). LDS: K 32K + V 32K + P 16K.
__global__ __launch_bounds__(256) void k_flash(const __bf16* __restrict__ q,
                                               const __bf16* __restrict__ k,
                                               const __bf16* __restrict__ vt,
                                               float* __restrict__ opart,
                                               float2* __restrict__ ml) {
  int id = blockIdx.x;
  int w = (id & 7) * 64 + (id >> 3);     // chunked bijective over 512
  int b = w >> 7;
  int rem = w & 127;
  int spl = rem >> 5;
  int t0 = (rem & 31) * 64;
  const __bf16* qb = q + (size_t)b * NT * NH;
  const __bf16* kb = k + (size_t)b * NT * NH;
  const __bf16* vtb = vt + (size_t)b * NH * NT;

  __shared__ __bf16 Ks[2][128 * 64];   // [d-chunk][s-row][64]
  __shared__ __bf16 Vs[2][128 * 64];   // [s-chunk][d-row][64]
  __shared__ __bf16 Ps[2][64 * 64];    // [s-chunk][t-row][64]
  int tid = threadIdx.x, lane = tid & 63, wid = tid >> 6, wrow = wid * 16;
  int colq = lane & 15, quad = lane >> 4;

  // Q fragments in registers (force-resolved before staging starts)
  bf16x8 qf[4];
  {
    const __bf16* qr = qb + (size_t)(t0 + wrow + colq) * NH + quad * 8;
#pragma unroll
    for (int kk = 0; kk < 4; kk++) qf[kk] = *(const bf16x8*)(qr + kk * 32);
  }
  asm volatile("" :: "v"(qf[0]), "v"(qf[1]), "v"(qf[2]), "v"(qf[3]));
  SFENCE();

  auto stage_K = [&](int s0) {
#pragma unroll
    for (int c = 0; c < 2; c++)
#pragma unroll
      for (int i = 0; i < 4; i++)
        gl_lds16(swz_src(kb + (size_t)s0 * NH + c * 64, NH, tid, i),
                 (char*)Ks[c] + wid * 1024 + i * 4096);
  };
  auto stage_V = [&](int s0) {
#pragma unroll
    for (int c = 0; c < 2; c++)
#pragma unroll
      for (int i = 0; i < 4; i++)
        gl_lds16(swz_src(vtb + s0 + c * 64, NT, tid, i),
                 (char*)Vs[c] + wid * 1024 + i * 4096);
  };

  f32x4 oacc[8];
#pragma unroll
  for (int i = 0; i < 8; i++) { f32x4 z = {0.f, 0.f, 0.f, 0.f}; oacc[i] = z; }
  float mr[4], lr[4];
#pragma unroll
  for (int r = 0; r < 4; r++) { mr[r] = -1e30f; lr[r] = 0.f; }

  const int sbase = spl * 512;
  stage_K(sbase);
  stage_V(sbase);
  VMWAIT(8); BARRIER(); SFENCE();        // K(0) resident; V(0) 8 loads in flight

  for (int t = 0; t < 4; t++) {
    // ---- QK^T for s-tile t (already in log2 domain via pre-scaled Q) ----
    f32x4 sacc[8];
#pragma unroll
    for (int i = 0; i < 8; i++) { f32x4 z = {0.f, 0.f, 0.f, 0.f}; sacc[i] = z; }
    __builtin_amdgcn_s_setprio(1);
    mfma_regA(qf[0], qf[1], Ks[0], lane, sacc);
    mfma_regA(qf[2], qf[3], Ks[1], lane, sacc);
    __builtin_amdgcn_s_setprio(0);
    SFENCE();
    BARRIER();                           // all waves done reading Ks
    if (t < 3) stage_K(sbase + (t + 1) * 128);   // +8 in flight

    // ---- online softmax (base 2); P -> LDS (own wave's rows only) ----
    float tm[4];
#pragma unroll
    for (int r = 0; r < 4; r++) {
      float v = sacc[0][r];
#pragma unroll
      for (int nt = 1; nt < 8; nt++) v = fmaxf(v, sacc[nt][r]);
      tm[r] = v;
    }
#pragma unroll
    for (int off = 1; off < 16; off <<= 1)
#pragma unroll
      for (int r = 0; r < 4; r++) tm[r] = fmaxf(tm[r], __shfl_xor(tm[r], off));
    float alpha[4], rs[4];
#pragma unroll
    for (int r = 0; r < 4; r++) {
      float mn = fmaxf(mr[r], tm[r]);
      alpha[r] = exp2f(mr[r] - mn);
      mr[r] = mn;
      rs[r] = 0.f;
    }
#pragma unroll
    for (int nt = 0; nt < 8; nt++) {
      char* pc = (char*)Ps[nt >> 2];
      int colb = ((nt & 3) * 16 + colq) * 2;
#pragma unroll
      for (int r = 0; r < 4; r++) {
        int row = wrow + quad * 4 + r;
        float p = exp2f(sacc[nt][r] - mr[r]);
        rs[r] += p;
        *(__bf16*)(pc + row * 128 + (colb ^ ((row & 7) << 4))) = f2bf(p);
      }
    }
#pragma unroll
    for (int off = 1; off < 16; off <<= 1)
#pragma unroll
      for (int r = 0; r < 4; r++) rs[r] += __shfl_xor(rs[r], off);
#pragma unroll
    for (int r = 0; r < 4; r++) lr[r] = alpha[r] * lr[r] + rs[r];
#pragma unroll
    for (int nt = 0; nt < 8; nt++)
#pragma unroll
      for (int r = 0; r < 4; r++) oacc[nt][r] *= alpha[r];

    LGKMWAIT0();                         // P writes done
    if (t < 3) { VMWAIT(8); } else { VMWAIT(0); }   // V(t) resident (own loads)
    BARRIER(); SFENCE();                 // everyone's V(t) + P ready

    // ---- PV ----
    __builtin_amdgcn_s_setprio(1);
    mfma_block(Ps[0], Vs[0], lane, wrow, oacc);
    mfma_block(Ps[1], Vs[1], lane, wrow, oacc);
    __builtin_amdgcn_s_setprio(0);
    SFENCE();
    BARRIER();                           // all done reading Vs, Ps
    if (t < 3) {
      stage_V(sbase + (t + 1) * 128);    // +8 -> 16 in flight
      VMWAIT(8); BARRIER(); SFENCE();    // K(t+1) resident
    }
  }

  // epilogue: unnormalized partial O + (m,l) in log2 domain
  size_t base = (size_t)(b * 4 + spl) * NT + t0;
#pragma unroll
  for (int r = 0; r < 4; r++) {
    size_t row = base + wrow + quad * 4 + r;
#pragma unroll
    for (int nt = 0; nt < 8; nt++)
      opart[row * NH + nt * 16 + colq] = oacc[nt][r];
  }
  if (colq == 0) {
#pragma unroll
    for (int r = 0; r < 4; r++) {
      float2 v; v.x = mr[r]; v.y = lr[r];
      ml[base + wrow + quad * 4 + r] = v;
    }
  }
}

// ---------------- gather o: merge 4 split partials (base-2 LSE) -> slot-major bf16 ----------------
__global__ __launch_bounds__(256) void k_gather_o(const float* __restrict__ opart,
                                                  const float2* __restrict__ ml,
                                                  const int* __restrict__ slot_token,
                                                  const int* __restrict__ offsets,
                                                  __bf16* __restrict__ og) {
  int slot = blockIdx.x * 2 + (threadIdx.x >> 7);
  int h = threadIdx.x & 127;
  int total = offsets[NE]; if (total > CAP) total = CAP;
  if (slot >= total) return;
  int n = slot_token[slot];
  int b = n >> 11, trow = n & 2047;
  size_t rb = (size_t)b * 4 * NT + trow;
  float2 m0 = ml[rb], m1 = ml[rb + NT], m2 = ml[rb + 2 * NT], m3 = ml[rb + 3 * NT];
  float M = fmaxf(fmaxf(m0.x, m1.x), fmaxf(m2.x, m3.x));
  float e0 = exp2f(m0.x - M), e1 = exp2f(m1.x - M), e2 = exp2f(m2.x - M), e3 = exp2f(m3.x - M);
  float den = m0.y * e0 + m1.y * e1 + m2.y * e2 + m3.y * e3;
  float num = opart[rb * NH + h] * e0 + opart[(rb + NT) * NH + h] * e1 +
              opart[(rb + 2 * NT) * NH + h] * e2 + opart[(rb + 3 * NT) * NH + h] * e3;
  og[(size_t)slot * NH + h] = f2bf(num / den);
}

// ------- grouped GEMM: out-proj, BM=128, 2 N-chunks/block (A staged once) -------
__global__ __launch_bounds__(256) void k_out2(
    const __bf16* __restrict__ og, const __bf16* __restrict__ pot,
    const int* __restrict__ offsets, const int2* __restrict__ tile_desc,
    const int* __restrict__ n_tiles, __bf16* __restrict__ zy) {
  int id = blockIdx.x;
  int w = (id & 7) * (4 * NT2_MAX / 8) + (id >> 3);  // chunked bijective (608)
  int ti = w >> 2, p = w & 3;                        // p = 256-wide nc chunk 0..3
  if (ti >= *n_tiles) return;
  int2 td = tile_desc[ti];
  int e = td.x, s0 = td.y;
  int seg_end = offsets[e + 1]; if (seg_end > CAP) seg_end = CAP;
  int nc0 = p * 256;
  const __bf16* Bt = pot + (size_t)e * NC * NH;

  __shared__ __bf16 As[2][128 * 64];
  __shared__ __bf16 Bs[2][128 * 64];
  int tid = threadIdx.x, lane = tid & 63, wid = tid >> 6, wrow2 = wid * 32;
  const __bf16* asrc[4];
  const __bf16* bsrc[4];
#pragma unroll
  for (int i = 0; i < 4; i++) asrc[i] = swz_src(og + (size_t)s0 * NH, NH, tid, i);
#pragma unroll
  for (int i = 0; i < 4; i++) bsrc[i] = swz_src(Bt + (size_t)nc0 * NH, NH, tid, i);
  auto stageA = [&](int buf, int k0) {
#pragma unroll
    for (int i = 0; i < 4; i++)
      gl_lds16(asrc[i] + k0, (char*)As[buf] + tid * 16 + i * 4096);
  };
  auto stageB = [&](int buf, int k0, int noff) {
#pragma unroll
    for (int i = 0; i < 4; i++)
      gl_lds16(bsrc[i] + (size_t)noff * NH + k0, (char*)Bs[buf] + tid * 16 + i * 4096);
  };
  f32x4 acc[2][8];
  int col = lane & 15, quad = lane >> 4;
  auto store_acc = [&](int nco) {
#pragma unroll
    for (int rf = 0; rf < 2; rf++)
#pragma unroll
      for (int r = 0; r < 4; r++) {
        int s = s0 + wrow2 + rf * 16 + quad * 4 + r;
        if (s < seg_end) {
#pragma unroll
          for (int nt = 0; nt < 8; nt++)
            zy[(size_t)s * NC + nco + nt * 16 + col] = f2bf(acc[rf][nt][r]);
        }
      }
  };

#pragma unroll
  for (int rf = 0; rf < 2; rf++)
#pragma unroll
    for (int i = 0; i < 8; i++) { f32x4 z = {0.f, 0.f, 0.f, 0.f}; acc[rf][i] = z; }

  // A (full K=128) staged once; B re-staged per 128-wide n-chunk.
  stageA(0, 0); stageB(0, 0, 0);        // first 8: As[0] + Bs[0] (chunk 0)
  stageA(1, 64); stageB(1, 64, 0);
  VMWAIT(8); BARRIER(); SFENCE();
  __builtin_amdgcn_s_setprio(1);
  mfma_block128(As[0], Bs[0], lane, wrow2, acc);
  __builtin_amdgcn_s_setprio(0);
  SFENCE();
  VMWAIT(0); BARRIER(); SFENCE();
  __builtin_amdgcn_s_setprio(1);
  mfma_block128(As[1], Bs[1], lane, wrow2, acc);
  __builtin_amdgcn_s_setprio(0);
  SFENCE();
  store_acc(nc0);
  BARRIER();                            // all waves done reading Bs
  stageB(0, 0, 128); stageB(1, 64, 128);   // B for chunk 1; As untouched
#pragma unroll
  for (int rf = 0; rf < 2; rf++)
#pragma unroll
    for (int i = 0; i < 8; i++) { f32x4 z = {0.f, 0.f, 0.f, 0.f}; acc[rf][i] = z; }
  VMWAIT(0); BARRIER(); SFENCE();
  __builtin_amdgcn_s_setprio(1);
  mfma_block128(As[0], Bs[0], lane, wrow2, acc);
  mfma_block128(As[1], Bs[1], lane, wrow2, acc);
  __builtin_amdgcn_s_setprio(0);
  store_acc(nc0 + 128);
}

// ---------------- combine ZY slots -> dense fp32 out ----------------
__global__ __launch_bounds__(256) void k_combine_out(
    const __bf16* __restrict__ zy, const int* __restrict__ tok_slots,
    const int* __restrict__ tok_cnt, const float* __restrict__ slot_w,
    float* __restrict__ out) {
  int token = blockIdx.x;
  int c = threadIdx.x * 4;
  int cnt = tok_cnt[token];
  float a0 = 0.f, a1 = 0.f, a2 = 0.f, a3 = 0.f;
  for (int j = 0; j < cnt; j++) {
    int s = tok_slots[token * 16 + j];
    if (s < CAP) {
      float w = slot_w[s];
      bf16x4 z = *(const bf16x4*)&zy[(size_t)s * NC + c];
      a0 += w * (float)z[0];
      a1 += w * (float)z[1];
      a2 += w * (float)z[2];
      a3 += w * (float)z[3];
    }
  }
  float4 o = {a0, a1, a2, a3};
  *(float4*)&out[(size_t)token * NC + c] = o;
}

extern "C" void kernel_launch(void* const* d_in, const int* in_sizes, int n_in,
                              void* d_out, int out_size, void* d_ws, size_t ws_size,
                              hipStream_t stream) {
  const float* hs    = (const float*)d_in[0];  // [4,2048,1024]
  const float* sim   = (const float*)d_in[1];  // [1024,16]
  const float* gates = (const float*)d_in[2];  // [16]
  const float* qp    = (const float*)d_in[3];  // [16,1024,128]
  const float* kp    = (const float*)d_in[4];
  const float* vp    = (const float*)d_in[5];
  const float* op    = (const float*)d_in[6];  // [16,128,1024]
  float* out = (float*)d_out;
  char* ws = (char*)d_ws;

  // ---- workspace arena (aliased by lifetime) ----
  const size_t M = 1048576;
  __bf16* PQT = (__bf16*)(ws + 0 * M);         // 4 MiB each
  __bf16* PKT = (__bf16*)(ws + 4 * M);
  __bf16* PVT = (__bf16*)(ws + 8 * M);
  __bf16* POT = (__bf16*)(ws + 12 * M);
  __bf16* Qb  = (__bf16*)(ws + 16 * M);        // 2 MiB each, token-major bf16
  __bf16* Kb  = (__bf16*)(ws + 18 * M);
  __bf16* VT  = (__bf16*)(ws + 22 * M);        // 2 MiB [b][h][t]
  int*    CNTB = (int*)(ws + 27 * M);          // 32 KiB per-block gating counts
  float*  WALL = (float*)(ws + 28 * M);        // 512 KiB
  int*    STOK = (int*)(ws + 28 * M + 524288); // 512 KiB
  float*  SW   = (float*)(ws + 28 * M + 1048576);
  int*    TSL  = (int*)(ws + 28 * M + 1572864);  // tok_slots 512 KiB
  int*    TCN  = (int*)(ws + 28 * M + 2097152);  // tok_cnt 32 KiB
  int* CNT = (int*)(ws + 28 * M + 2130432);    // control block
  int* OFF = CNT + 16;
  int* CUR = CNT + 40;
  int* NTL = CNT + 60;
  int2* DESC = (int2*)(ws + 28 * M + 2131456);
  // R region (32M..96M), aliased by lifetime:
  __bf16* XBF = (__bf16*)(ws + 32 * M);        // 16.8 MiB dense bf16 x (dies after qkv2)
  __bf16* YQ = (__bf16*)(ws + 72 * M);         // 4.5 MiB each (die before flash)
  __bf16* YK = (__bf16*)(ws + 77 * M);
  __bf16* YV = (__bf16*)(ws + 82 * M);
  float*  OP2 = (float*)(ws + 32 * M);         // 16.8 MiB partial O (after XBF dead)
  float2* MLB = (float2*)(ws + 50 * M);        // 256 KiB (m,l) per split-row
  __bf16* OG = (__bf16*)(ws + 52 * M);         // 4.5 MiB
  __bf16* ZY = (__bf16*)(ws + 60 * M);         // 36.1 MiB

  k_front<<<512 + 64 * 128, 256, 0, stream>>>(hs, sim, gates, qp, kp, vp, op,
                                              PQT, PKT, PVT, POT, WALL, CNTB, XBF);
  k_scan<<<1, 256, 0, stream>>>(CNTB, OFF, DESC, NTL, CUR);
  k_assign<<<NTOK / 256, 256, 0, stream>>>(WALL, OFF, CUR, STOK, SW, TSL, TCN);
  k_moe_qkv2<<<3 * NT2_MAX, 256, 0, stream>>>(XBF, STOK, PQT, PKT, PVT, OFF, DESC, NTL, YQ, YK, YV);
  k_combine_qkv<<<dim3(NTOK / 32, 3), 256, 0, stream>>>(YQ, YK, YV, TSL, TCN, SW, Qb, Kb, VT);
  k_flash<<<512, 256, 0, stream>>>(Qb, Kb, VT, OP2, MLB);
  k_gather_o<<<CAP / 2, 256, 0, stream>>>(OP2, MLB, STOK, OFF, OG);
  k_out2<<<4 * NT2_MAX, 256, 0, stream>>>(OG, POT, OFF, DESC, NTL, ZY);
  k_combine_out<<<NTOK, 256, 0, stream>>>(ZY, TSL, TCN, SW, out);
}

// Round 11
// 309.394 us; speedup vs baseline: 1.2011x; 1.2011x over previous
//
#include <hip/hip_runtime.h>
#include <hip/hip_bf16.h>
#include <math.h>

// DynSMHA: B=4 T=2048 C=1024 H=128 E=16 MIN_E=2, non-causal.
// weight transposes + prep -> fp64 gating (16 tok/block, per-block counts,
// emits dense bf16 x) -> parallel scan -> ballot-aggregated slot assign ->
// grouped GEMMs (BM=128, indirect A-gather, counted-vmcnt, XOR-swizzled LDS) ->
// flash attention (exp2-domain online softmax, split-s LSE) -> combines.
#define NBATCH 4
#define NT     2048
#define NC     1024
#define NH     128
#define NE     16
#define NTOK   (NBATCH * NT)
#define CAP    18432         // slot capacity (actual ~16384)
#define NT2_MAX 152          // sum ceil(cnt_e/128) + slack; multiple of 8

typedef __bf16 bf16x8 __attribute__((ext_vector_type(8)));
typedef __bf16 bf16x4 __attribute__((ext_vector_type(4)));
typedef float  f32x4  __attribute__((ext_vector_type(4)));

__device__ __forceinline__ __bf16 f2bf(float f) { return (__bf16)f; }

#define BARRIER() __builtin_amdgcn_s_barrier()
#define SFENCE()  __builtin_amdgcn_sched_barrier(0)
#define VMWAIT(n) asm volatile("s_waitcnt vmcnt(" #n ")" ::: "memory")
#define LGKMWAIT0() asm volatile("s_waitcnt lgkmcnt(0)" ::: "memory")

// async global->LDS, 16B per lane; LDS dest = wave-uniform base + lane*16
__device__ __forceinline__ void gl_lds16(const void* g, void* l) {
  __builtin_amdgcn_global_load_lds((const __attribute__((address_space(1))) void*)g,
                                   (__attribute__((address_space(3))) void*)l, 16, 0, 0);
}

// Pre-swizzled global source (swizzle BOTH sides or neither).
// LDS tile is [rows][64] bf16, linear 128B rows; swizzle byte ^= ((row&7)<<4).
__device__ __forceinline__ const __bf16* swz_src(const __bf16* row0, size_t stride,
                                                 int tid, int i) {
  int lin = (tid + 256 * i) * 16;
  int r = lin >> 7, cb = lin & 127;
  return row0 + (size_t)r * stride + ((cb ^ ((r & 7) << 4)) >> 1);
}

// ------- fused: weight transposes (fp32->bf16) + sim-norm/sigmoid prep -------
// Lightweight LDS footprint (4KB+2KB) -> high occupancy for the BW-bound path.
__global__ void k_transpose_all(const float* __restrict__ qp, const float* __restrict__ kp,
                                const float* __restrict__ vp, const float* __restrict__ op,
                                __bf16* __restrict__ pqt, __bf16* __restrict__ pkt,
                                __bf16* __restrict__ pvt, __bf16* __restrict__ pot,
                                const float* __restrict__ sim, const float* __restrict__ gates,
                                double* __restrict__ snorm, double* __restrict__ sig) {
  __shared__ float tile[32][33];
  __shared__ double red[16][17];
  int z = blockIdx.y;
  int tid = threadIdx.x;
  if (z == 64) {                          // prep block
    if (blockIdx.x != 0) return;
    int e = tid & 15, chunk = tid >> 4;
    double a = 0.0;
#pragma unroll 4
    for (int j = 0; j < 64; j++) {
      double v = (double)sim[(chunk * 64 + j) * NE + e];
      a += v * v;
    }
    red[chunk][e] = a;
    __syncthreads();
    if (tid < 16) {
      double s = 0.0;
      for (int k = 0; k < 16; k++) s += red[k][tid];
      snorm[tid] = fmax(sqrt(s), 1e-12);
      sig[tid] = 1.0 / (1.0 + exp(-(double)gates[tid]));
    }
    return;
  }
  const float* in;
  __bf16* out;
  int R, Cd, g, r0, c0;
  if (z < 48) {
    int which = z >> 4; g = z & 15; R = 1024; Cd = 128;
    in = which == 0 ? qp : (which == 1 ? kp : vp);
    out = which == 0 ? pqt : (which == 1 ? pkt : pvt);
    r0 = (blockIdx.x >> 2) * 32; c0 = (blockIdx.x & 3) * 32;
  } else {
    g = z - 48; R = 128; Cd = 1024;
    in = op; out = pot;
    r0 = (blockIdx.x & 3) * 32; c0 = (blockIdx.x >> 2) * 32;
  }
  int tx = tid & 31, ty0 = tid >> 5;
  const float* src = in + (size_t)g * R * Cd;
  __bf16* dst = out + (size_t)g * R * Cd;
#pragma unroll
  for (int ty = ty0; ty < 32; ty += 8)
    tile[ty][tx] = src[(size_t)(r0 + ty) * Cd + (c0 + tx)];
  __syncthreads();
#pragma unroll
  for (int ty = ty0; ty < 32; ty += 8)
    dst[(size_t)(c0 + ty) * R + (r0 + tx)] = f2bf(tile[tx][ty]);
}

// ---------------- gating: 16 tokens/block (512 blocks), chunked LDS, f64 acc ----------------
// Per-block expert counts -> cntb (no global atomics). Also emits dense bf16 x.
__global__ __launch_bounds__(256, 2) void k_gating3(const float* __restrict__ x,
                                                    const float* __restrict__ sim,
                                                    const double* __restrict__ snorm,
                                                    const double* __restrict__ sig,
                                                    float* __restrict__ w_all,
                                                    int* __restrict__ cntb,
                                                    __bf16* __restrict__ xbf) {
  __shared__ union {
    struct {
      float xs_[16][66];    // [token][col-in-chunk]
      float ss_[16][66];    // [e][col-in-chunk]
    } s;
    double red[8][32][2][17];  // [tkg][cg][t][dot0..15,norm] = 69632 B
  } u;
  __shared__ float w_lds[16][16];
  __shared__ int cnt_lds[16];
  int tid = threadIdx.x;
  if (tid < 16) cnt_lds[tid] = 0;
  int cg = tid & 31, tkg = tid >> 5;
  int tok0 = blockIdx.x * 16;

  double acc[2][17];
#pragma unroll
  for (int t = 0; t < 2; t++)
#pragma unroll
    for (int i = 0; i < 17; i++) acc[t][i] = 0.0;

  // staging roles
  int xr0 = tid >> 4, xc4 = (tid & 15) * 4;   // x row xr0, 4 cols
  int sr = tid >> 2, se4 = (tid & 3) * 4;     // sim row c0+sr, 4 experts

  float4 xa, sv;
  auto ldchunk = [&](int c0) {
    xa = *(const float4*)(x + (size_t)(tok0 + xr0) * NC + c0 + xc4);
    sv = *(const float4*)(sim + (size_t)(c0 + sr) * NE + se4);
  };
  auto stchunk = [&]() {
    *(float4*)&u.s.xs_[xr0][xc4] = xa;
    u.s.ss_[se4 + 0][sr] = sv.x;
    u.s.ss_[se4 + 1][sr] = sv.y;
    u.s.ss_[se4 + 2][sr] = sv.z;
    u.s.ss_[se4 + 3][sr] = sv.w;
  };
  auto stxbf = [&](int c0) {   // dense bf16 emit (xa still live)
    bf16x4 a;
    a[0]=f2bf(xa.x); a[1]=f2bf(xa.y); a[2]=f2bf(xa.z); a[3]=f2bf(xa.w);
    *(bf16x4*)(xbf + (size_t)(tok0 + xr0) * NC + c0 + xc4) = a;
  };

  ldchunk(0);
  for (int ch = 0; ch < 16; ch++) {
    stchunk();
    stxbf(ch * 64);
    __syncthreads();
    if (ch < 15) ldchunk((ch + 1) * 64);   // prefetch next chunk into regs
    double xd[2][2];
#pragma unroll
    for (int t = 0; t < 2; t++) {
      float2 xv = *(const float2*)&u.s.xs_[tkg * 2 + t][cg * 2];
      xd[t][0] = (double)xv.x;
      xd[t][1] = (double)xv.y;
      acc[t][16] += xd[t][0] * xd[t][0] + xd[t][1] * xd[t][1];
    }
#pragma unroll
    for (int e = 0; e < 16; e++) {
      float2 sv2 = *(const float2*)&u.s.ss_[e][cg * 2];
      double s0 = (double)sv2.x, s1 = (double)sv2.y;
#pragma unroll
      for (int t = 0; t < 2; t++)
        acc[t][e] += xd[t][0] * s0 + xd[t][1] * s1;
    }
    __syncthreads();
  }

  // one-shot LDS reduce (xs_/ss_ dead; union'd)
#pragma unroll
  for (int t = 0; t < 2; t++)
#pragma unroll
    for (int i = 0; i < 17; i++)
      u.red[tkg][cg][t][i] = acc[t][i];
  __syncthreads();

  if (tid < 16) {
    double dots[17];
    for (int i = 0; i < 17; i++) {
      double s = 0.0;
      for (int c = 0; c < 32; c++) s += u.red[tid >> 1][c][tid & 1][i];
      dots[i] = s;
    }
    double xn = fmax(sqrt(dots[16]), 1e-12);
    double logits[NE];
    unsigned act = 0;
    int cnt = 0;
    for (int ee = 0; ee < NE; ee++) {
      logits[ee] = dots[ee] / (xn * snorm[ee]) - sig[ee];
      if (logits[ee] > 0.0) { act |= 1u << ee; cnt++; }
    }
    if (cnt == 0) {  // top-MIN_E(=2) fallback, lowest-index tie-break
      int i1 = 0; double b1 = logits[0];
      for (int ee = 1; ee < NE; ee++) if (logits[ee] > b1) { b1 = logits[ee]; i1 = ee; }
      int i2 = -1; double b2 = -1e300;
      for (int ee = 0; ee < NE; ee++) if (ee != i1 && logits[ee] > b2) { b2 = logits[ee]; i2 = ee; }
      act = (1u << i1) | (1u << i2);
    }
    double m = -1e300;
    for (int ee = 0; ee < NE; ee++) if ((act >> ee) & 1) m = fmax(m, fmax(logits[ee], 0.0));
    double s = 0.0, wvv[NE];
    for (int ee = 0; ee < NE; ee++) {
      if ((act >> ee) & 1) { wvv[ee] = exp(fmax(logits[ee], 0.0) - m); s += wvv[ee]; }
      else wvv[ee] = 0.0;
    }
    for (int ee = 0; ee < NE; ee++) {
      if ((act >> ee) & 1) {
        w_lds[tid][ee] = (float)(wvv[ee] / s);
        atomicAdd(&cnt_lds[ee], 1);
      } else w_lds[tid][ee] = 0.0f;
    }
  }
  __syncthreads();
  w_all[(size_t)(tok0 + (tid >> 4)) * NE + (tid & 15)] = w_lds[tid >> 4][tid & 15];
  if (tid < 16) cntb[blockIdx.x * 16 + tid] = cnt_lds[tid];
}

// ---------------- scan: reduce per-block counts -> offsets + 128-row tiles ----------------
__global__ void k_scan(const int* __restrict__ cntb, int* __restrict__ offsets,
                       int2* __restrict__ tile_desc, int* __restrict__ n_tiles,
                       int* __restrict__ cursors) {
  __shared__ int part[16][17];
  int tid = threadIdx.x;
  int e = tid & 15, pp = tid >> 4;
  int s = 0;
  for (int b = pp; b < 512; b += 16) s += cntb[b * 16 + e];
  part[pp][e] = s;
  __syncthreads();
  if (tid >= 16 && tid < 32) cursors[tid - 16] = 0;
  if (tid == 0) {
    int off = 0, nt = 0;
    for (int ee = 0; ee < NE; ee++) {
      int c = 0;
      for (int p = 0; p < 16; p++) c += part[p][ee];
      offsets[ee] = off;
      int tiles = (c + 127) >> 7;
      for (int t = 0; t < tiles; t++) {
        int s0 = off + t * 128;
        if (s0 < CAP && nt < NT2_MAX) { tile_desc[nt].x = ee; tile_desc[nt].y = s0; nt++; }
      }
      off += c;
    }
    offsets[NE] = off;
    *n_tiles = nt;
  }
}

// ------- slot assignment + token->slot inverse map (ballot-aggregated atomics) -------
__global__ void k_assign(const float* __restrict__ w_all, const int* __restrict__ offsets,
                         int* __restrict__ cursors, int* __restrict__ slot_token,
                         float* __restrict__ slot_w, int* __restrict__ tok_slots,
                         int* __restrict__ tok_cnt) {
  int n = blockIdx.x * 256 + threadIdx.x;   // grid exactly covers NTOK
  int lane = threadIdx.x & 63;
  int j = 0;
  for (int e = 0; e < NE; e++) {
    float w = w_all[(size_t)n * NE + e];
    bool a = w > 0.0f;
    unsigned long long mask = __ballot(a);
    if (mask) {
      int leader = (int)__ffsll((long long)mask) - 1;
      int base = 0;
      if (lane == leader) base = atomicAdd(&cursors[e], (int)__popcll(mask));
      base = __shfl(base, leader);
      if (a) {
        int pos = base + (int)__popcll(mask & ((1ULL << lane) - 1ULL));
        int s = offsets[e] + pos;
        slot_token[s] = n;
        slot_w[s] = w;
        tok_slots[n * 16 + j] = s;
        j++;
      }
    }
  }
  tok_cnt[n] = j;
}

// ---------------- MFMA tiles on XOR-swizzled LDS ----------------
// 64x128 (A rows 64): used by flash.
__device__ __forceinline__ void mfma_block(const __bf16* As, const __bf16* Bs,
                                           int lane, int wrow, f32x4 acc[8]) {
  const char* Ab = (const char*)As;
  const char* Bb = (const char*)Bs;
  int arow = wrow + (lane & 15);
  int rb = lane & 15;
#pragma unroll
  for (int ks = 0; ks < 2; ks++) {
    int kb = ks * 64 + (lane >> 4) * 16;   // byte offset within 128B row
    bf16x8 af = *(const bf16x8*)(Ab + arow * 128 + (kb ^ ((arow & 7) << 4)));
#pragma unroll
    for (int nt = 0; nt < 8; nt++) {
      int brow = nt * 16 + rb;
      bf16x8 bv = *(const bf16x8*)(Bb + brow * 128 + (kb ^ ((brow & 7) << 4)));
      acc[nt] = __builtin_amdgcn_mfma_f32_16x16x32_bf16(af, bv, acc[nt], 0, 0, 0);
    }
  }
}

// 128x128 (A rows 128, wave owns 32 A-rows): grouped GEMMs.
__device__ __forceinline__ void mfma_block128(const __bf16* As, const __bf16* Bs,
                                              int lane, int wrow2, f32x4 acc[2][8]) {
  const char* Ab = (const char*)As;
  const char* Bb = (const char*)Bs;
  int rb = lane & 15;
#pragma unroll
  for (int ks = 0; ks < 2; ks++) {
    int kb = ks * 64 + (lane >> 4) * 16;
    int ar = wrow2 + rb;                   // (ar&7) == ((ar+16)&7)
    int sw = kb ^ ((ar & 7) << 4);
    bf16x8 af0 = *(const bf16x8*)(Ab + ar * 128 + sw);
    bf16x8 af1 = *(const bf16x8*)(Ab + (ar + 16) * 128 + sw);
#pragma unroll
    for (int nt = 0; nt < 8; nt++) {
      int brow = nt * 16 + rb;
      bf16x8 bv = *(const bf16x8*)(Bb + brow * 128 + (kb ^ ((brow & 7) << 4)));
      acc[0][nt] = __builtin_amdgcn_mfma_f32_16x16x32_bf16(af0, bv, acc[0][nt], 0, 0, 0);
      acc[1][nt] = __builtin_amdgcn_mfma_f32_16x16x32_bf16(af1, bv, acc[1][nt], 0, 0, 0);
    }
  }
}

// A-operand from registers (Q frags), B from swizzled LDS
__device__ __forceinline__ void mfma_regA(bf16x8 af0, bf16x8 af1, const __bf16* Bs,
                                          int lane, f32x4 acc[8]) {
  const char* Bb = (const char*)Bs;
  int rb = lane & 15;
#pragma unroll
  for (int ks = 0; ks < 2; ks++) {
    int kb = ks * 64 + (lane >> 4) * 16;
    bf16x8 af = ks ? af1 : af0;
#pragma unroll
    for (int nt = 0; nt < 8; nt++) {
      int brow = nt * 16 + rb;
      bf16x8 bv = *(const bf16x8*)(Bb + brow * 128 + (kb ^ ((brow & 7) << 4)));
      acc[nt] = __builtin_amdgcn_mfma_f32_16x16x32_bf16(af, bv, acc[nt], 0, 0, 0);
    }
  }
}

// ------- grouped GEMM: QKV projections, BM=128, indirect A-gather, counted vmcnt -------
__global__ __launch_bounds__(256) void k_moe_qkv2(
    const __bf16* __restrict__ xbf, const int* __restrict__ slot_token,
    const __bf16* __restrict__ pq, const __bf16* __restrict__ pk, const __bf16* __restrict__ pv,
    const int* __restrict__ offsets, const int2* __restrict__ tile_desc,
    const int* __restrict__ n_tiles,
    __bf16* __restrict__ yq, __bf16* __restrict__ yk, __bf16* __restrict__ yv) {
  int id = blockIdx.x;
  int w = (id & 7) * (3 * NT2_MAX / 8) + (id >> 3);  // chunked bijective (456)
  int ti = w / 3, p = w % 3;
  if (ti >= *n_tiles) return;
  int2 td = tile_desc[ti];
  int e = td.x, s0 = td.y;
  int seg_end = offsets[e + 1]; if (seg_end > CAP) seg_end = CAP;
  const __bf16* Bt;
  __bf16* Yd;
  if (p == 0)      { Bt = pq; Yd = yq; }
  else if (p == 1) { Bt = pk; Yd = yk; }
  else             { Bt = pv; Yd = yv; }
  Bt += (size_t)e * NH * NC;

  __shared__ __bf16 As[2][128 * 64];
  __shared__ __bf16 Bs[2][128 * 64];
  int tid = threadIdx.x, lane = tid & 63, wid = tid >> 6, wrow2 = wid * 32;
  // per-lane indirect A source: row r of tile -> token slot_token[s0+r]
  const __bf16* asrc[4];
  const __bf16* bsrc[4];
#pragma unroll
  for (int i = 0; i < 4; i++) {
    int lin = (tid + 256 * i) * 16;
    int r = lin >> 7, cb = lin & 127;
    int tok = slot_token[s0 + r] & (NTOK - 1);   // mask poisoned tails
    asrc[i] = xbf + (size_t)tok * NC + ((cb ^ ((r & 7) << 4)) >> 1);
  }
#pragma unroll
  for (int i = 0; i < 4; i++) bsrc[i] = swz_src(Bt, NC, tid, i);
  auto stage = [&](int buf, int k0) {
#pragma unroll
    for (int i = 0; i < 4; i++)
      gl_lds16(asrc[i] + k0, (char*)As[buf] + tid * 16 + i * 4096);
#pragma unroll
    for (int i = 0; i < 4; i++)
      gl_lds16(bsrc[i] + k0, (char*)Bs[buf] + tid * 16 + i * 4096);
  };

  f32x4 acc[2][8];
#pragma unroll
  for (int rf = 0; rf < 2; rf++)
#pragma unroll
    for (int i = 0; i < 8; i++) { f32x4 z = {0.f, 0.f, 0.f, 0.f}; acc[rf][i] = z; }

  // 16 K-steps, 2 LDS buffers, 2 tiles (16 loads/wave) always in flight.
  stage(0, 0);
  stage(1, 64);
  VMWAIT(8); BARRIER(); SFENCE();        // tile 0 resident everywhere
  int cur = 0;
  for (int t = 0; t <= 13; t++) {        // compute tile t; stage tile t+2
    __builtin_amdgcn_s_setprio(1);
    mfma_block128(As[cur], Bs[cur], lane, wrow2, acc);
    __builtin_amdgcn_s_setprio(0);
    SFENCE();
    BARRIER();                           // all waves done reading buf[cur]
    stage(cur, (t + 2) * 64);            // overwrite buf[cur] with tile t+2
    VMWAIT(8); BARRIER(); SFENCE();      // tile t+1 resident everywhere
    cur ^= 1;
  }
  __builtin_amdgcn_s_setprio(1);
  mfma_block128(As[cur], Bs[cur], lane, wrow2, acc);      // tile 14
  __builtin_amdgcn_s_setprio(0);
  SFENCE();
  VMWAIT(0); BARRIER(); SFENCE();                         // tile 15 resident
  __builtin_amdgcn_s_setprio(1);
  mfma_block128(As[cur ^ 1], Bs[cur ^ 1], lane, wrow2, acc);  // tile 15
  __builtin_amdgcn_s_setprio(0);

  int col = lane & 15, quad = lane >> 4;
#pragma unroll
  for (int rf = 0; rf < 2; rf++)
#pragma unroll
    for (int r = 0; r < 4; r++) {
      int s = s0 + wrow2 + rf * 16 + quad * 4 + r;
      if (s < seg_end) {
#pragma unroll
        for (int nt = 0; nt < 8; nt++)
          Yd[(size_t)s * NH + nt * 16 + col] = f2bf(acc[rf][nt][r]);
      }
    }
}

// ------- combine Y slots -> token-major bf16 q/k + direct V^T (fused transpose) -------
// Q is pre-scaled by scale*log2(e) so flash works in exp2 domain.
__global__ __launch_bounds__(256) void k_combine_qkv(
    const __bf16* __restrict__ yq, const __bf16* __restrict__ yk, const __bf16* __restrict__ yv,
    const int* __restrict__ tok_slots, const int* __restrict__ tok_cnt,
    const float* __restrict__ slot_w,
    __bf16* __restrict__ qb, __bf16* __restrict__ kb, __bf16* __restrict__ vt) {
  __shared__ __bf16 vtile[128][34];
  int tid = threadIdx.x;
  int tok0 = blockIdx.x * 32;
  int tt = tok0 + (tid >> 3);
  int h0 = (tid & 7) * 16;
  const __bf16* Y = blockIdx.y == 0 ? yq : (blockIdx.y == 1 ? yk : yv);
  int cnt = tok_cnt[tt];
  float acc[16];
#pragma unroll
  for (int i = 0; i < 16; i++) acc[i] = 0.f;
  for (int j = 0; j < cnt; j++) {
    int s = tok_slots[tt * 16 + j];
    if (s < CAP) {
      float w = slot_w[s];
      bf16x8 v0 = *(const bf16x8*)(Y + (size_t)s * NH + h0);
      bf16x8 v1 = *(const bf16x8*)(Y + (size_t)s * NH + h0 + 8);
#pragma unroll
      for (int i = 0; i < 8; i++) { acc[i] += w * (float)v0[i]; acc[8 + i] += w * (float)v1[i]; }
    }
  }
  if (blockIdx.y == 2) {
    // V: LDS transpose tile [h][t], write VT [b][h][t] coalesced
#pragma unroll
    for (int i = 0; i < 16; i++) vtile[h0 + i][tid >> 3] = f2bf(acc[i]);
    __syncthreads();
    int h = tid >> 1, tp = (tid & 1) * 16;
    int b = tok0 >> 11, trow = tok0 & 2047;
    __bf16* dst = vt + ((size_t)b * NH + h) * NT + trow + tp;
    bf16x8 o0, o1;
#pragma unroll
    for (int i = 0; i < 8; i++) { o0[i] = vtile[h][tp + i]; o1[i] = vtile[h][tp + 8 + i]; }
    *(bf16x8*)dst = o0;
    *(bf16x8*)(dst + 8) = o1;
  } else {
    float sc = blockIdx.y == 0 ? 0.12751744458115337f : 1.0f;  // (1/sqrt(128))*log2(e)
    __bf16* D = blockIdx.y == 0 ? qb : kb;
    bf16x8 o0, o1;
#pragma unroll
    for (int i = 0; i < 8; i++) { o0[i] = f2bf(acc[i] * sc); o1[i] = f2bf(acc[8 + i] * sc); }
    __bf16* d = D + (size_t)tt * NH + h0;
    *(bf16x8*)d = o0;
    *(bf16x8*)(d + 8) = o1;
  }
}

// ---------------- flash attention: QK^T -> exp2-domain online softmax -> PV ----------------
// grid 512 = 4 b x 4 splits x 32 t-blocks (XCD-chunked). LDS: K 32K + V 32K + P 16K.
__global__ __launch_bounds__(256) void k_flash(const __bf16* __restrict__ q,
                                               const __bf16* __restrict__ k,
                                               const __bf16* __restrict__ vt,
                                               float* __restrict__ opart,
                                               float2* __restrict__ ml) {
  int id = blockIdx.x;
  int w = (id & 7) * 64 + (id >> 3);     // chunked bijective over 512
  int b = w >> 7;
  int rem = w & 127;
  int spl = rem >> 5;
  int t0 = (rem & 31) * 64;
  const __bf16* qb = q + (size_t)b * NT * NH;
  const __bf16* kb = k + (size_t)b * NT * NH;
  const __bf16* vtb = vt + (size_t)b * NH * NT;

  __shared__ __bf16 Ks[2][128 * 64];   // [d-chunk][s-row][64]
  __shared__ __bf16 Vs[2][128 * 64];   // [s-chunk][d-row][64]
  __shared__ __bf16 Ps[2][64 * 64];    // [s-chunk][t-row][64]
  int tid = threadIdx.x, lane = tid & 63, wid = tid >> 6, wrow = wid * 16;
  int colq = lane & 15, quad = lane >> 4;

  // Q fragments in registers (force-resolved before staging starts)
  bf16x8 qf[4];
  {
    const __bf16* qr = qb + (size_t)(t0 + wrow + colq) * NH + quad * 8;
#pragma unroll
    for (int kk = 0; kk < 4; kk++) qf[kk] = *(const bf16x8*)(qr + kk * 32);
  }
  asm volatile("" :: "v"(qf[0]), "v"(qf[1]), "v"(qf[2]), "v"(qf[3]));
  SFENCE();

  auto stage_K = [&](int s0) {
#pragma unroll
    for (int c = 0; c < 2; c++)
#pragma unroll
      for (int i = 0; i < 4; i++)
        gl_lds16(swz_src(kb + (size_t)s0 * NH + c * 64, NH, tid, i),
                 (char*)Ks[c] + wid * 1024 + i * 4096);
  };
  auto stage_V = [&](int s0) {
#pragma unroll
    for (int c = 0; c < 2; c++)
#pragma unroll
      for (int i = 0; i < 4; i++)
        gl_lds16(swz_src(vtb + s0 + c * 64, NT, tid, i),
                 (char*)Vs[c] + wid * 1024 + i * 4096);
  };

  f32x4 oacc[8];
#pragma unroll
  for (int i = 0; i < 8; i++) { f32x4 z = {0.f, 0.f, 0.f, 0.f}; oacc[i] = z; }
  float mr[4], lr[4];
#pragma unroll
  for (int r = 0; r < 4; r++) { mr[r] = -1e30f; lr[r] = 0.f; }

  const int sbase = spl * 512;
  stage_K(sbase);
  stage_V(sbase);
  VMWAIT(8); BARRIER(); SFENCE();        // K(0) resident; V(0) 8 loads in flight

  for (int t = 0; t < 4; t++) {
    // ---- QK^T for s-tile t (already in log2 domain via pre-scaled Q) ----
    f32x4 sacc[8];
#pragma unroll
    for (int i = 0; i < 8; i++) { f32x4 z = {0.f, 0.f, 0.f, 0.f}; sacc[i] = z; }
    __builtin_amdgcn_s_setprio(1);
    mfma_regA(qf[0], qf[1], Ks[0], lane, sacc);
    mfma_regA(qf[2], qf[3], Ks[1], lane, sacc);
    __builtin_amdgcn_s_setprio(0);
    SFENCE();
    BARRIER();                           // all waves done reading Ks
    if (t < 3) stage_K(sbase + (t + 1) * 128);   // +8 in flight

    // ---- online softmax (base 2); P -> LDS (own wave's rows only) ----
    float tm[4];
#pragma unroll
    for (int r = 0; r < 4; r++) {
      float v = sacc[0][r];
#pragma unroll
      for (int nt = 1; nt < 8; nt++) v = fmaxf(v, sacc[nt][r]);
      tm[r] = v;
    }
#pragma unroll
    for (int off = 1; off < 16; off <<= 1)
#pragma unroll
      for (int r = 0; r < 4; r++) tm[r] = fmaxf(tm[r], __shfl_xor(tm[r], off));
    float alpha[4], rs[4];
#pragma unroll
    for (int r = 0; r < 4; r++) {
      float mn = fmaxf(mr[r], tm[r]);
      alpha[r] = exp2f(mr[r] - mn);
      mr[r] = mn;
      rs[r] = 0.f;
    }
#pragma unroll
    for (int nt = 0; nt < 8; nt++) {
      char* pc = (char*)Ps[nt >> 2];
      int colb = ((nt & 3) * 16 + colq) * 2;
#pragma unroll
      for (int r = 0; r < 4; r++) {
        int row = wrow + quad * 4 + r;
        float p = exp2f(sacc[nt][r] - mr[r]);
        rs[r] += p;
        *(__bf16*)(pc + row * 128 + (colb ^ ((row & 7) << 4))) = f2bf(p);
      }
    }
#pragma unroll
    for (int off = 1; off < 16; off <<= 1)
#pragma unroll
      for (int r = 0; r < 4; r++) rs[r] += __shfl_xor(rs[r], off);
#pragma unroll
    for (int r = 0; r < 4; r++) lr[r] = alpha[r] * lr[r] + rs[r];
#pragma unroll
    for (int nt = 0; nt < 8; nt++)
#pragma unroll
      for (int r = 0; r < 4; r++) oacc[nt][r] *= alpha[r];

    LGKMWAIT0();                         // P writes done
    if (t < 3) { VMWAIT(8); } else { VMWAIT(0); }   // V(t) resident (own loads)
    BARRIER(); SFENCE();                 // everyone's V(t) + P ready

    // ---- PV ----
    __builtin_amdgcn_s_setprio(1);
    mfma_block(Ps[0], Vs[0], lane, wrow, oacc);
    mfma_block(Ps[1], Vs[1], lane, wrow, oacc);
    __builtin_amdgcn_s_setprio(0);
    SFENCE();
    BARRIER();                           // all done reading Vs, Ps
    if (t < 3) {
      stage_V(sbase + (t + 1) * 128);    // +8 -> 16 in flight
      VMWAIT(8); BARRIER(); SFENCE();    // K(t+1) resident
    }
  }

  // epilogue: unnormalized partial O + (m,l) in log2 domain
  size_t base = (size_t)(b * 4 + spl) * NT + t0;
#pragma unroll
  for (int r = 0; r < 4; r++) {
    size_t row = base + wrow + quad * 4 + r;
#pragma unroll
    for (int nt = 0; nt < 8; nt++)
      opart[row * NH + nt * 16 + colq] = oacc[nt][r];
  }
  if (colq == 0) {
#pragma unroll
    for (int r = 0; r < 4; r++) {
      float2 v; v.x = mr[r]; v.y = lr[r];
      ml[base + wrow + quad * 4 + r] = v;
    }
  }
}

// ---------------- gather o: merge 4 split partials (base-2 LSE) -> slot-major bf16 ----------------
__global__ __launch_bounds__(256) void k_gather_o(const float* __restrict__ opart,
                                                  const float2* __restrict__ ml,
                                                  const int* __restrict__ slot_token,
                                                  const int* __restrict__ offsets,
                                                  __bf16* __restrict__ og) {
  int slot = blockIdx.x * 2 + (threadIdx.x >> 7);
  int h = threadIdx.x & 127;
  int total = offsets[NE]; if (total > CAP) total = CAP;
  if (slot >= total) return;
  int n = slot_token[slot];
  int b = n >> 11, trow = n & 2047;
  size_t rb = (size_t)b * 4 * NT + trow;
  float2 m0 = ml[rb], m1 = ml[rb + NT], m2 = ml[rb + 2 * NT], m3 = ml[rb + 3 * NT];
  float M = fmaxf(fmaxf(m0.x, m1.x), fmaxf(m2.x, m3.x));
  float e0 = exp2f(m0.x - M), e1 = exp2f(m1.x - M), e2 = exp2f(m2.x - M), e3 = exp2f(m3.x - M);
  float den = m0.y * e0 + m1.y * e1 + m2.y * e2 + m3.y * e3;
  float num = opart[rb * NH + h] * e0 + opart[(rb + NT) * NH + h] * e1 +
              opart[(rb + 2 * NT) * NH + h] * e2 + opart[(rb + 3 * NT) * NH + h] * e3;
  og[(size_t)slot * NH + h] = f2bf(num / den);
}

// ------- grouped GEMM: out-proj, BM=128, 2 N-chunks/block (A staged once) -------
__global__ __launch_bounds__(256) void k_out2(
    const __bf16* __restrict__ og, const __bf16* __restrict__ pot,
    const int* __restrict__ offsets, const int2* __restrict__ tile_desc,
    const int* __restrict__ n_tiles, __bf16* __restrict__ zy) {
  int id = blockIdx.x;
  int w = (id & 7) * (4 * NT2_MAX / 8) + (id >> 3);  // chunked bijective (608)
  int ti = w >> 2, p = w & 3;                        // p = 256-wide nc chunk 0..3
  if (ti >= *n_tiles) return;
  int2 td = tile_desc[ti];
  int e = td.x, s0 = td.y;
  int seg_end = offsets[e + 1]; if (seg_end > CAP) seg_end = CAP;
  int nc0 = p * 256;
  const __bf16* Bt = pot + (size_t)e * NC * NH;

  __shared__ __bf16 As[2][128 * 64];
  __shared__ __bf16 Bs[2][128 * 64];
  int tid = threadIdx.x, lane = tid & 63, wid = tid >> 6, wrow2 = wid * 32;
  const __bf16* asrc[4];
  const __bf16* bsrc[4];
#pragma unroll
  for (int i = 0; i < 4; i++) asrc[i] = swz_src(og + (size_t)s0 * NH, NH, tid, i);
#pragma unroll
  for (int i = 0; i < 4; i++) bsrc[i] = swz_src(Bt + (size_t)nc0 * NH, NH, tid, i);
  auto stageA = [&](int buf, int k0) {
#pragma unroll
    for (int i = 0; i < 4; i++)
      gl_lds16(asrc[i] + k0, (char*)As[buf] + tid * 16 + i * 4096);
  };
  auto stageB = [&](int buf, int k0, int noff) {
#pragma unroll
    for (int i = 0; i < 4; i++)
      gl_lds16(bsrc[i] + (size_t)noff * NH + k0, (char*)Bs[buf] + tid * 16 + i * 4096);
  };
  f32x4 acc[2][8];
  int col = lane & 15, quad = lane >> 4;
  auto store_acc = [&](int nco) {
#pragma unroll
    for (int rf = 0; rf < 2; rf++)
#pragma unroll
      for (int r = 0; r < 4; r++) {
        int s = s0 + wrow2 + rf * 16 + quad * 4 + r;
        if (s < seg_end) {
#pragma unroll
          for (int nt = 0; nt < 8; nt++)
            zy[(size_t)s * NC + nco + nt * 16 + col] = f2bf(acc[rf][nt][r]);
        }
      }
  };

#pragma unroll
  for (int rf = 0; rf < 2; rf++)
#pragma unroll
    for (int i = 0; i < 8; i++) { f32x4 z = {0.f, 0.f, 0.f, 0.f}; acc[rf][i] = z; }

  // A (full K=128) staged once; B re-staged per 128-wide n-chunk.
  stageA(0, 0); stageB(0, 0, 0);        // first 8: As[0] + Bs[0] (chunk 0)
  stageA(1, 64); stageB(1, 64, 0);
  VMWAIT(8); BARRIER(); SFENCE();
  __builtin_amdgcn_s_setprio(1);
  mfma_block128(As[0], Bs[0], lane, wrow2, acc);
  __builtin_amdgcn_s_setprio(0);
  SFENCE();
  VMWAIT(0); BARRIER(); SFENCE();
  __builtin_amdgcn_s_setprio(1);
  mfma_block128(As[1], Bs[1], lane, wrow2, acc);
  __builtin_amdgcn_s_setprio(0);
  SFENCE();
  store_acc(nc0);
  BARRIER();                            // all waves done reading Bs
  stageB(0, 0, 128); stageB(1, 64, 128);   // B for chunk 1; As untouched
#pragma unroll
  for (int rf = 0; rf < 2; rf++)
#pragma unroll
    for (int i = 0; i < 8; i++) { f32x4 z = {0.f, 0.f, 0.f, 0.f}; acc[rf][i] = z; }
  VMWAIT(0); BARRIER(); SFENCE();
  __builtin_amdgcn_s_setprio(1);
  mfma_block128(As[0], Bs[0], lane, wrow2, acc);
  mfma_block128(As[1], Bs[1], lane, wrow2, acc);
  __builtin_amdgcn_s_setprio(0);
  store_acc(nc0 + 128);
}

// ---------------- combine ZY slots -> dense fp32 out ----------------
__global__ __launch_bounds__(256) void k_combine_out(
    const __bf16* __restrict__ zy, const int* __restrict__ tok_slots,
    const int* __restrict__ tok_cnt, const float* __restrict__ slot_w,
    float* __restrict__ out) {
  int token = blockIdx.x;
  int c = threadIdx.x * 4;
  int cnt = tok_cnt[token];
  float a0 = 0.f, a1 = 0.f, a2 = 0.f, a3 = 0.f;
  for (int j = 0; j < cnt; j++) {
    int s = tok_slots[token * 16 + j];
    if (s < CAP) {
      float w = slot_w[s];
      bf16x4 z = *(const bf16x4*)&zy[(size_t)s * NC + c];
      a0 += w * (float)z[0];
      a1 += w * (float)z[1];
      a2 += w * (float)z[2];
      a3 += w * (float)z[3];
    }
  }
  float4 o = {a0, a1, a2, a3};
  *(float4*)&out[(size_t)token * NC + c] = o;
}

extern "C" void kernel_launch(void* const* d_in, const int* in_sizes, int n_in,
                              void* d_out, int out_size, void* d_ws, size_t ws_size,
                              hipStream_t stream) {
  const float* hs    = (const float*)d_in[0];  // [4,2048,1024]
  const float* sim   = (const float*)d_in[1];  // [1024,16]
  const float* gates = (const float*)d_in[2];  // [16]
  const float* qp    = (const float*)d_in[3];  // [16,1024,128]
  const float* kp    = (const float*)d_in[4];
  const float* vp    = (const float*)d_in[5];
  const float* op    = (const float*)d_in[6];  // [16,128,1024]
  float* out = (float*)d_out;
  char* ws = (char*)d_ws;

  // ---- workspace arena (aliased by lifetime) ----
  const size_t M = 1048576;
  __bf16* PQT = (__bf16*)(ws + 0 * M);         // 4 MiB each
  __bf16* PKT = (__bf16*)(ws + 4 * M);
  __bf16* PVT = (__bf16*)(ws + 8 * M);
  __bf16* POT = (__bf16*)(ws + 12 * M);
  __bf16* Qb  = (__bf16*)(ws + 16 * M);        // 2 MiB each, token-major bf16
  __bf16* Kb  = (__bf16*)(ws + 18 * M);
  __bf16* VT  = (__bf16*)(ws + 22 * M);        // 2 MiB [b][h][t]
  int*    CNTB = (int*)(ws + 27 * M);          // 32 KiB per-block gating counts
  float*  WALL = (float*)(ws + 28 * M);        // 512 KiB
  int*    STOK = (int*)(ws + 28 * M + 524288); // 512 KiB
  float*  SW   = (float*)(ws + 28 * M + 1048576);
  int*    TSL  = (int*)(ws + 28 * M + 1572864);  // tok_slots 512 KiB
  int*    TCN  = (int*)(ws + 28 * M + 2097152);  // tok_cnt 32 KiB
  double* SNORM = (double*)(ws + 28 * M + 2129920);
  double* SIG   = SNORM + 16;
  int* CNT = (int*)(ws + 28 * M + 2130432);    // control block
  int* OFF = CNT + 16;
  int* CUR = CNT + 40;
  int* NTL = CNT + 60;
  int2* DESC = (int2*)(ws + 28 * M + 2131456);
  // R region (32M..96M), aliased by lifetime:
  __bf16* XBF = (__bf16*)(ws + 32 * M);        // 16.8 MiB dense bf16 x (dies after qkv2)
  __bf16* YQ = (__bf16*)(ws + 72 * M);         // 4.5 MiB each (die before flash)
  __bf16* YK = (__bf16*)(ws + 77 * M);
  __bf16* YV = (__bf16*)(ws + 82 * M);
  float*  OP2 = (float*)(ws + 32 * M);         // 16.8 MiB partial O (after XBF dead)
  float2* MLB = (float2*)(ws + 50 * M);        // 256 KiB (m,l) per split-row
  __bf16* OG = (__bf16*)(ws + 52 * M);         // 4.5 MiB
  __bf16* ZY = (__bf16*)(ws + 60 * M);         // 36.1 MiB

  k_transpose_all<<<dim3(128, 65), 256, 0, stream>>>(qp, kp, vp, op, PQT, PKT, PVT, POT,
                                                     sim, gates, SNORM, SIG);
  k_gating3<<<NTOK / 16, 256, 0, stream>>>(hs, sim, SNORM, SIG, WALL, CNTB, XBF);
  k_scan<<<1, 256, 0, stream>>>(CNTB, OFF, DESC, NTL, CUR);
  k_assign<<<NTOK / 256, 256, 0, stream>>>(WALL, OFF, CUR, STOK, SW, TSL, TCN);
  k_moe_qkv2<<<3 * NT2_MAX, 256, 0, stream>>>(XBF, STOK, PQT, PKT, PVT, OFF, DESC, NTL, YQ, YK, YV);
  k_combine_qkv<<<dim3(NTOK / 32, 3), 256, 0, stream>>>(YQ, YK, YV, TSL, TCN, SW, Qb, Kb, VT);
  k_flash<<<512, 256, 0, stream>>>(Qb, Kb, VT, OP2, MLB);
  k_gather_o<<<CAP / 2, 256, 0, stream>>>(OP2, MLB, STOK, OFF, OG);
  k_out2<<<4 * NT2_MAX, 256, 0, stream>>>(OG, POT, OFF, DESC, NTL, ZY);
  k_combine_out<<<NTOK, 256, 0, stream>>>(ZY, TSL, TCN, SW, out);
}

// Round 12
// 276.025 us; speedup vs baseline: 1.3463x; 1.1209x over previous
//
#include <hip/hip_runtime.h>
#include <hip/hip_bf16.h>
#include <math.h>

// DynSMHA: B=4 T=2048 C=1024 H=128 E=16 MIN_E=2, non-causal.
// weight transposes + prep (+ctrl zero) -> fp64 gating (16 tok/block, atomic
// counts, emits dense bf16 x) -> serial scan -> ballot-aggregated slot assign ->
// grouped GEMMs (BM=128, indirect A-gather, counted-vmcnt, XOR-swizzled LDS) ->
// flash attention (exp2-domain online softmax, split-s LSE) -> combines.
#define NBATCH 4
#define NT     2048
#define NC     1024
#define NH     128
#define NE     16
#define NTOK   (NBATCH * NT)
#define CAP    18432         // slot capacity (actual ~16384)
#define NT2_MAX 152          // sum ceil(cnt_e/128) + slack; multiple of 8

typedef __bf16 bf16x8 __attribute__((ext_vector_type(8)));
typedef __bf16 bf16x4 __attribute__((ext_vector_type(4)));
typedef float  f32x4  __attribute__((ext_vector_type(4)));

__device__ __forceinline__ __bf16 f2bf(float f) { return (__bf16)f; }

#define BARRIER() __builtin_amdgcn_s_barrier()
#define SFENCE()  __builtin_amdgcn_sched_barrier(0)
#define VMWAIT(n) asm volatile("s_waitcnt vmcnt(" #n ")" ::: "memory")
#define LGKMWAIT0() asm volatile("s_waitcnt lgkmcnt(0)" ::: "memory")

// async global->LDS, 16B per lane; LDS dest = wave-uniform base + lane*16
__device__ __forceinline__ void gl_lds16(const void* g, void* l) {
  __builtin_amdgcn_global_load_lds((const __attribute__((address_space(1))) void*)g,
                                   (__attribute__((address_space(3))) void*)l, 16, 0, 0);
}

// Pre-swizzled global source (swizzle BOTH sides or neither).
// LDS tile is [rows][64] bf16, linear 128B rows; swizzle byte ^= ((row&7)<<4).
__device__ __forceinline__ const __bf16* swz_src(const __bf16* row0, size_t stride,
                                                 int tid, int i) {
  int lin = (tid + 256 * i) * 16;
  int r = lin >> 7, cb = lin & 127;
  return row0 + (size_t)r * stride + ((cb ^ ((r & 7) << 4)) >> 1);
}

// ------- fused: weight transposes (fp32->bf16) + sim-norm/sigmoid prep + ctrl zero -------
__global__ void k_transpose_all(const float* __restrict__ qp, const float* __restrict__ kp,
                                const float* __restrict__ vp, const float* __restrict__ op,
                                __bf16* __restrict__ pqt, __bf16* __restrict__ pkt,
                                __bf16* __restrict__ pvt, __bf16* __restrict__ pot,
                                const float* __restrict__ sim, const float* __restrict__ gates,
                                double* __restrict__ snorm, double* __restrict__ sig,
                                int* __restrict__ ctrl) {
  __shared__ float tile[32][33];
  __shared__ double red[16][17];
  int z = blockIdx.y;
  int tid = threadIdx.x;
  if (z == 64) {                          // prep block
    if (blockIdx.x != 0) return;
    if (tid < 128) ctrl[tid] = 0;         // zero CNT/OFF/CUR/NTL
    int e = tid & 15, chunk = tid >> 4;
    double a = 0.0;
#pragma unroll 4
    for (int j = 0; j < 64; j++) {
      double v = (double)sim[(chunk * 64 + j) * NE + e];
      a += v * v;
    }
    red[chunk][e] = a;
    __syncthreads();
    if (tid < 16) {
      double s = 0.0;
      for (int k = 0; k < 16; k++) s += red[k][tid];
      snorm[tid] = fmax(sqrt(s), 1e-12);
      sig[tid] = 1.0 / (1.0 + exp(-(double)gates[tid]));
    }
    return;
  }
  const float* in;
  __bf16* out;
  int R, Cd, g, r0, c0;
  if (z < 48) {
    int which = z >> 4; g = z & 15; R = 1024; Cd = 128;
    in = which == 0 ? qp : (which == 1 ? kp : vp);
    out = which == 0 ? pqt : (which == 1 ? pkt : pvt);
    r0 = (blockIdx.x >> 2) * 32; c0 = (blockIdx.x & 3) * 32;
  } else {
    g = z - 48; R = 128; Cd = 1024;
    in = op; out = pot;
    r0 = (blockIdx.x & 3) * 32; c0 = (blockIdx.x >> 2) * 32;
  }
  int tx = tid & 31, ty0 = tid >> 5;
  const float* src = in + (size_t)g * R * Cd;
  __bf16* dst = out + (size_t)g * R * Cd;
#pragma unroll
  for (int ty = ty0; ty < 32; ty += 8)
    tile[ty][tx] = src[(size_t)(r0 + ty) * Cd + (c0 + tx)];
  __syncthreads();
#pragma unroll
  for (int ty = ty0; ty < 32; ty += 8)
    dst[(size_t)(c0 + ty) * R + (r0 + tx)] = f2bf(tile[tx][ty]);
}

// ---------------- gating: 16 tokens/block (512 blocks), chunked LDS, f64 acc ----------------
// Global atomic counts (wave-coalesced, 16 addresses). Also emits dense bf16 x.
__global__ __launch_bounds__(256, 2) void k_gating3(const float* __restrict__ x,
                                                    const float* __restrict__ sim,
                                                    const double* __restrict__ snorm,
                                                    const double* __restrict__ sig,
                                                    float* __restrict__ w_all,
                                                    int* __restrict__ counts,
                                                    __bf16* __restrict__ xbf) {
  __shared__ union {
    struct {
      float xs_[16][66];    // [token][col-in-chunk]
      float ss_[16][66];    // [e][col-in-chunk]
    } s;
    double red[8][32][2][17];  // [tkg][cg][t][dot0..15,norm] = 69632 B
  } u;
  __shared__ float w_lds[16][16];
  __shared__ int cnt_lds[16];
  int tid = threadIdx.x;
  if (tid < 16) cnt_lds[tid] = 0;
  int cg = tid & 31, tkg = tid >> 5;
  int tok0 = blockIdx.x * 16;

  double acc[2][17];
#pragma unroll
  for (int t = 0; t < 2; t++)
#pragma unroll
    for (int i = 0; i < 17; i++) acc[t][i] = 0.0;

  // staging roles
  int xr0 = tid >> 4, xc4 = (tid & 15) * 4;   // x row xr0, 4 cols
  int sr = tid >> 2, se4 = (tid & 3) * 4;     // sim row c0+sr, 4 experts

  float4 xa, sv;
  auto ldchunk = [&](int c0) {
    xa = *(const float4*)(x + (size_t)(tok0 + xr0) * NC + c0 + xc4);
    sv = *(const float4*)(sim + (size_t)(c0 + sr) * NE + se4);
  };
  auto stchunk = [&]() {
    *(float4*)&u.s.xs_[xr0][xc4] = xa;
    u.s.ss_[se4 + 0][sr] = sv.x;
    u.s.ss_[se4 + 1][sr] = sv.y;
    u.s.ss_[se4 + 2][sr] = sv.z;
    u.s.ss_[se4 + 3][sr] = sv.w;
  };
  auto stxbf = [&](int c0) {   // dense bf16 emit (xa still live)
    bf16x4 a;
    a[0]=f2bf(xa.x); a[1]=f2bf(xa.y); a[2]=f2bf(xa.z); a[3]=f2bf(xa.w);
    *(bf16x4*)(xbf + (size_t)(tok0 + xr0) * NC + c0 + xc4) = a;
  };

  ldchunk(0);
  for (int ch = 0; ch < 16; ch++) {
    stchunk();
    stxbf(ch * 64);
    __syncthreads();
    if (ch < 15) ldchunk((ch + 1) * 64);   // prefetch next chunk into regs
    double xd[2][2];
#pragma unroll
    for (int t = 0; t < 2; t++) {
      float2 xv = *(const float2*)&u.s.xs_[tkg * 2 + t][cg * 2];
      xd[t][0] = (double)xv.x;
      xd[t][1] = (double)xv.y;
      acc[t][16] += xd[t][0] * xd[t][0] + xd[t][1] * xd[t][1];
    }
#pragma unroll
    for (int e = 0; e < 16; e++) {
      float2 sv2 = *(const float2*)&u.s.ss_[e][cg * 2];
      double s0 = (double)sv2.x, s1 = (double)sv2.y;
#pragma unroll
      for (int t = 0; t < 2; t++)
        acc[t][e] += xd[t][0] * s0 + xd[t][1] * s1;
    }
    __syncthreads();
  }

  // one-shot LDS reduce (xs_/ss_ dead; union'd)
#pragma unroll
  for (int t = 0; t < 2; t++)
#pragma unroll
    for (int i = 0; i < 17; i++)
      u.red[tkg][cg][t][i] = acc[t][i];
  __syncthreads();

  if (tid < 16) {
    double dots[17];
    for (int i = 0; i < 17; i++) {
      double s = 0.0;
      for (int c = 0; c < 32; c++) s += u.red[tid >> 1][c][tid & 1][i];
      dots[i] = s;
    }
    double xn = fmax(sqrt(dots[16]), 1e-12);
    double logits[NE];
    unsigned act = 0;
    int cnt = 0;
    for (int ee = 0; ee < NE; ee++) {
      logits[ee] = dots[ee] / (xn * snorm[ee]) - sig[ee];
      if (logits[ee] > 0.0) { act |= 1u << ee; cnt++; }
    }
    if (cnt == 0) {  // top-MIN_E(=2) fallback, lowest-index tie-break
      int i1 = 0; double b1 = logits[0];
      for (int ee = 1; ee < NE; ee++) if (logits[ee] > b1) { b1 = logits[ee]; i1 = ee; }
      int i2 = -1; double b2 = -1e300;
      for (int ee = 0; ee < NE; ee++) if (ee != i1 && logits[ee] > b2) { b2 = logits[ee]; i2 = ee; }
      act = (1u << i1) | (1u << i2);
    }
    double m = -1e300;
    for (int ee = 0; ee < NE; ee++) if ((act >> ee) & 1) m = fmax(m, fmax(logits[ee], 0.0));
    double s = 0.0, wvv[NE];
    for (int ee = 0; ee < NE; ee++) {
      if ((act >> ee) & 1) { wvv[ee] = exp(fmax(logits[ee], 0.0) - m); s += wvv[ee]; }
      else wvv[ee] = 0.0;
    }
    for (int ee = 0; ee < NE; ee++) {
      if ((act >> ee) & 1) {
        w_lds[tid][ee] = (float)(wvv[ee] / s);
        atomicAdd(&cnt_lds[ee], 1);
      } else w_lds[tid][ee] = 0.0f;
    }
  }
  __syncthreads();
  w_all[(size_t)(tok0 + (tid >> 4)) * NE + (tid & 15)] = w_lds[tid >> 4][tid & 15];
  if (tid < 16 && cnt_lds[tid] > 0) atomicAdd(&counts[tid], cnt_lds[tid]);
}

// ---------------- scan counts -> offsets + 128-row tile descriptors (serial) ----------------
__global__ void k_scan(const int* __restrict__ counts, int* __restrict__ offsets,
                       int2* __restrict__ tile_desc, int* __restrict__ n_tiles) {
  if (threadIdx.x == 0 && blockIdx.x == 0) {
    int off = 0, nt = 0;
    for (int e = 0; e < NE; e++) {
      offsets[e] = off;
      int c = counts[e];
      int tiles = (c + 127) >> 7;
      for (int t = 0; t < tiles; t++) {
        int s0 = off + t * 128;
        if (s0 < CAP && nt < NT2_MAX) { tile_desc[nt].x = e; tile_desc[nt].y = s0; nt++; }
      }
      off += c;
    }
    offsets[NE] = off;
    *n_tiles = nt;
  }
}

// ------- slot assignment + token->slot inverse map (ballot-aggregated atomics) -------
__global__ void k_assign(const float* __restrict__ w_all, const int* __restrict__ offsets,
                         int* __restrict__ cursors, int* __restrict__ slot_token,
                         float* __restrict__ slot_w, int* __restrict__ tok_slots,
                         int* __restrict__ tok_cnt) {
  int n = blockIdx.x * 256 + threadIdx.x;   // grid exactly covers NTOK
  int lane = threadIdx.x & 63;
  int j = 0;
  for (int e = 0; e < NE; e++) {
    float w = w_all[(size_t)n * NE + e];
    bool a = w > 0.0f;
    unsigned long long mask = __ballot(a);
    if (mask) {
      int leader = (int)__ffsll((long long)mask) - 1;
      int base = 0;
      if (lane == leader) base = atomicAdd(&cursors[e], (int)__popcll(mask));
      base = __shfl(base, leader);
      if (a) {
        int pos = base + (int)__popcll(mask & ((1ULL << lane) - 1ULL));
        int s = offsets[e] + pos;
        slot_token[s] = n;
        slot_w[s] = w;
        tok_slots[n * 16 + j] = s;
        j++;
      }
    }
  }
  tok_cnt[n] = j;
}

// ---------------- MFMA tiles on XOR-swizzled LDS ----------------
// 64x128 (A rows 64): used by flash.
__device__ __forceinline__ void mfma_block(const __bf16* As, const __bf16* Bs,
                                           int lane, int wrow, f32x4 acc[8]) {
  const char* Ab = (const char*)As;
  const char* Bb = (const char*)Bs;
  int arow = wrow + (lane & 15);
  int rb = lane & 15;
#pragma unroll
  for (int ks = 0; ks < 2; ks++) {
    int kb = ks * 64 + (lane >> 4) * 16;   // byte offset within 128B row
    bf16x8 af = *(const bf16x8*)(Ab + arow * 128 + (kb ^ ((arow & 7) << 4)));
#pragma unroll
    for (int nt = 0; nt < 8; nt++) {
      int brow = nt * 16 + rb;
      bf16x8 bv = *(const bf16x8*)(Bb + brow * 128 + (kb ^ ((brow & 7) << 4)));
      acc[nt] = __builtin_amdgcn_mfma_f32_16x16x32_bf16(af, bv, acc[nt], 0, 0, 0);
    }
  }
}

// 128x128 (A rows 128, wave owns 32 A-rows): grouped GEMMs.
__device__ __forceinline__ void mfma_block128(const __bf16* As, const __bf16* Bs,
                                              int lane, int wrow2, f32x4 acc[2][8]) {
  const char* Ab = (const char*)As;
  const char* Bb = (const char*)Bs;
  int rb = lane & 15;
#pragma unroll
  for (int ks = 0; ks < 2; ks++) {
    int kb = ks * 64 + (lane >> 4) * 16;
    int ar = wrow2 + rb;                   // (ar&7) == ((ar+16)&7)
    int sw = kb ^ ((ar & 7) << 4);
    bf16x8 af0 = *(const bf16x8*)(Ab + ar * 128 + sw);
    bf16x8 af1 = *(const bf16x8*)(Ab + (ar + 16) * 128 + sw);
#pragma unroll
    for (int nt = 0; nt < 8; nt++) {
      int brow = nt * 16 + rb;
      bf16x8 bv = *(const bf16x8*)(Bb + brow * 128 + (kb ^ ((brow & 7) << 4)));
      acc[0][nt] = __builtin_amdgcn_mfma_f32_16x16x32_bf16(af0, bv, acc[0][nt], 0, 0, 0);
      acc[1][nt] = __builtin_amdgcn_mfma_f32_16x16x32_bf16(af1, bv, acc[1][nt], 0, 0, 0);
    }
  }
}

// A-operand from registers (Q frags), B from swizzled LDS
__device__ __forceinline__ void mfma_regA(bf16x8 af0, bf16x8 af1, const __bf16* Bs,
                                          int lane, f32x4 acc[8]) {
  const char* Bb = (const char*)Bs;
  int rb = lane & 15;
#pragma unroll
  for (int ks = 0; ks < 2; ks++) {
    int kb = ks * 64 + (lane >> 4) * 16;
    bf16x8 af = ks ? af1 : af0;
#pragma unroll
    for (int nt = 0; nt < 8; nt++) {
      int brow = nt * 16 + rb;
      bf16x8 bv = *(const bf16x8*)(Bb + brow * 128 + (kb ^ ((brow & 7) << 4)));
      acc[nt] = __builtin_amdgcn_mfma_f32_16x16x32_bf16(af, bv, acc[nt], 0, 0, 0);
    }
  }
}

// ------- grouped GEMM: QKV projections, BM=128, indirect A-gather, counted vmcnt -------
__global__ __launch_bounds__(256) void k_moe_qkv2(
    const __bf16* __restrict__ xbf, const int* __restrict__ slot_token,
    const __bf16* __restrict__ pq, const __bf16* __restrict__ pk, const __bf16* __restrict__ pv,
    const int* __restrict__ offsets, const int2* __restrict__ tile_desc,
    const int* __restrict__ n_tiles,
    __bf16* __restrict__ yq, __bf16* __restrict__ yk, __bf16* __restrict__ yv) {
  int id = blockIdx.x;
  int w = (id & 7) * (3 * NT2_MAX / 8) + (id >> 3);  // chunked bijective (456)
  int ti = w / 3, p = w % 3;
  if (ti >= *n_tiles) return;
  int2 td = tile_desc[ti];
  int e = td.x, s0 = td.y;
  int seg_end = offsets[e + 1]; if (seg_end > CAP) seg_end = CAP;
  const __bf16* Bt;
  __bf16* Yd;
  if (p == 0)      { Bt = pq; Yd = yq; }
  else if (p == 1) { Bt = pk; Yd = yk; }
  else             { Bt = pv; Yd = yv; }
  Bt += (size_t)e * NH * NC;

  __shared__ __bf16 As[2][128 * 64];
  __shared__ __bf16 Bs[2][128 * 64];
  int tid = threadIdx.x, lane = tid & 63, wid = tid >> 6, wrow2 = wid * 32;
  // per-lane indirect A source: row r of tile -> token slot_token[s0+r]
  const __bf16* asrc[4];
  const __bf16* bsrc[4];
#pragma unroll
  for (int i = 0; i < 4; i++) {
    int lin = (tid + 256 * i) * 16;
    int r = lin >> 7, cb = lin & 127;
    int tok = slot_token[s0 + r] & (NTOK - 1);   // mask poisoned tails
    asrc[i] = xbf + (size_t)tok * NC + ((cb ^ ((r & 7) << 4)) >> 1);
  }
#pragma unroll
  for (int i = 0; i < 4; i++) bsrc[i] = swz_src(Bt, NC, tid, i);
  auto stage = [&](int buf, int k0) {
#pragma unroll
    for (int i = 0; i < 4; i++)
      gl_lds16(asrc[i] + k0, (char*)As[buf] + tid * 16 + i * 4096);
#pragma unroll
    for (int i = 0; i < 4; i++)
      gl_lds16(bsrc[i] + k0, (char*)Bs[buf] + tid * 16 + i * 4096);
  };

  f32x4 acc[2][8];
#pragma unroll
  for (int rf = 0; rf < 2; rf++)
#pragma unroll
    for (int i = 0; i < 8; i++) { f32x4 z = {0.f, 0.f, 0.f, 0.f}; acc[rf][i] = z; }

  // 16 K-steps, 2 LDS buffers, 2 tiles (16 loads/wave) always in flight.
  stage(0, 0);
  stage(1, 64);
  VMWAIT(8); BARRIER(); SFENCE();        // tile 0 resident everywhere
  int cur = 0;
  for (int t = 0; t <= 13; t++) {        // compute tile t; stage tile t+2
    __builtin_amdgcn_s_setprio(1);
    mfma_block128(As[cur], Bs[cur], lane, wrow2, acc);
    __builtin_amdgcn_s_setprio(0);
    SFENCE();
    BARRIER();                           // all waves done reading buf[cur]
    stage(cur, (t + 2) * 64);            // overwrite buf[cur] with tile t+2
    VMWAIT(8); BARRIER(); SFENCE();      // tile t+1 resident everywhere
    cur ^= 1;
  }
  __builtin_amdgcn_s_setprio(1);
  mfma_block128(As[cur], Bs[cur], lane, wrow2, acc);      // tile 14
  __builtin_amdgcn_s_setprio(0);
  SFENCE();
  VMWAIT(0); BARRIER(); SFENCE();                         // tile 15 resident
  __builtin_amdgcn_s_setprio(1);
  mfma_block128(As[cur ^ 1], Bs[cur ^ 1], lane, wrow2, acc);  // tile 15
  __builtin_amdgcn_s_setprio(0);

  int col = lane & 15, quad = lane >> 4;
#pragma unroll
  for (int rf = 0; rf < 2; rf++)
#pragma unroll
    for (int r = 0; r < 4; r++) {
      int s = s0 + wrow2 + rf * 16 + quad * 4 + r;
      if (s < seg_end) {
#pragma unroll
        for (int nt = 0; nt < 8; nt++)
          Yd[(size_t)s * NH + nt * 16 + col] = f2bf(acc[rf][nt][r]);
      }
    }
}

// ------- combine Y slots -> token-major bf16 q/k + direct V^T (fused transpose) -------
// Q is pre-scaled by scale*log2(e) so flash works in exp2 domain.
__global__ __launch_bounds__(256) void k_combine_qkv(
    const __bf16* __restrict__ yq, const __bf16* __restrict__ yk, const __bf16* __restrict__ yv,
    const int* __restrict__ tok_slots, const int* __restrict__ tok_cnt,
    const float* __restrict__ slot_w,
    __bf16* __restrict__ qb, __bf16* __restrict__ kb, __bf16* __restrict__ vt) {
  __shared__ __bf16 vtile[128][34];
  int tid = threadIdx.x;
  int tok0 = blockIdx.x * 32;
  int tt = tok0 + (tid >> 3);
  int h0 = (tid & 7) * 16;
  const __bf16* Y = blockIdx.y == 0 ? yq : (blockIdx.y == 1 ? yk : yv);
  int cnt = tok_cnt[tt];
  float acc[16];
#pragma unroll
  for (int i = 0; i < 16; i++) acc[i] = 0.f;
  for (int j = 0; j < cnt; j++) {
    int s = tok_slots[tt * 16 + j];
    if (s < CAP) {
      float w = slot_w[s];
      bf16x8 v0 = *(const bf16x8*)(Y + (size_t)s * NH + h0);
      bf16x8 v1 = *(const bf16x8*)(Y + (size_t)s * NH + h0 + 8);
#pragma unroll
      for (int i = 0; i < 8; i++) { acc[i] += w * (float)v0[i]; acc[8 + i] += w * (float)v1[i]; }
    }
  }
  if (blockIdx.y == 2) {
    // V: LDS transpose tile [h][t], write VT [b][h][t] coalesced
#pragma unroll
    for (int i = 0; i < 16; i++) vtile[h0 + i][tid >> 3] = f2bf(acc[i]);
    __syncthreads();
    int h = tid >> 1, tp = (tid & 1) * 16;
    int b = tok0 >> 11, trow = tok0 & 2047;
    __bf16* dst = vt + ((size_t)b * NH + h) * NT + trow + tp;
    bf16x8 o0, o1;
#pragma unroll
    for (int i = 0; i < 8; i++) { o0[i] = vtile[h][tp + i]; o1[i] = vtile[h][tp + 8 + i]; }
    *(bf16x8*)dst = o0;
    *(bf16x8*)(dst + 8) = o1;
  } else {
    float sc = blockIdx.y == 0 ? 0.12751744458115337f : 1.0f;  // (1/sqrt(128))*log2(e)
    __bf16* D = blockIdx.y == 0 ? qb : kb;
    bf16x8 o0, o1;
#pragma unroll
    for (int i = 0; i < 8; i++) { o0[i] = f2bf(acc[i] * sc); o1[i] = f2bf(acc[8 + i] * sc); }
    __bf16* d = D + (size_t)tt * NH + h0;
    *(bf16x8*)d = o0;
    *(bf16x8*)(d + 8) = o1;
  }
}

// ---------------- flash attention: QK^T -> exp2-domain online softmax -> PV ----------------
// grid 512 = 4 b x 4 splits x 32 t-blocks (XCD-chunked). LDS: K 32K + V 32K + P 16K.
__global__ __launch_bounds__(256) void k_flash(const __bf16* __restrict__ q,
                                               const __bf16* __restrict__ k,
                                               const __bf16* __restrict__ vt,
                                               float* __restrict__ opart,
                                               float2* __restrict__ ml) {
  int id = blockIdx.x;
  int w = (id & 7) * 64 + (id >> 3);     // chunked bijective over 512
  int b = w >> 7;
  int rem = w & 127;
  int spl = rem >> 5;
  int t0 = (rem & 31) * 64;
  const __bf16* qb = q + (size_t)b * NT * NH;
  const __bf16* kb = k + (size_t)b * NT * NH;
  const __bf16* vtb = vt + (size_t)b * NH * NT;

  __shared__ __bf16 Ks[2][128 * 64];   // [d-chunk][s-row][64]
  __shared__ __bf16 Vs[2][128 * 64];   // [s-chunk][d-row][64]
  __shared__ __bf16 Ps[2][64 * 64];    // [s-chunk][t-row][64]
  int tid = threadIdx.x, lane = tid & 63, wid = tid >> 6, wrow = wid * 16;
  int colq = lane & 15, quad = lane >> 4;

  // Q fragments in registers (force-resolved before staging starts)
  bf16x8 qf[4];
  {
    const __bf16* qr = qb + (size_t)(t0 + wrow + colq) * NH + quad * 8;
#pragma unroll
    for (int kk = 0; kk < 4; kk++) qf[kk] = *(const bf16x8*)(qr + kk * 32);
  }
  asm volatile("" :: "v"(qf[0]), "v"(qf[1]), "v"(qf[2]), "v"(qf[3]));
  SFENCE();

  auto stage_K = [&](int s0) {
#pragma unroll
    for (int c = 0; c < 2; c++)
#pragma unroll
      for (int i = 0; i < 4; i++)
        gl_lds16(swz_src(kb + (size_t)s0 * NH + c * 64, NH, tid, i),
                 (char*)Ks[c] + wid * 1024 + i * 4096);
  };
  auto stage_V = [&](int s0) {
#pragma unroll
    for (int c = 0; c < 2; c++)
#pragma unroll
      for (int i = 0; i < 4; i++)
        gl_lds16(swz_src(vtb + s0 + c * 64, NT, tid, i),
                 (char*)Vs[c] + wid * 1024 + i * 4096);
  };

  f32x4 oacc[8];
#pragma unroll
  for (int i = 0; i < 8; i++) { f32x4 z = {0.f, 0.f, 0.f, 0.f}; oacc[i] = z; }
  float mr[4], lr[4];
#pragma unroll
  for (int r = 0; r < 4; r++) { mr[r] = -1e30f; lr[r] = 0.f; }

  const int sbase = spl * 512;
  stage_K(sbase);
  stage_V(sbase);
  VMWAIT(8); BARRIER(); SFENCE();        // K(0) resident; V(0) 8 loads in flight

  for (int t = 0; t < 4; t++) {
    // ---- QK^T for s-tile t (already in log2 domain via pre-scaled Q) ----
    f32x4 sacc[8];
#pragma unroll
    for (int i = 0; i < 8; i++) { f32x4 z = {0.f, 0.f, 0.f, 0.f}; sacc[i] = z; }
    __builtin_amdgcn_s_setprio(1);
    mfma_regA(qf[0], qf[1], Ks[0], lane, sacc);
    mfma_regA(qf[2], qf[3], Ks[1], lane, sacc);
    __builtin_amdgcn_s_setprio(0);
    SFENCE();
    BARRIER();                           // all waves done reading Ks
    if (t < 3) stage_K(sbase + (t + 1) * 128);   // +8 in flight

    // ---- online softmax (base 2); P -> LDS (own wave's rows only) ----
    float tm[4];
#pragma unroll
    for (int r = 0; r < 4; r++) {
      float v = sacc[0][r];
#pragma unroll
      for (int nt = 1; nt < 8; nt++) v = fmaxf(v, sacc[nt][r]);
      tm[r] = v;
    }
#pragma unroll
    for (int off = 1; off < 16; off <<= 1)
#pragma unroll
      for (int r = 0; r < 4; r++) tm[r] = fmaxf(tm[r], __shfl_xor(tm[r], off));
    float alpha[4], rs[4];
#pragma unroll
    for (int r = 0; r < 4; r++) {
      float mn = fmaxf(mr[r], tm[r]);
      alpha[r] = exp2f(mr[r] - mn);
      mr[r] = mn;
      rs[r] = 0.f;
    }
#pragma unroll
    for (int nt = 0; nt < 8; nt++) {
      char* pc = (char*)Ps[nt >> 2];
      int colb = ((nt & 3) * 16 + colq) * 2;
#pragma unroll
      for (int r = 0; r < 4; r++) {
        int row = wrow + quad * 4 + r;
        float p = exp2f(sacc[nt][r] - mr[r]);
        rs[r] += p;
        *(__bf16*)(pc + row * 128 + (colb ^ ((row & 7) << 4))) = f2bf(p);
      }
    }
#pragma unroll
    for (int off = 1; off < 16; off <<= 1)
#pragma unroll
      for (int r = 0; r < 4; r++) rs[r] += __shfl_xor(rs[r], off);
#pragma unroll
    for (int r = 0; r < 4; r++) lr[r] = alpha[r] * lr[r] + rs[r];
#pragma unroll
    for (int nt = 0; nt < 8; nt++)
#pragma unroll
      for (int r = 0; r < 4; r++) oacc[nt][r] *= alpha[r];

    LGKMWAIT0();                         // P writes done
    if (t < 3) { VMWAIT(8); } else { VMWAIT(0); }   // V(t) resident (own loads)
    BARRIER(); SFENCE();                 // everyone's V(t) + P ready

    // ---- PV ----
    __builtin_amdgcn_s_setprio(1);
    mfma_block(Ps[0], Vs[0], lane, wrow, oacc);
    mfma_block(Ps[1], Vs[1], lane, wrow, oacc);
    __builtin_amdgcn_s_setprio(0);
    SFENCE();
    BARRIER();                           // all done reading Vs, Ps
    if (t < 3) {
      stage_V(sbase + (t + 1) * 128);    // +8 -> 16 in flight
      VMWAIT(8); BARRIER(); SFENCE();    // K(t+1) resident
    }
  }

  // epilogue: unnormalized partial O + (m,l) in log2 domain
  size_t base = (size_t)(b * 4 + spl) * NT + t0;
#pragma unroll
  for (int r = 0; r < 4; r++) {
    size_t row = base + wrow + quad * 4 + r;
#pragma unroll
    for (int nt = 0; nt < 8; nt++)
      opart[row * NH + nt * 16 + colq] = oacc[nt][r];
  }
  if (colq == 0) {
#pragma unroll
    for (int r = 0; r < 4; r++) {
      float2 v; v.x = mr[r]; v.y = lr[r];
      ml[base + wrow + quad * 4 + r] = v;
    }
  }
}

// ---------------- gather o: merge 4 split partials (base-2 LSE) -> slot-major bf16 ----------------
__global__ __launch_bounds__(256) void k_gather_o(const float* __restrict__ opart,
                                                  const float2* __restrict__ ml,
                                                  const int* __restrict__ slot_token,
                                                  const int* __restrict__ offsets,
                                                  __bf16* __restrict__ og) {
  int slot = blockIdx.x * 2 + (threadIdx.x >> 7);
  int h = threadIdx.x & 127;
  int total = offsets[NE]; if (total > CAP) total = CAP;
  if (slot >= total) return;
  int n = slot_token[slot];
  int b = n >> 11, trow = n & 2047;
  size_t rb = (size_t)b * 4 * NT + trow;
  float2 m0 = ml[rb], m1 = ml[rb + NT], m2 = ml[rb + 2 * NT], m3 = ml[rb + 3 * NT];
  float M = fmaxf(fmaxf(m0.x, m1.x), fmaxf(m2.x, m3.x));
  float e0 = exp2f(m0.x - M), e1 = exp2f(m1.x - M), e2 = exp2f(m2.x - M), e3 = exp2f(m3.x - M);
  float den = m0.y * e0 + m1.y * e1 + m2.y * e2 + m3.y * e3;
  float num = opart[rb * NH + h] * e0 + opart[(rb + NT) * NH + h] * e1 +
              opart[(rb + 2 * NT) * NH + h] * e2 + opart[(rb + 3 * NT) * NH + h] * e3;
  og[(size_t)slot * NH + h] = f2bf(num / den);
}

// ------- grouped GEMM: out-proj, BM=128, 2 N-chunks/block (A staged once) -------
__global__ __launch_bounds__(256) void k_out2(
    const __bf16* __restrict__ og, const __bf16* __restrict__ pot,
    const int* __restrict__ offsets, const int2* __restrict__ tile_desc,
    const int* __restrict__ n_tiles, __bf16* __restrict__ zy) {
  int id = blockIdx.x;
  int w = (id & 7) * (4 * NT2_MAX / 8) + (id >> 3);  // chunked bijective (608)
  int ti = w >> 2, p = w & 3;                        // p = 256-wide nc chunk 0..3
  if (ti >= *n_tiles) return;
  int2 td = tile_desc[ti];
  int e = td.x, s0 = td.y;
  int seg_end = offsets[e + 1]; if (seg_end > CAP) seg_end = CAP;
  int nc0 = p * 256;
  const __bf16* Bt = pot + (size_t)e * NC * NH;

  __shared__ __bf16 As[2][128 * 64];
  __shared__ __bf16 Bs[2][128 * 64];
  int tid = threadIdx.x, lane = tid & 63, wid = tid >> 6, wrow2 = wid * 32;
  const __bf16* asrc[4];
  const __bf16* bsrc[4];
#pragma unroll
  for (int i = 0; i < 4; i++) asrc[i] = swz_src(og + (size_t)s0 * NH, NH, tid, i);
#pragma unroll
  for (int i = 0; i < 4; i++) bsrc[i] = swz_src(Bt + (size_t)nc0 * NH, NH, tid, i);
  auto stageA = [&](int buf, int k0) {
#pragma unroll
    for (int i = 0; i < 4; i++)
      gl_lds16(asrc[i] + k0, (char*)As[buf] + tid * 16 + i * 4096);
  };
  auto stageB = [&](int buf, int k0, int noff) {
#pragma unroll
    for (int i = 0; i < 4; i++)
      gl_lds16(bsrc[i] + (size_t)noff * NH + k0, (char*)Bs[buf] + tid * 16 + i * 4096);
  };
  f32x4 acc[2][8];
  int col = lane & 15, quad = lane >> 4;
  auto store_acc = [&](int nco) {
#pragma unroll
    for (int rf = 0; rf < 2; rf++)
#pragma unroll
      for (int r = 0; r < 4; r++) {
        int s = s0 + wrow2 + rf * 16 + quad * 4 + r;
        if (s < seg_end) {
#pragma unroll
          for (int nt = 0; nt < 8; nt++)
            zy[(size_t)s * NC + nco + nt * 16 + col] = f2bf(acc[rf][nt][r]);
        }
      }
  };

#pragma unroll
  for (int rf = 0; rf < 2; rf++)
#pragma unroll
    for (int i = 0; i < 8; i++) { f32x4 z = {0.f, 0.f, 0.f, 0.f}; acc[rf][i] = z; }

  // A (full K=128) staged once; B re-staged per 128-wide n-chunk.
  stageA(0, 0); stageB(0, 0, 0);        // first 8: As[0] + Bs[0] (chunk 0)
  stageA(1, 64); stageB(1, 64, 0);
  VMWAIT(8); BARRIER(); SFENCE();
  __builtin_amdgcn_s_setprio(1);
  mfma_block128(As[0], Bs[0], lane, wrow2, acc);
  __builtin_amdgcn_s_setprio(0);
  SFENCE();
  VMWAIT(0); BARRIER(); SFENCE();
  __builtin_amdgcn_s_setprio(1);
  mfma_block128(As[1], Bs[1], lane, wrow2, acc);
  __builtin_amdgcn_s_setprio(0);
  SFENCE();
  store_acc(nc0);
  BARRIER();                            // all waves done reading Bs
  stageB(0, 0, 128); stageB(1, 64, 128);   // B for chunk 1; As untouched
#pragma unroll
  for (int rf = 0; rf < 2; rf++)
#pragma unroll
    for (int i = 0; i < 8; i++) { f32x4 z = {0.f, 0.f, 0.f, 0.f}; acc[rf][i] = z; }
  VMWAIT(0); BARRIER(); SFENCE();
  __builtin_amdgcn_s_setprio(1);
  mfma_block128(As[0], Bs[0], lane, wrow2, acc);
  mfma_block128(As[1], Bs[1], lane, wrow2, acc);
  __builtin_amdgcn_s_setprio(0);
  store_acc(nc0 + 128);
}

// ---------------- combine ZY slots -> dense fp32 out ----------------
__global__ __launch_bounds__(256) void k_combine_out(
    const __bf16* __restrict__ zy, const int* __restrict__ tok_slots,
    const int* __restrict__ tok_cnt, const float* __restrict__ slot_w,
    float* __restrict__ out) {
  int token = blockIdx.x;
  int c = threadIdx.x * 4;
  int cnt = tok_cnt[token];
  float a0 = 0.f, a1 = 0.f, a2 = 0.f, a3 = 0.f;
  for (int j = 0; j < cnt; j++) {
    int s = tok_slots[token * 16 + j];
    if (s < CAP) {
      float w = slot_w[s];
      bf16x4 z = *(const bf16x4*)&zy[(size_t)s * NC + c];
      a0 += w * (float)z[0];
      a1 += w * (float)z[1];
      a2 += w * (float)z[2];
      a3 += w * (float)z[3];
    }
  }
  float4 o = {a0, a1, a2, a3};
  *(float4*)&out[(size_t)token * NC + c] = o;
}

extern "C" void kernel_launch(void* const* d_in, const int* in_sizes, int n_in,
                              void* d_out, int out_size, void* d_ws, size_t ws_size,
                              hipStream_t stream) {
  const float* hs    = (const float*)d_in[0];  // [4,2048,1024]
  const float* sim   = (const float*)d_in[1];  // [1024,16]
  const float* gates = (const float*)d_in[2];  // [16]
  const float* qp    = (const float*)d_in[3];  // [16,1024,128]
  const float* kp    = (const float*)d_in[4];
  const float* vp    = (const float*)d_in[5];
  const float* op    = (const float*)d_in[6];  // [16,128,1024]
  float* out = (float*)d_out;
  char* ws = (char*)d_ws;

  // ---- workspace arena (aliased by lifetime) ----
  const size_t M = 1048576;
  __bf16* PQT = (__bf16*)(ws + 0 * M);         // 4 MiB each
  __bf16* PKT = (__bf16*)(ws + 4 * M);
  __bf16* PVT = (__bf16*)(ws + 8 * M);
  __bf16* POT = (__bf16*)(ws + 12 * M);
  __bf16* Qb  = (__bf16*)(ws + 16 * M);        // 2 MiB each, token-major bf16
  __bf16* Kb  = (__bf16*)(ws + 18 * M);
  __bf16* VT  = (__bf16*)(ws + 22 * M);        // 2 MiB [b][h][t]
  float*  WALL = (float*)(ws + 28 * M);        // 512 KiB
  int*    STOK = (int*)(ws + 28 * M + 524288); // 512 KiB
  float*  SW   = (float*)(ws + 28 * M + 1048576);
  int*    TSL  = (int*)(ws + 28 * M + 1572864);  // tok_slots 512 KiB
  int*    TCN  = (int*)(ws + 28 * M + 2097152);  // tok_cnt 32 KiB
  double* SNORM = (double*)(ws + 28 * M + 2129920);
  double* SIG   = SNORM + 16;
  int* CNT = (int*)(ws + 28 * M + 2130432);    // control block (zeroed in prep)
  int* OFF = CNT + 16;
  int* CUR = CNT + 40;
  int* NTL = CNT + 60;
  int2* DESC = (int2*)(ws + 28 * M + 2131456);
  // R region (32M..96M), aliased by lifetime:
  __bf16* XBF = (__bf16*)(ws + 32 * M);        // 16.8 MiB dense bf16 x (dies after qkv2)
  __bf16* YQ = (__bf16*)(ws + 72 * M);         // 4.5 MiB each (die before flash)
  __bf16* YK = (__bf16*)(ws + 77 * M);
  __bf16* YV = (__bf16*)(ws + 82 * M);
  float*  OP2 = (float*)(ws + 32 * M);         // 16.8 MiB partial O (after XBF dead)
  float2* MLB = (float2*)(ws + 50 * M);        // 256 KiB (m,l) per split-row
  __bf16* OG = (__bf16*)(ws + 52 * M);         // 4.5 MiB
  __bf16* ZY = (__bf16*)(ws + 60 * M);         // 36.1 MiB

  k_transpose_all<<<dim3(128, 65), 256, 0, stream>>>(qp, kp, vp, op, PQT, PKT, PVT, POT,
                                                     sim, gates, SNORM, SIG, CNT);
  k_gating3<<<NTOK / 16, 256, 0, stream>>>(hs, sim, SNORM, SIG, WALL, CNT, XBF);
  k_scan<<<1, 64, 0, stream>>>(CNT, OFF, DESC, NTL);
  k_assign<<<NTOK / 256, 256, 0, stream>>>(WALL, OFF, CUR, STOK, SW, TSL, TCN);
  k_moe_qkv2<<<3 * NT2_MAX, 256, 0, stream>>>(XBF, STOK, PQT, PKT, PVT, OFF, DESC, NTL, YQ, YK, YV);
  k_combine_qkv<<<dim3(NTOK / 32, 3), 256, 0, stream>>>(YQ, YK, YV, TSL, TCN, SW, Qb, Kb, VT);
  k_flash<<<512, 256, 0, stream>>>(Qb, Kb, VT, OP2, MLB);
  k_gather_o<<<CAP / 2, 256, 0, stream>>>(OP2, MLB, STOK, OFF, OG);
  k_out2<<<4 * NT2_MAX, 256, 0, stream>>>(OG, POT, OFF, DESC, NTL, ZY);
  k_combine_out<<<NTOK, 256, 0, stream>>>(ZY, TSL, TCN, SW, out);
}

// Round 13
// 265.780 us; speedup vs baseline: 1.3982x; 1.0385x over previous
//
#include <hip/hip_runtime.h>
#include <hip/hip_bf16.h>
#include <math.h>

// DynSMHA: B=4 T=2048 C=1024 H=128 E=16 MIN_E=2, non-causal.
// weight transposes + prep (+ctrl zero) -> fp64 gating (16 tok/block, atomic
// counts, emits dense bf16 x) -> ballot-aggregated slot assign (inline offsets)
// -> grouped GEMMs (BM=128, indirect A-gather, counted-vmcnt, XOR-swizzled LDS,
// tile location computed from counts) -> flash attention (exp2-domain online
// softmax, split-s LSE) -> combines.  No k_scan: descriptors derived inline.
#define NBATCH 4
#define NT     2048
#define NC     1024
#define NH     128
#define NE     16
#define NTOK   (NBATCH * NT)
#define CAP    18432         // slot capacity (actual ~16384)
#define NT2_MAX 152          // sum ceil(cnt_e/128) + slack; multiple of 8

typedef __bf16 bf16x8 __attribute__((ext_vector_type(8)));
typedef __bf16 bf16x4 __attribute__((ext_vector_type(4)));
typedef float  f32x4  __attribute__((ext_vector_type(4)));

__device__ __forceinline__ __bf16 f2bf(float f) { return (__bf16)f; }

#define BARRIER() __builtin_amdgcn_s_barrier()
#define SFENCE()  __builtin_amdgcn_sched_barrier(0)
#define VMWAIT(n) asm volatile("s_waitcnt vmcnt(" #n ")" ::: "memory")
#define LGKMWAIT0() asm volatile("s_waitcnt lgkmcnt(0)" ::: "memory")

// async global->LDS, 16B per lane; LDS dest = wave-uniform base + lane*16
__device__ __forceinline__ void gl_lds16(const void* g, void* l) {
  __builtin_amdgcn_global_load_lds((const __attribute__((address_space(1))) void*)g,
                                   (__attribute__((address_space(3))) void*)l, 16, 0, 0);
}

// Pre-swizzled global source (swizzle BOTH sides or neither).
// LDS tile is [rows][64] bf16, linear 128B rows; swizzle byte ^= ((row&7)<<4).
__device__ __forceinline__ const __bf16* swz_src(const __bf16* row0, size_t stride,
                                                 int tid, int i) {
  int lin = (tid + 256 * i) * 16;
  int r = lin >> 7, cb = lin & 127;
  return row0 + (size_t)r * stride + ((cb ^ ((r & 7) << 4)) >> 1);
}

// Locate 128-row tile ti from per-expert counts (same semantics as old k_scan).
// Returns false if ti beyond last tile or s0 >= CAP.
__device__ __forceinline__ bool locate_tile(const int* __restrict__ counts, int ti,
                                            int& e_out, int& s0_out, int& seg_end_out) {
  int off = 0, nt = 0, e = -1, s0 = 0, seg_end = 0;
#pragma unroll
  for (int ee = 0; ee < NE; ee++) {
    int c = counts[ee];
    int tiles = (c + 127) >> 7;
    if (e < 0 && ti < nt + tiles) {
      e = ee;
      s0 = off + (ti - nt) * 128;
      seg_end = off + c;
    }
    nt += tiles;
    off += c;
  }
  if (e < 0 || s0 >= CAP) return false;
  if (seg_end > CAP) seg_end = CAP;
  e_out = e; s0_out = s0; seg_end_out = seg_end;
  return true;
}

// ------- fused: weight transposes (fp32->bf16) + sim-norm/sigmoid prep + ctrl zero -------
__global__ void k_transpose_all(const float* __restrict__ qp, const float* __restrict__ kp,
                                const float* __restrict__ vp, const float* __restrict__ op,
                                __bf16* __restrict__ pqt, __bf16* __restrict__ pkt,
                                __bf16* __restrict__ pvt, __bf16* __restrict__ pot,
                                const float* __restrict__ sim, const float* __restrict__ gates,
                                double* __restrict__ snorm, double* __restrict__ sig,
                                int* __restrict__ ctrl) {
  __shared__ float tile[32][33];
  __shared__ double red[16][17];
  int z = blockIdx.y;
  int tid = threadIdx.x;
  if (z == 64) {                          // prep block
    if (blockIdx.x != 0) return;
    if (tid < 128) ctrl[tid] = 0;         // zero CNT + CUR cursors
    int e = tid & 15, chunk = tid >> 4;
    double a = 0.0;
#pragma unroll 4
    for (int j = 0; j < 64; j++) {
      double v = (double)sim[(chunk * 64 + j) * NE + e];
      a += v * v;
    }
    red[chunk][e] = a;
    __syncthreads();
    if (tid < 16) {
      double s = 0.0;
      for (int k = 0; k < 16; k++) s += red[k][tid];
      snorm[tid] = fmax(sqrt(s), 1e-12);
      sig[tid] = 1.0 / (1.0 + exp(-(double)gates[tid]));
    }
    return;
  }
  const float* in;
  __bf16* out;
  int R, Cd, g, r0, c0;
  if (z < 48) {
    int which = z >> 4; g = z & 15; R = 1024; Cd = 128;
    in = which == 0 ? qp : (which == 1 ? kp : vp);
    out = which == 0 ? pqt : (which == 1 ? pkt : pvt);
    r0 = (blockIdx.x >> 2) * 32; c0 = (blockIdx.x & 3) * 32;
  } else {
    g = z - 48; R = 128; Cd = 1024;
    in = op; out = pot;
    r0 = (blockIdx.x & 3) * 32; c0 = (blockIdx.x >> 2) * 32;
  }
  int tx = tid & 31, ty0 = tid >> 5;
  const float* src = in + (size_t)g * R * Cd;
  __bf16* dst = out + (size_t)g * R * Cd;
#pragma unroll
  for (int ty = ty0; ty < 32; ty += 8)
    tile[ty][tx] = src[(size_t)(r0 + ty) * Cd + (c0 + tx)];
  __syncthreads();
#pragma unroll
  for (int ty = ty0; ty < 32; ty += 8)
    dst[(size_t)(c0 + ty) * R + (r0 + tx)] = f2bf(tile[tx][ty]);
}

// ---------------- gating: 16 tokens/block (512 blocks), chunked LDS, f64 acc ----------------
// Global atomic counts (wave-coalesced, 16 addresses). Also emits dense bf16 x.
__global__ __launch_bounds__(256, 2) void k_gating3(const float* __restrict__ x,
                                                    const float* __restrict__ sim,
                                                    const double* __restrict__ snorm,
                                                    const double* __restrict__ sig,
                                                    float* __restrict__ w_all,
                                                    int* __restrict__ counts,
                                                    __bf16* __restrict__ xbf) {
  __shared__ union {
    struct {
      float xs_[16][66];    // [token][col-in-chunk]
      float ss_[16][66];    // [e][col-in-chunk]
    } s;
    double red[8][32][2][17];  // [tkg][cg][t][dot0..15,norm] = 69632 B
  } u;
  __shared__ float w_lds[16][16];
  __shared__ int cnt_lds[16];
  int tid = threadIdx.x;
  if (tid < 16) cnt_lds[tid] = 0;
  int cg = tid & 31, tkg = tid >> 5;
  int tok0 = blockIdx.x * 16;

  double acc[2][17];
#pragma unroll
  for (int t = 0; t < 2; t++)
#pragma unroll
    for (int i = 0; i < 17; i++) acc[t][i] = 0.0;

  // staging roles
  int xr0 = tid >> 4, xc4 = (tid & 15) * 4;   // x row xr0, 4 cols
  int sr = tid >> 2, se4 = (tid & 3) * 4;     // sim row c0+sr, 4 experts

  float4 xa, sv;
  auto ldchunk = [&](int c0) {
    xa = *(const float4*)(x + (size_t)(tok0 + xr0) * NC + c0 + xc4);
    sv = *(const float4*)(sim + (size_t)(c0 + sr) * NE + se4);
  };
  auto stchunk = [&]() {
    *(float4*)&u.s.xs_[xr0][xc4] = xa;
    u.s.ss_[se4 + 0][sr] = sv.x;
    u.s.ss_[se4 + 1][sr] = sv.y;
    u.s.ss_[se4 + 2][sr] = sv.z;
    u.s.ss_[se4 + 3][sr] = sv.w;
  };
  auto stxbf = [&](int c0) {   // dense bf16 emit (xa still live)
    bf16x4 a;
    a[0]=f2bf(xa.x); a[1]=f2bf(xa.y); a[2]=f2bf(xa.z); a[3]=f2bf(xa.w);
    *(bf16x4*)(xbf + (size_t)(tok0 + xr0) * NC + c0 + xc4) = a;
  };

  ldchunk(0);
  for (int ch = 0; ch < 16; ch++) {
    stchunk();
    stxbf(ch * 64);
    __syncthreads();
    if (ch < 15) ldchunk((ch + 1) * 64);   // prefetch next chunk into regs
    double xd[2][2];
#pragma unroll
    for (int t = 0; t < 2; t++) {
      float2 xv = *(const float2*)&u.s.xs_[tkg * 2 + t][cg * 2];
      xd[t][0] = (double)xv.x;
      xd[t][1] = (double)xv.y;
      acc[t][16] += xd[t][0] * xd[t][0] + xd[t][1] * xd[t][1];
    }
#pragma unroll
    for (int e = 0; e < 16; e++) {
      float2 sv2 = *(const float2*)&u.s.ss_[e][cg * 2];
      double s0 = (double)sv2.x, s1 = (double)sv2.y;
#pragma unroll
      for (int t = 0; t < 2; t++)
        acc[t][e] += xd[t][0] * s0 + xd[t][1] * s1;
    }
    __syncthreads();
  }

  // one-shot LDS reduce (xs_/ss_ dead; union'd)
#pragma unroll
  for (int t = 0; t < 2; t++)
#pragma unroll
    for (int i = 0; i < 17; i++)
      u.red[tkg][cg][t][i] = acc[t][i];
  __syncthreads();

  if (tid < 16) {
    double dots[17];
    for (int i = 0; i < 17; i++) {
      double s = 0.0;
      for (int c = 0; c < 32; c++) s += u.red[tid >> 1][c][tid & 1][i];
      dots[i] = s;
    }
    double xn = fmax(sqrt(dots[16]), 1e-12);
    double logits[NE];
    unsigned act = 0;
    int cnt = 0;
    for (int ee = 0; ee < NE; ee++) {
      logits[ee] = dots[ee] / (xn * snorm[ee]) - sig[ee];
      if (logits[ee] > 0.0) { act |= 1u << ee; cnt++; }
    }
    if (cnt == 0) {  // top-MIN_E(=2) fallback, lowest-index tie-break
      int i1 = 0; double b1 = logits[0];
      for (int ee = 1; ee < NE; ee++) if (logits[ee] > b1) { b1 = logits[ee]; i1 = ee; }
      int i2 = -1; double b2 = -1e300;
      for (int ee = 0; ee < NE; ee++) if (ee != i1 && logits[ee] > b2) { b2 = logits[ee]; i2 = ee; }
      act = (1u << i1) | (1u << i2);
    }
    double m = -1e300;
    for (int ee = 0; ee < NE; ee++) if ((act >> ee) & 1) m = fmax(m, fmax(logits[ee], 0.0));
    double s = 0.0, wvv[NE];
    for (int ee = 0; ee < NE; ee++) {
      if ((act >> ee) & 1) { wvv[ee] = exp(fmax(logits[ee], 0.0) - m); s += wvv[ee]; }
      else wvv[ee] = 0.0;
    }
    for (int ee = 0; ee < NE; ee++) {
      if ((act >> ee) & 1) {
        w_lds[tid][ee] = (float)(wvv[ee] / s);
        atomicAdd(&cnt_lds[ee], 1);
      } else w_lds[tid][ee] = 0.0f;
    }
  }
  __syncthreads();
  w_all[(size_t)(tok0 + (tid >> 4)) * NE + (tid & 15)] = w_lds[tid >> 4][tid & 15];
  if (tid < 16 && cnt_lds[tid] > 0) atomicAdd(&counts[tid], cnt_lds[tid]);
}

// ------- slot assignment + token->slot inverse map (ballot atomics, inline offsets) -------
__global__ void k_assign(const float* __restrict__ w_all, const int* __restrict__ counts,
                         int* __restrict__ cursors, int* __restrict__ slot_token,
                         float* __restrict__ slot_w, int* __restrict__ tok_slots,
                         int* __restrict__ tok_cnt) {
  int n = blockIdx.x * 256 + threadIdx.x;   // grid exactly covers NTOK
  int lane = threadIdx.x & 63;
  int j = 0;
  int off = 0;                              // running prefix of counts
#pragma unroll
  for (int e = 0; e < NE; e++) {
    float w = w_all[(size_t)n * NE + e];
    bool a = w > 0.0f;
    unsigned long long mask = __ballot(a);
    if (mask) {
      int leader = (int)__ffsll((long long)mask) - 1;
      int base = 0;
      if (lane == leader) base = atomicAdd(&cursors[e], (int)__popcll(mask));
      base = __shfl(base, leader);
      if (a) {
        int pos = base + (int)__popcll(mask & ((1ULL << lane) - 1ULL));
        int s = off + pos;
        slot_token[s] = n;
        slot_w[s] = w;
        tok_slots[n * 16 + j] = s;
        j++;
      }
    }
    off += counts[e];
  }
  tok_cnt[n] = j;
}

// ---------------- MFMA tiles on XOR-swizzled LDS ----------------
// 64x128 (A rows 64): used by flash.
__device__ __forceinline__ void mfma_block(const __bf16* As, const __bf16* Bs,
                                           int lane, int wrow, f32x4 acc[8]) {
  const char* Ab = (const char*)As;
  const char* Bb = (const char*)Bs;
  int arow = wrow + (lane & 15);
  int rb = lane & 15;
#pragma unroll
  for (int ks = 0; ks < 2; ks++) {
    int kb = ks * 64 + (lane >> 4) * 16;   // byte offset within 128B row
    bf16x8 af = *(const bf16x8*)(Ab + arow * 128 + (kb ^ ((arow & 7) << 4)));
#pragma unroll
    for (int nt = 0; nt < 8; nt++) {
      int brow = nt * 16 + rb;
      bf16x8 bv = *(const bf16x8*)(Bb + brow * 128 + (kb ^ ((brow & 7) << 4)));
      acc[nt] = __builtin_amdgcn_mfma_f32_16x16x32_bf16(af, bv, acc[nt], 0, 0, 0);
    }
  }
}

// 128x128 (A rows 128, wave owns 32 A-rows): grouped GEMMs.
__device__ __forceinline__ void mfma_block128(const __bf16* As, const __bf16* Bs,
                                              int lane, int wrow2, f32x4 acc[2][8]) {
  const char* Ab = (const char*)As;
  const char* Bb = (const char*)Bs;
  int rb = lane & 15;
#pragma unroll
  for (int ks = 0; ks < 2; ks++) {
    int kb = ks * 64 + (lane >> 4) * 16;
    int ar = wrow2 + rb;                   // (ar&7) == ((ar+16)&7)
    int sw = kb ^ ((ar & 7) << 4);
    bf16x8 af0 = *(const bf16x8*)(Ab + ar * 128 + sw);
    bf16x8 af1 = *(const bf16x8*)(Ab + (ar + 16) * 128 + sw);
#pragma unroll
    for (int nt = 0; nt < 8; nt++) {
      int brow = nt * 16 + rb;
      bf16x8 bv = *(const bf16x8*)(Bb + brow * 128 + (kb ^ ((brow & 7) << 4)));
      acc[0][nt] = __builtin_amdgcn_mfma_f32_16x16x32_bf16(af0, bv, acc[0][nt], 0, 0, 0);
      acc[1][nt] = __builtin_amdgcn_mfma_f32_16x16x32_bf16(af1, bv, acc[1][nt], 0, 0, 0);
    }
  }
}

// A-operand from registers (Q frags), B from swizzled LDS
__device__ __forceinline__ void mfma_regA(bf16x8 af0, bf16x8 af1, const __bf16* Bs,
                                          int lane, f32x4 acc[8]) {
  const char* Bb = (const char*)Bs;
  int rb = lane & 15;
#pragma unroll
  for (int ks = 0; ks < 2; ks++) {
    int kb = ks * 64 + (lane >> 4) * 16;
    bf16x8 af = ks ? af1 : af0;
#pragma unroll
    for (int nt = 0; nt < 8; nt++) {
      int brow = nt * 16 + rb;
      bf16x8 bv = *(const bf16x8*)(Bb + brow * 128 + (kb ^ ((brow & 7) << 4)));
      acc[nt] = __builtin_amdgcn_mfma_f32_16x16x32_bf16(af, bv, acc[nt], 0, 0, 0);
    }
  }
}

// ------- grouped GEMM: QKV projections, BM=128, indirect A-gather, counted vmcnt -------
__global__ __launch_bounds__(256) void k_moe_qkv2(
    const __bf16* __restrict__ xbf, const int* __restrict__ slot_token,
    const __bf16* __restrict__ pq, const __bf16* __restrict__ pk, const __bf16* __restrict__ pv,
    const int* __restrict__ counts,
    __bf16* __restrict__ yq, __bf16* __restrict__ yk, __bf16* __restrict__ yv) {
  int id = blockIdx.x;
  int w = (id & 7) * (3 * NT2_MAX / 8) + (id >> 3);  // chunked bijective (456)
  int ti = w / 3, p = w % 3;
  int e, s0, seg_end;
  if (!locate_tile(counts, ti, e, s0, seg_end)) return;
  const __bf16* Bt;
  __bf16* Yd;
  if (p == 0)      { Bt = pq; Yd = yq; }
  else if (p == 1) { Bt = pk; Yd = yk; }
  else             { Bt = pv; Yd = yv; }
  Bt += (size_t)e * NH * NC;

  __shared__ __bf16 As[2][128 * 64];
  __shared__ __bf16 Bs[2][128 * 64];
  int tid = threadIdx.x, lane = tid & 63, wid = tid >> 6, wrow2 = wid * 32;
  // per-lane indirect A source: row r of tile -> token slot_token[s0+r]
  const __bf16* asrc[4];
  const __bf16* bsrc[4];
#pragma unroll
  for (int i = 0; i < 4; i++) {
    int lin = (tid + 256 * i) * 16;
    int r = lin >> 7, cb = lin & 127;
    int tok = slot_token[s0 + r] & (NTOK - 1);   // mask poisoned tails
    asrc[i] = xbf + (size_t)tok * NC + ((cb ^ ((r & 7) << 4)) >> 1);
  }
#pragma unroll
  for (int i = 0; i < 4; i++) bsrc[i] = swz_src(Bt, NC, tid, i);
  auto stage = [&](int buf, int k0) {
#pragma unroll
    for (int i = 0; i < 4; i++)
      gl_lds16(asrc[i] + k0, (char*)As[buf] + tid * 16 + i * 4096);
#pragma unroll
    for (int i = 0; i < 4; i++)
      gl_lds16(bsrc[i] + k0, (char*)Bs[buf] + tid * 16 + i * 4096);
  };

  f32x4 acc[2][8];
#pragma unroll
  for (int rf = 0; rf < 2; rf++)
#pragma unroll
    for (int i = 0; i < 8; i++) { f32x4 z = {0.f, 0.f, 0.f, 0.f}; acc[rf][i] = z; }

  // 16 K-steps, 2 LDS buffers, 2 tiles (16 loads/wave) always in flight.
  stage(0, 0);
  stage(1, 64);
  VMWAIT(8); BARRIER(); SFENCE();        // tile 0 resident everywhere
  int cur = 0;
  for (int t = 0; t <= 13; t++) {        // compute tile t; stage tile t+2
    __builtin_amdgcn_s_setprio(1);
    mfma_block128(As[cur], Bs[cur], lane, wrow2, acc);
    __builtin_amdgcn_s_setprio(0);
    SFENCE();
    BARRIER();                           // all waves done reading buf[cur]
    stage(cur, (t + 2) * 64);            // overwrite buf[cur] with tile t+2
    VMWAIT(8); BARRIER(); SFENCE();      // tile t+1 resident everywhere
    cur ^= 1;
  }
  __builtin_amdgcn_s_setprio(1);
  mfma_block128(As[cur], Bs[cur], lane, wrow2, acc);      // tile 14
  __builtin_amdgcn_s_setprio(0);
  SFENCE();
  VMWAIT(0); BARRIER(); SFENCE();                         // tile 15 resident
  __builtin_amdgcn_s_setprio(1);
  mfma_block128(As[cur ^ 1], Bs[cur ^ 1], lane, wrow2, acc);  // tile 15
  __builtin_amdgcn_s_setprio(0);

  int col = lane & 15, quad = lane >> 4;
#pragma unroll
  for (int rf = 0; rf < 2; rf++)
#pragma unroll
    for (int r = 0; r < 4; r++) {
      int s = s0 + wrow2 + rf * 16 + quad * 4 + r;
      if (s < seg_end) {
#pragma unroll
        for (int nt = 0; nt < 8; nt++)
          Yd[(size_t)s * NH + nt * 16 + col] = f2bf(acc[rf][nt][r]);
      }
    }
}

// ------- combine Y slots -> token-major bf16 q/k + direct V^T (fused transpose) -------
// Q is pre-scaled by scale*log2(e) so flash works in exp2 domain.
__global__ __launch_bounds__(256) void k_combine_qkv(
    const __bf16* __restrict__ yq, const __bf16* __restrict__ yk, const __bf16* __restrict__ yv,
    const int* __restrict__ tok_slots, const int* __restrict__ tok_cnt,
    const float* __restrict__ slot_w,
    __bf16* __restrict__ qb, __bf16* __restrict__ kb, __bf16* __restrict__ vt) {
  __shared__ __bf16 vtile[128][34];
  int tid = threadIdx.x;
  int tok0 = blockIdx.x * 32;
  int tt = tok0 + (tid >> 3);
  int h0 = (tid & 7) * 16;
  const __bf16* Y = blockIdx.y == 0 ? yq : (blockIdx.y == 1 ? yk : yv);
  int cnt = tok_cnt[tt];
  float acc[16];
#pragma unroll
  for (int i = 0; i < 16; i++) acc[i] = 0.f;
  for (int j = 0; j < cnt; j++) {
    int s = tok_slots[tt * 16 + j];
    if (s < CAP) {
      float w = slot_w[s];
      bf16x8 v0 = *(const bf16x8*)(Y + (size_t)s * NH + h0);
      bf16x8 v1 = *(const bf16x8*)(Y + (size_t)s * NH + h0 + 8);
#pragma unroll
      for (int i = 0; i < 8; i++) { acc[i] += w * (float)v0[i]; acc[8 + i] += w * (float)v1[i]; }
    }
  }
  if (blockIdx.y == 2) {
    // V: LDS transpose tile [h][t], write VT [b][h][t] coalesced
#pragma unroll
    for (int i = 0; i < 16; i++) vtile[h0 + i][tid >> 3] = f2bf(acc[i]);
    __syncthreads();
    int h = tid >> 1, tp = (tid & 1) * 16;
    int b = tok0 >> 11, trow = tok0 & 2047;
    __bf16* dst = vt + ((size_t)b * NH + h) * NT + trow + tp;
    bf16x8 o0, o1;
#pragma unroll
    for (int i = 0; i < 8; i++) { o0[i] = vtile[h][tp + i]; o1[i] = vtile[h][tp + 8 + i]; }
    *(bf16x8*)dst = o0;
    *(bf16x8*)(dst + 8) = o1;
  } else {
    float sc = blockIdx.y == 0 ? 0.12751744458115337f : 1.0f;  // (1/sqrt(128))*log2(e)
    __bf16* D = blockIdx.y == 0 ? qb : kb;
    bf16x8 o0, o1;
#pragma unroll
    for (int i = 0; i < 8; i++) { o0[i] = f2bf(acc[i] * sc); o1[i] = f2bf(acc[8 + i] * sc); }
    __bf16* d = D + (size_t)tt * NH + h0;
    *(bf16x8*)d = o0;
    *(bf16x8*)(d + 8) = o1;
  }
}

// ---------------- flash attention: QK^T -> exp2-domain online softmax -> PV ----------------
// grid 512 = 4 b x 4 splits x 32 t-blocks (XCD-chunked). LDS: K 32K + V 32K + P 16K.
__global__ __launch_bounds__(256) void k_flash(const __bf16* __restrict__ q,
                                               const __bf16* __restrict__ k,
                                               const __bf16* __restrict__ vt,
                                               float* __restrict__ opart,
                                               float2* __restrict__ ml) {
  int id = blockIdx.x;
  int w = (id & 7) * 64 + (id >> 3);     // chunked bijective over 512
  int b = w >> 7;
  int rem = w & 127;
  int spl = rem >> 5;
  int t0 = (rem & 31) * 64;
  const __bf16* qb = q + (size_t)b * NT * NH;
  const __bf16* kb = k + (size_t)b * NT * NH;
  const __bf16* vtb = vt + (size_t)b * NH * NT;

  __shared__ __bf16 Ks[2][128 * 64];   // [d-chunk][s-row][64]
  __shared__ __bf16 Vs[2][128 * 64];   // [s-chunk][d-row][64]
  __shared__ __bf16 Ps[2][64 * 64];    // [s-chunk][t-row][64]
  int tid = threadIdx.x, lane = tid & 63, wid = tid >> 6, wrow = wid * 16;
  int colq = lane & 15, quad = lane >> 4;

  // Q fragments in registers (force-resolved before staging starts)
  bf16x8 qf[4];
  {
    const __bf16* qr = qb + (size_t)(t0 + wrow + colq) * NH + quad * 8;
#pragma unroll
    for (int kk = 0; kk < 4; kk++) qf[kk] = *(const bf16x8*)(qr + kk * 32);
  }
  asm volatile("" :: "v"(qf[0]), "v"(qf[1]), "v"(qf[2]), "v"(qf[3]));
  SFENCE();

  auto stage_K = [&](int s0) {
#pragma unroll
    for (int c = 0; c < 2; c++)
#pragma unroll
      for (int i = 0; i < 4; i++)
        gl_lds16(swz_src(kb + (size_t)s0 * NH + c * 64, NH, tid, i),
                 (char*)Ks[c] + wid * 1024 + i * 4096);
  };
  auto stage_V = [&](int s0) {
#pragma unroll
    for (int c = 0; c < 2; c++)
#pragma unroll
      for (int i = 0; i < 4; i++)
        gl_lds16(swz_src(vtb + s0 + c * 64, NT, tid, i),
                 (char*)Vs[c] + wid * 1024 + i * 4096);
  };

  f32x4 oacc[8];
#pragma unroll
  for (int i = 0; i < 8; i++) { f32x4 z = {0.f, 0.f, 0.f, 0.f}; oacc[i] = z; }
  float mr[4], lr[4];
#pragma unroll
  for (int r = 0; r < 4; r++) { mr[r] = -1e30f; lr[r] = 0.f; }

  const int sbase = spl * 512;
  stage_K(sbase);
  stage_V(sbase);
  VMWAIT(8); BARRIER(); SFENCE();        // K(0) resident; V(0) 8 loads in flight

  for (int t = 0; t < 4; t++) {
    // ---- QK^T for s-tile t (already in log2 domain via pre-scaled Q) ----
    f32x4 sacc[8];
#pragma unroll
    for (int i = 0; i < 8; i++) { f32x4 z = {0.f, 0.f, 0.f, 0.f}; sacc[i] = z; }
    __builtin_amdgcn_s_setprio(1);
    mfma_regA(qf[0], qf[1], Ks[0], lane, sacc);
    mfma_regA(qf[2], qf[3], Ks[1], lane, sacc);
    __builtin_amdgcn_s_setprio(0);
    SFENCE();
    BARRIER();                           // all waves done reading Ks
    if (t < 3) stage_K(sbase + (t + 1) * 128);   // +8 in flight

    // ---- online softmax (base 2); P -> LDS (own wave's rows only) ----
    float tm[4];
#pragma unroll
    for (int r = 0; r < 4; r++) {
      float v = sacc[0][r];
#pragma unroll
      for (int nt = 1; nt < 8; nt++) v = fmaxf(v, sacc[nt][r]);
      tm[r] = v;
    }
#pragma unroll
    for (int off = 1; off < 16; off <<= 1)
#pragma unroll
      for (int r = 0; r < 4; r++) tm[r] = fmaxf(tm[r], __shfl_xor(tm[r], off));
    float alpha[4], rs[4];
#pragma unroll
    for (int r = 0; r < 4; r++) {
      float mn = fmaxf(mr[r], tm[r]);
      alpha[r] = exp2f(mr[r] - mn);
      mr[r] = mn;
      rs[r] = 0.f;
    }
#pragma unroll
    for (int nt = 0; nt < 8; nt++) {
      char* pc = (char*)Ps[nt >> 2];
      int colb = ((nt & 3) * 16 + colq) * 2;
#pragma unroll
      for (int r = 0; r < 4; r++) {
        int row = wrow + quad * 4 + r;
        float p = exp2f(sacc[nt][r] - mr[r]);
        rs[r] += p;
        *(__bf16*)(pc + row * 128 + (colb ^ ((row & 7) << 4))) = f2bf(p);
      }
    }
#pragma unroll
    for (int off = 1; off < 16; off <<= 1)
#pragma unroll
      for (int r = 0; r < 4; r++) rs[r] += __shfl_xor(rs[r], off);
#pragma unroll
    for (int r = 0; r < 4; r++) lr[r] = alpha[r] * lr[r] + rs[r];
#pragma unroll
    for (int nt = 0; nt < 8; nt++)
#pragma unroll
      for (int r = 0; r < 4; r++) oacc[nt][r] *= alpha[r];

    LGKMWAIT0();                         // P writes done
    if (t < 3) { VMWAIT(8); } else { VMWAIT(0); }   // V(t) resident (own loads)
    BARRIER(); SFENCE();                 // everyone's V(t) + P ready

    // ---- PV ----
    __builtin_amdgcn_s_setprio(1);
    mfma_block(Ps[0], Vs[0], lane, wrow, oacc);
    mfma_block(Ps[1], Vs[1], lane, wrow, oacc);
    __builtin_amdgcn_s_setprio(0);
    SFENCE();
    BARRIER();                           // all done reading Vs, Ps
    if (t < 3) {
      stage_V(sbase + (t + 1) * 128);    // +8 -> 16 in flight
      VMWAIT(8); BARRIER(); SFENCE();    // K(t+1) resident
    }
  }

  // epilogue: unnormalized partial O + (m,l) in log2 domain
  size_t base = (size_t)(b * 4 + spl) * NT + t0;
#pragma unroll
  for (int r = 0; r < 4; r++) {
    size_t row = base + wrow + quad * 4 + r;
#pragma unroll
    for (int nt = 0; nt < 8; nt++)
      opart[row * NH + nt * 16 + colq] = oacc[nt][r];
  }
  if (colq == 0) {
#pragma unroll
    for (int r = 0; r < 4; r++) {
      float2 v; v.x = mr[r]; v.y = lr[r];
      ml[base + wrow + quad * 4 + r] = v;
    }
  }
}

// ---------------- gather o: merge 4 split partials (base-2 LSE) -> slot-major bf16 ----------------
__global__ __launch_bounds__(256) void k_gather_o(const float* __restrict__ opart,
                                                  const float2* __restrict__ ml,
                                                  const int* __restrict__ slot_token,
                                                  const int* __restrict__ counts,
                                                  __bf16* __restrict__ og) {
  int slot = blockIdx.x * 2 + (threadIdx.x >> 7);
  int h = threadIdx.x & 127;
  int total = 0;
#pragma unroll
  for (int e = 0; e < NE; e++) total += counts[e];
  if (total > CAP) total = CAP;
  if (slot >= total) return;
  int n = slot_token[slot];
  int b = n >> 11, trow = n & 2047;
  size_t rb = (size_t)b * 4 * NT + trow;
  float2 m0 = ml[rb], m1 = ml[rb + NT], m2 = ml[rb + 2 * NT], m3 = ml[rb + 3 * NT];
  float M = fmaxf(fmaxf(m0.x, m1.x), fmaxf(m2.x, m3.x));
  float e0 = exp2f(m0.x - M), e1 = exp2f(m1.x - M), e2 = exp2f(m2.x - M), e3 = exp2f(m3.x - M);
  float den = m0.y * e0 + m1.y * e1 + m2.y * e2 + m3.y * e3;
  float num = opart[rb * NH + h] * e0 + opart[(rb + NT) * NH + h] * e1 +
              opart[(rb + 2 * NT) * NH + h] * e2 + opart[(rb + 3 * NT) * NH + h] * e3;
  og[(size_t)slot * NH + h] = f2bf(num / den);
}

// ------- grouped GEMM: out-proj, BM=128, 2 N-chunks/block (A staged once) -------
__global__ __launch_bounds__(256) void k_out2(
    const __bf16* __restrict__ og, const __bf16* __restrict__ pot,
    const int* __restrict__ counts, __bf16* __restrict__ zy) {
  int id = blockIdx.x;
  int w = (id & 7) * (4 * NT2_MAX / 8) + (id >> 3);  // chunked bijective (608)
  int ti = w >> 2, p = w & 3;                        // p = 256-wide nc chunk 0..3
  int e, s0, seg_end;
  if (!locate_tile(counts, ti, e, s0, seg_end)) return;
  int nc0 = p * 256;
  const __bf16* Bt = pot + (size_t)e * NC * NH;

  __shared__ __bf16 As[2][128 * 64];
  __shared__ __bf16 Bs[2][128 * 64];
  int tid = threadIdx.x, lane = tid & 63, wid = tid >> 6, wrow2 = wid * 32;
  const __bf16* asrc[4];
  const __bf16* bsrc[4];
#pragma unroll
  for (int i = 0; i < 4; i++) asrc[i] = swz_src(og + (size_t)s0 * NH, NH, tid, i);
#pragma unroll
  for (int i = 0; i < 4; i++) bsrc[i] = swz_src(Bt + (size_t)nc0 * NH, NH, tid, i);
  auto stageA = [&](int buf, int k0) {
#pragma unroll
    for (int i = 0; i < 4; i++)
      gl_lds16(asrc[i] + k0, (char*)As[buf] + tid * 16 + i * 4096);
  };
  auto stageB = [&](int buf, int k0, int noff) {
#pragma unroll
    for (int i = 0; i < 4; i++)
      gl_lds16(bsrc[i] + (size_t)noff * NH + k0, (char*)Bs[buf] + tid * 16 + i * 4096);
  };
  f32x4 acc[2][8];
  int col = lane & 15, quad = lane >> 4;
  auto store_acc = [&](int nco) {
#pragma unroll
    for (int rf = 0; rf < 2; rf++)
#pragma unroll
      for (int r = 0; r < 4; r++) {
        int s = s0 + wrow2 + rf * 16 + quad * 4 + r;
        if (s < seg_end) {
#pragma unroll
          for (int nt = 0; nt < 8; nt++)
            zy[(size_t)s * NC + nco + nt * 16 + col] = f2bf(acc[rf][nt][r]);
        }
      }
  };

#pragma unroll
  for (int rf = 0; rf < 2; rf++)
#pragma unroll
    for (int i = 0; i < 8; i++) { f32x4 z = {0.f, 0.f, 0.f, 0.f}; acc[rf][i] = z; }

  // A (full K=128) staged once; B re-staged per 128-wide n-chunk.
  stageA(0, 0); stageB(0, 0, 0);        // first 8: As[0] + Bs[0] (chunk 0)
  stageA(1, 64); stageB(1, 64, 0);
  VMWAIT(8); BARRIER(); SFENCE();
  __builtin_amdgcn_s_setprio(1);
  mfma_block128(As[0], Bs[0], lane, wrow2, acc);
  __builtin_amdgcn_s_setprio(0);
  SFENCE();
  VMWAIT(0); BARRIER(); SFENCE();
  __builtin_amdgcn_s_setprio(1);
  mfma_block128(As[1], Bs[1], lane, wrow2, acc);
  __builtin_amdgcn_s_setprio(0);
  SFENCE();
  store_acc(nc0);
  BARRIER();                            // all waves done reading Bs
  stageB(0, 0, 128); stageB(1, 64, 128);   // B for chunk 1; As untouched
#pragma unroll
  for (int rf = 0; rf < 2; rf++)
#pragma unroll
    for (int i = 0; i < 8; i++) { f32x4 z = {0.f, 0.f, 0.f, 0.f}; acc[rf][i] = z; }
  VMWAIT(0); BARRIER(); SFENCE();
  __builtin_amdgcn_s_setprio(1);
  mfma_block128(As[0], Bs[0], lane, wrow2, acc);
  mfma_block128(As[1], Bs[1], lane, wrow2, acc);
  __builtin_amdgcn_s_setprio(0);
  store_acc(nc0 + 128);
}

// ---------------- combine ZY slots -> dense fp32 out ----------------
__global__ __launch_bounds__(256) void k_combine_out(
    const __bf16* __restrict__ zy, const int* __restrict__ tok_slots,
    const int* __restrict__ tok_cnt, const float* __restrict__ slot_w,
    float* __restrict__ out) {
  int token = blockIdx.x;
  int c = threadIdx.x * 4;
  int cnt = tok_cnt[token];
  float a0 = 0.f, a1 = 0.f, a2 = 0.f, a3 = 0.f;
  for (int j = 0; j < cnt; j++) {
    int s = tok_slots[token * 16 + j];
    if (s < CAP) {
      float w = slot_w[s];
      bf16x4 z = *(const bf16x4*)&zy[(size_t)s * NC + c];
      a0 += w * (float)z[0];
      a1 += w * (float)z[1];
      a2 += w * (float)z[2];
      a3 += w * (float)z[3];
    }
  }
  float4 o = {a0, a1, a2, a3};
  *(float4*)&out[(size_t)token * NC + c] = o;
}

extern "C" void kernel_launch(void* const* d_in, const int* in_sizes, int n_in,
                              void* d_out, int out_size, void* d_ws, size_t ws_size,
                              hipStream_t stream) {
  const float* hs    = (const float*)d_in[0];  // [4,2048,1024]
  const float* sim   = (const float*)d_in[1];  // [1024,16]
  const float* gates = (const float*)d_in[2];  // [16]
  const float* qp    = (const float*)d_in[3];  // [16,1024,128]
  const float* kp    = (const float*)d_in[4];
  const float* vp    = (const float*)d_in[5];
  const float* op    = (const float*)d_in[6];  // [16,128,1024]
  float* out = (float*)d_out;
  char* ws = (char*)d_ws;

  // ---- workspace arena (aliased by lifetime) ----
  const size_t M = 1048576;
  __bf16* PQT = (__bf16*)(ws + 0 * M);         // 4 MiB each
  __bf16* PKT = (__bf16*)(ws + 4 * M);
  __bf16* PVT = (__bf16*)(ws + 8 * M);
  __bf16* POT = (__bf16*)(ws + 12 * M);
  __bf16* Qb  = (__bf16*)(ws + 16 * M);        // 2 MiB each, token-major bf16
  __bf16* Kb  = (__bf16*)(ws + 18 * M);
  __bf16* VT  = (__bf16*)(ws + 22 * M);        // 2 MiB [b][h][t]
  float*  WALL = (float*)(ws + 28 * M);        // 512 KiB
  int*    STOK = (int*)(ws + 28 * M + 524288); // 512 KiB
  float*  SW   = (float*)(ws + 28 * M + 1048576);
  int*    TSL  = (int*)(ws + 28 * M + 1572864);  // tok_slots 512 KiB
  int*    TCN  = (int*)(ws + 28 * M + 2097152);  // tok_cnt 32 KiB
  double* SNORM = (double*)(ws + 28 * M + 2129920);
  double* SIG   = SNORM + 16;
  int* CNT = (int*)(ws + 28 * M + 2130432);    // control block (zeroed in prep)
  int* CUR = CNT + 40;
  // R region (32M..96M), aliased by lifetime:
  __bf16* XBF = (__bf16*)(ws + 32 * M);        // 16.8 MiB dense bf16 x (dies after qkv2)
  __bf16* YQ = (__bf16*)(ws + 72 * M);         // 4.5 MiB each (die before flash)
  __bf16* YK = (__bf16*)(ws + 77 * M);
  __bf16* YV = (__bf16*)(ws + 82 * M);
  float*  OP2 = (float*)(ws + 32 * M);         // 16.8 MiB partial O (after XBF dead)
  float2* MLB = (float2*)(ws + 50 * M);        // 256 KiB (m,l) per split-row
  __bf16* OG = (__bf16*)(ws + 52 * M);         // 4.5 MiB
  __bf16* ZY = (__bf16*)(ws + 60 * M);         // 36.1 MiB

  k_transpose_all<<<dim3(128, 65), 256, 0, stream>>>(qp, kp, vp, op, PQT, PKT, PVT, POT,
                                                     sim, gates, SNORM, SIG, CNT);
  k_gating3<<<NTOK / 16, 256, 0, stream>>>(hs, sim, SNORM, SIG, WALL, CNT, XBF);
  k_assign<<<NTOK / 256, 256, 0, stream>>>(WALL, CNT, CUR, STOK, SW, TSL, TCN);
  k_moe_qkv2<<<3 * NT2_MAX, 256, 0, stream>>>(XBF, STOK, PQT, PKT, PVT, CNT, YQ, YK, YV);
  k_combine_qkv<<<dim3(NTOK / 32, 3), 256, 0, stream>>>(YQ, YK, YV, TSL, TCN, SW, Qb, Kb, VT);
  k_flash<<<512, 256, 0, stream>>>(Qb, Kb, VT, OP2, MLB);
  k_gather_o<<<CAP / 2, 256, 0, stream>>>(OP2, MLB, STOK, CNT, OG);
  k_out2<<<4 * NT2_MAX, 256, 0, stream>>>(OG, POT, CNT, ZY);
  k_combine_out<<<NTOK, 256, 0, stream>>>(ZY, TSL, TCN, SW, out);
}

// Round 14
// 251.724 us; speedup vs baseline: 1.4763x; 1.0558x over previous
//
#include <hip/hip_runtime.h>
#include <hip/hip_bf16.h>
#include <math.h>

// DynSMHA: B=4 T=2048 C=1024 H=128 E=16 MIN_E=2, non-causal.
// memset ctrl -> fp64 gating (16 tok/block, in-block sim-norm/sigmoid prep,
// atomic counts, emits dense bf16 x) -> fused {ballot slot-assign || weight
// transposes} -> grouped GEMMs (BM=128, indirect A-gather, counted-vmcnt,
// XOR-swizzled LDS, tiles located from counts) -> flash attention (exp2-domain
// online softmax, split-s LSE) -> combines.
#define NBATCH 4
#define NT     2048
#define NC     1024
#define NH     128
#define NE     16
#define NTOK   (NBATCH * NT)
#define CAP    18432         // slot capacity (actual ~16384)
#define NT2_MAX 152          // sum ceil(cnt_e/128) + slack; multiple of 8

typedef __bf16 bf16x8 __attribute__((ext_vector_type(8)));
typedef __bf16 bf16x4 __attribute__((ext_vector_type(4)));
typedef float  f32x4  __attribute__((ext_vector_type(4)));

__device__ __forceinline__ __bf16 f2bf(float f) { return (__bf16)f; }

#define BARRIER() __builtin_amdgcn_s_barrier()
#define SFENCE()  __builtin_amdgcn_sched_barrier(0)
#define VMWAIT(n) asm volatile("s_waitcnt vmcnt(" #n ")" ::: "memory")
#define LGKMWAIT0() asm volatile("s_waitcnt lgkmcnt(0)" ::: "memory")

// async global->LDS, 16B per lane; LDS dest = wave-uniform base + lane*16
__device__ __forceinline__ void gl_lds16(const void* g, void* l) {
  __builtin_amdgcn_global_load_lds((const __attribute__((address_space(1))) void*)g,
                                   (__attribute__((address_space(3))) void*)l, 16, 0, 0);
}

// Pre-swizzled global source (swizzle BOTH sides or neither).
// LDS tile is [rows][64] bf16, linear 128B rows; swizzle byte ^= ((row&7)<<4).
__device__ __forceinline__ const __bf16* swz_src(const __bf16* row0, size_t stride,
                                                 int tid, int i) {
  int lin = (tid + 256 * i) * 16;
  int r = lin >> 7, cb = lin & 127;
  return row0 + (size_t)r * stride + ((cb ^ ((r & 7) << 4)) >> 1);
}

// Locate 128-row tile ti from per-expert counts (same semantics as old k_scan).
__device__ __forceinline__ bool locate_tile(const int* __restrict__ counts, int ti,
                                            int& e_out, int& s0_out, int& seg_end_out) {
  int off = 0, nt = 0, e = -1, s0 = 0, seg_end = 0;
#pragma unroll
  for (int ee = 0; ee < NE; ee++) {
    int c = counts[ee];
    int tiles = (c + 127) >> 7;
    if (e < 0 && ti < nt + tiles) {
      e = ee;
      s0 = off + (ti - nt) * 128;
      seg_end = off + c;
    }
    nt += tiles;
    off += c;
  }
  if (e < 0 || s0 >= CAP) return false;
  if (seg_end > CAP) seg_end = CAP;
  e_out = e; s0_out = s0; seg_end_out = seg_end;
  return true;
}

// ------- gating: 16 tok/block (512 blocks), chunked LDS, f64 acc, in-block prep -------
// Wave 0 accumulates sim column-norms from the staged sim tile (padded snred —
// no bank conflicts). sigmoid(gates) computed per block. Emits dense bf16 x.
__global__ __launch_bounds__(256, 2) void k_gating3(const float* __restrict__ x,
                                                    const float* __restrict__ sim,
                                                    const float* __restrict__ gates,
                                                    float* __restrict__ w_all,
                                                    int* __restrict__ counts,
                                                    __bf16* __restrict__ xbf) {
  __shared__ union {
    struct {
      float xs_[16][66];    // [token][col-in-chunk]
      float ss_[16][66];    // [e][col-in-chunk]
    } s;
    double red[8][32][2][17];  // [tkg][cg][t][dot0..15,norm] = 69632 B
  } u;
  __shared__ double snred[32][17];   // padded: conflict-free f64 rows
  __shared__ double snorm_lds[16];
  __shared__ double sig_lds[16];
  __shared__ float w_lds[16][16];
  __shared__ int cnt_lds[16];
  int tid = threadIdx.x;
  if (tid < 16) {
    cnt_lds[tid] = 0;
    sig_lds[tid] = 1.0 / (1.0 + exp(-(double)gates[tid]));
  }
  int cg = tid & 31, tkg = tid >> 5;
  int tok0 = blockIdx.x * 16;

  double acc[2][17];
#pragma unroll
  for (int t = 0; t < 2; t++)
#pragma unroll
    for (int i = 0; i < 17; i++) acc[t][i] = 0.0;
  double sn[16];
#pragma unroll
  for (int i = 0; i < 16; i++) sn[i] = 0.0;
  bool dosn = tid < 64;   // wave-uniform: wave 0 accumulates sim norms

  // staging roles
  int xr0 = tid >> 4, xc4 = (tid & 15) * 4;   // x row xr0, 4 cols
  int sr = tid >> 2, se4 = (tid & 3) * 4;     // sim row c0+sr, 4 experts

  float4 xa, sv;
  auto ldchunk = [&](int c0) {
    xa = *(const float4*)(x + (size_t)(tok0 + xr0) * NC + c0 + xc4);
    sv = *(const float4*)(sim + (size_t)(c0 + sr) * NE + se4);
  };
  auto stchunk = [&]() {
    *(float4*)&u.s.xs_[xr0][xc4] = xa;
    u.s.ss_[se4 + 0][sr] = sv.x;
    u.s.ss_[se4 + 1][sr] = sv.y;
    u.s.ss_[se4 + 2][sr] = sv.z;
    u.s.ss_[se4 + 3][sr] = sv.w;
  };
  auto stxbf = [&](int c0) {   // dense bf16 emit (xa still live)
    bf16x4 a;
    a[0]=f2bf(xa.x); a[1]=f2bf(xa.y); a[2]=f2bf(xa.z); a[3]=f2bf(xa.w);
    *(bf16x4*)(xbf + (size_t)(tok0 + xr0) * NC + c0 + xc4) = a;
  };

  ldchunk(0);
  for (int ch = 0; ch < 16; ch++) {
    stchunk();
    stxbf(ch * 64);
    __syncthreads();
    if (ch < 15) ldchunk((ch + 1) * 64);   // prefetch next chunk into regs
    double xd[2][2];
#pragma unroll
    for (int t = 0; t < 2; t++) {
      float2 xv = *(const float2*)&u.s.xs_[tkg * 2 + t][cg * 2];
      xd[t][0] = (double)xv.x;
      xd[t][1] = (double)xv.y;
      acc[t][16] += xd[t][0] * xd[t][0] + xd[t][1] * xd[t][1];
    }
#pragma unroll
    for (int e = 0; e < 16; e++) {
      float2 sv2 = *(const float2*)&u.s.ss_[e][cg * 2];
      double s0 = (double)sv2.x, s1 = (double)sv2.y;
#pragma unroll
      for (int t = 0; t < 2; t++)
        acc[t][e] += xd[t][0] * s0 + xd[t][1] * s1;
      if (dosn) sn[e] += s0 * s0 + s1 * s1;
    }
    __syncthreads();
  }

  // one-shot LDS reduce (xs_/ss_ dead; union'd)
#pragma unroll
  for (int t = 0; t < 2; t++)
#pragma unroll
    for (int i = 0; i < 17; i++)
      u.red[tkg][cg][t][i] = acc[t][i];
  if (tid < 32)
#pragma unroll
    for (int e = 0; e < 16; e++) snred[tid][e] = sn[e];
  __syncthreads();

  if (tid < 16) {   // sim norms (f64 reassociation vs old prep: ulp-only, r10-verified)
    double s = 0.0;
    for (int c = 0; c < 32; c++) s += snred[c][tid];
    snorm_lds[tid] = fmax(sqrt(s), 1e-12);
  }
  __syncthreads();

  if (tid < 16) {
    double dots[17];
    for (int i = 0; i < 17; i++) {
      double s = 0.0;
      for (int c = 0; c < 32; c++) s += u.red[tid >> 1][c][tid & 1][i];
      dots[i] = s;
    }
    double xn = fmax(sqrt(dots[16]), 1e-12);
    double logits[NE];
    unsigned act = 0;
    int cnt = 0;
    for (int ee = 0; ee < NE; ee++) {
      logits[ee] = dots[ee] / (xn * snorm_lds[ee]) - sig_lds[ee];
      if (logits[ee] > 0.0) { act |= 1u << ee; cnt++; }
    }
    if (cnt == 0) {  // top-MIN_E(=2) fallback, lowest-index tie-break
      int i1 = 0; double b1 = logits[0];
      for (int ee = 1; ee < NE; ee++) if (logits[ee] > b1) { b1 = logits[ee]; i1 = ee; }
      int i2 = -1; double b2 = -1e300;
      for (int ee = 0; ee < NE; ee++) if (ee != i1 && logits[ee] > b2) { b2 = logits[ee]; i2 = ee; }
      act = (1u << i1) | (1u << i2);
    }
    double m = -1e300;
    for (int ee = 0; ee < NE; ee++) if ((act >> ee) & 1) m = fmax(m, fmax(logits[ee], 0.0));
    double s = 0.0, wvv[NE];
    for (int ee = 0; ee < NE; ee++) {
      if ((act >> ee) & 1) { wvv[ee] = exp(fmax(logits[ee], 0.0) - m); s += wvv[ee]; }
      else wvv[ee] = 0.0;
    }
    for (int ee = 0; ee < NE; ee++) {
      if ((act >> ee) & 1) {
        w_lds[tid][ee] = (float)(wvv[ee] / s);
        atomicAdd(&cnt_lds[ee], 1);
      } else w_lds[tid][ee] = 0.0f;
    }
  }
  __syncthreads();
  w_all[(size_t)(tok0 + (tid >> 4)) * NE + (tid & 15)] = w_lds[tid >> 4][tid & 15];
  if (tid < 16 && cnt_lds[tid] > 0) atomicAdd(&counts[tid], cnt_lds[tid]);
}

// ------- fused: ballot slot-assign (32 blocks) || weight transposes (8192 blocks) -------
// Both paths are light (<=4.2KB LDS, ~48 VGPR) -> high occupancy for the
// BW-bound transposes; the independent transpose work hides the assign latency.
__global__ __launch_bounds__(256) void k_assign_tr(
    const float* __restrict__ w_all, const int* __restrict__ counts,
    int* __restrict__ cursors, int* __restrict__ slot_token,
    float* __restrict__ slot_w, int* __restrict__ tok_slots, int* __restrict__ tok_cnt,
    const float* __restrict__ qp, const float* __restrict__ kp,
    const float* __restrict__ vp, const float* __restrict__ op,
    __bf16* __restrict__ pqt, __bf16* __restrict__ pkt,
    __bf16* __restrict__ pvt, __bf16* __restrict__ pot) {
  __shared__ float tile[32][33];
  int id = blockIdx.x;
  int tid = threadIdx.x;

  if (id < 32) {   // ---- slot assignment (inline count prefix) ----
    int n = id * 256 + tid;
    int lane = tid & 63;
    int j = 0;
    int off = 0;
#pragma unroll
    for (int e = 0; e < NE; e++) {
      float w = w_all[(size_t)n * NE + e];
      bool a = w > 0.0f;
      unsigned long long mask = __ballot(a);
      if (mask) {
        int leader = (int)__ffsll((long long)mask) - 1;
        int base = 0;
        if (lane == leader) base = atomicAdd(&cursors[e], (int)__popcll(mask));
        base = __shfl(base, leader);
        if (a) {
          int pos = base + (int)__popcll(mask & ((1ULL << lane) - 1ULL));
          int s = off + pos;
          slot_token[s] = n;
          slot_w[s] = w;
          tok_slots[n * 16 + j] = s;
          j++;
        }
      }
      off += counts[e];
    }
    tok_cnt[n] = j;
    return;
  }

  // ---- weight transpose (fp32 -> bf16) ----
  int t2 = id - 32;
  int z = t2 >> 7, xb = t2 & 127;
  const float* in;
  __bf16* out;
  int R, Cd, g, r0, c0;
  if (z < 48) {
    int which = z >> 4; g = z & 15; R = 1024; Cd = 128;
    in = which == 0 ? qp : (which == 1 ? kp : vp);
    out = which == 0 ? pqt : (which == 1 ? pkt : pvt);
    r0 = (xb >> 2) * 32; c0 = (xb & 3) * 32;
  } else {
    g = z - 48; R = 128; Cd = 1024;
    in = op; out = pot;
    r0 = (xb & 3) * 32; c0 = (xb >> 2) * 32;
  }
  int tx = tid & 31, ty0 = tid >> 5;
  const float* src = in + (size_t)g * R * Cd;
  __bf16* dst = out + (size_t)g * R * Cd;
#pragma unroll
  for (int ty = ty0; ty < 32; ty += 8)
    tile[ty][tx] = src[(size_t)(r0 + ty) * Cd + (c0 + tx)];
  __syncthreads();
#pragma unroll
  for (int ty = ty0; ty < 32; ty += 8)
    dst[(size_t)(c0 + ty) * R + (r0 + tx)] = f2bf(tile[tx][ty]);
}

// ---------------- MFMA tiles on XOR-swizzled LDS ----------------
// 64x128 (A rows 64): used by flash.
__device__ __forceinline__ void mfma_block(const __bf16* As, const __bf16* Bs,
                                           int lane, int wrow, f32x4 acc[8]) {
  const char* Ab = (const char*)As;
  const char* Bb = (const char*)Bs;
  int arow = wrow + (lane & 15);
  int rb = lane & 15;
#pragma unroll
  for (int ks = 0; ks < 2; ks++) {
    int kb = ks * 64 + (lane >> 4) * 16;   // byte offset within 128B row
    bf16x8 af = *(const bf16x8*)(Ab + arow * 128 + (kb ^ ((arow & 7) << 4)));
#pragma unroll
    for (int nt = 0; nt < 8; nt++) {
      int brow = nt * 16 + rb;
      bf16x8 bv = *(const bf16x8*)(Bb + brow * 128 + (kb ^ ((brow & 7) << 4)));
      acc[nt] = __builtin_amdgcn_mfma_f32_16x16x32_bf16(af, bv, acc[nt], 0, 0, 0);
    }
  }
}

// 128x128 (A rows 128, wave owns 32 A-rows): grouped GEMMs.
__device__ __forceinline__ void mfma_block128(const __bf16* As, const __bf16* Bs,
                                              int lane, int wrow2, f32x4 acc[2][8]) {
  const char* Ab = (const char*)As;
  const char* Bb = (const char*)Bs;
  int rb = lane & 15;
#pragma unroll
  for (int ks = 0; ks < 2; ks++) {
    int kb = ks * 64 + (lane >> 4) * 16;
    int ar = wrow2 + rb;                   // (ar&7) == ((ar+16)&7)
    int sw = kb ^ ((ar & 7) << 4);
    bf16x8 af0 = *(const bf16x8*)(Ab + ar * 128 + sw);
    bf16x8 af1 = *(const bf16x8*)(Ab + (ar + 16) * 128 + sw);
#pragma unroll
    for (int nt = 0; nt < 8; nt++) {
      int brow = nt * 16 + rb;
      bf16x8 bv = *(const bf16x8*)(Bb + brow * 128 + (kb ^ ((brow & 7) << 4)));
      acc[0][nt] = __builtin_amdgcn_mfma_f32_16x16x32_bf16(af0, bv, acc[0][nt], 0, 0, 0);
      acc[1][nt] = __builtin_amdgcn_mfma_f32_16x16x32_bf16(af1, bv, acc[1][nt], 0, 0, 0);
    }
  }
}

// A-operand from registers (Q frags), B from swizzled LDS
__device__ __forceinline__ void mfma_regA(bf16x8 af0, bf16x8 af1, const __bf16* Bs,
                                          int lane, f32x4 acc[8]) {
  const char* Bb = (const char*)Bs;
  int rb = lane & 15;
#pragma unroll
  for (int ks = 0; ks < 2; ks++) {
    int kb = ks * 64 + (lane >> 4) * 16;
    bf16x8 af = ks ? af1 : af0;
#pragma unroll
    for (int nt = 0; nt < 8; nt++) {
      int brow = nt * 16 + rb;
      bf16x8 bv = *(const bf16x8*)(Bb + brow * 128 + (kb ^ ((brow & 7) << 4)));
      acc[nt] = __builtin_amdgcn_mfma_f32_16x16x32_bf16(af, bv, acc[nt], 0, 0, 0);
    }
  }
}

// ------- grouped GEMM: QKV projections, BM=128, indirect A-gather, counted vmcnt -------
__global__ __launch_bounds__(256) void k_moe_qkv2(
    const __bf16* __restrict__ xbf, const int* __restrict__ slot_token,
    const __bf16* __restrict__ pq, const __bf16* __restrict__ pk, const __bf16* __restrict__ pv,
    const int* __restrict__ counts,
    __bf16* __restrict__ yq, __bf16* __restrict__ yk, __bf16* __restrict__ yv) {
  int id = blockIdx.x;
  int w = (id & 7) * (3 * NT2_MAX / 8) + (id >> 3);  // chunked bijective (456)
  int ti = w / 3, p = w % 3;
  int e, s0, seg_end;
  if (!locate_tile(counts, ti, e, s0, seg_end)) return;
  const __bf16* Bt;
  __bf16* Yd;
  if (p == 0)      { Bt = pq; Yd = yq; }
  else if (p == 1) { Bt = pk; Yd = yk; }
  else             { Bt = pv; Yd = yv; }
  Bt += (size_t)e * NH * NC;

  __shared__ __bf16 As[2][128 * 64];
  __shared__ __bf16 Bs[2][128 * 64];
  int tid = threadIdx.x, lane = tid & 63, wid = tid >> 6, wrow2 = wid * 32;
  // per-lane indirect A source: row r of tile -> token slot_token[s0+r]
  const __bf16* asrc[4];
  const __bf16* bsrc[4];
#pragma unroll
  for (int i = 0; i < 4; i++) {
    int lin = (tid + 256 * i) * 16;
    int r = lin >> 7, cb = lin & 127;
    int tok = slot_token[s0 + r] & (NTOK - 1);   // mask poisoned tails
    asrc[i] = xbf + (size_t)tok * NC + ((cb ^ ((r & 7) << 4)) >> 1);
  }
#pragma unroll
  for (int i = 0; i < 4; i++) bsrc[i] = swz_src(Bt, NC, tid, i);
  auto stage = [&](int buf, int k0) {
#pragma unroll
    for (int i = 0; i < 4; i++)
      gl_lds16(asrc[i] + k0, (char*)As[buf] + tid * 16 + i * 4096);
#pragma unroll
    for (int i = 0; i < 4; i++)
      gl_lds16(bsrc[i] + k0, (char*)Bs[buf] + tid * 16 + i * 4096);
  };

  f32x4 acc[2][8];
#pragma unroll
  for (int rf = 0; rf < 2; rf++)
#pragma unroll
    for (int i = 0; i < 8; i++) { f32x4 z = {0.f, 0.f, 0.f, 0.f}; acc[rf][i] = z; }

  // 16 K-steps, 2 LDS buffers, 2 tiles (16 loads/wave) always in flight.
  stage(0, 0);
  stage(1, 64);
  VMWAIT(8); BARRIER(); SFENCE();        // tile 0 resident everywhere
  int cur = 0;
  for (int t = 0; t <= 13; t++) {        // compute tile t; stage tile t+2
    __builtin_amdgcn_s_setprio(1);
    mfma_block128(As[cur], Bs[cur], lane, wrow2, acc);
    __builtin_amdgcn_s_setprio(0);
    SFENCE();
    BARRIER();                           // all waves done reading buf[cur]
    stage(cur, (t + 2) * 64);            // overwrite buf[cur] with tile t+2
    VMWAIT(8); BARRIER(); SFENCE();      // tile t+1 resident everywhere
    cur ^= 1;
  }
  __builtin_amdgcn_s_setprio(1);
  mfma_block128(As[cur], Bs[cur], lane, wrow2, acc);      // tile 14
  __builtin_amdgcn_s_setprio(0);
  SFENCE();
  VMWAIT(0); BARRIER(); SFENCE();                         // tile 15 resident
  __builtin_amdgcn_s_setprio(1);
  mfma_block128(As[cur ^ 1], Bs[cur ^ 1], lane, wrow2, acc);  // tile 15
  __builtin_amdgcn_s_setprio(0);

  int col = lane & 15, quad = lane >> 4;
#pragma unroll
  for (int rf = 0; rf < 2; rf++)
#pragma unroll
    for (int r = 0; r < 4; r++) {
      int s = s0 + wrow2 + rf * 16 + quad * 4 + r;
      if (s < seg_end) {
#pragma unroll
        for (int nt = 0; nt < 8; nt++)
          Yd[(size_t)s * NH + nt * 16 + col] = f2bf(acc[rf][nt][r]);
      }
    }
}

// ------- combine Y slots -> token-major bf16 q/k + direct V^T (fused transpose) -------
// Q is pre-scaled by scale*log2(e) so flash works in exp2 domain.
__global__ __launch_bounds__(256) void k_combine_qkv(
    const __bf16* __restrict__ yq, const __bf16* __restrict__ yk, const __bf16* __restrict__ yv,
    const int* __restrict__ tok_slots, const int* __restrict__ tok_cnt,
    const float* __restrict__ slot_w,
    __bf16* __restrict__ qb, __bf16* __restrict__ kb, __bf16* __restrict__ vt) {
  __shared__ __bf16 vtile[128][34];
  int tid = threadIdx.x;
  int tok0 = blockIdx.x * 32;
  int tt = tok0 + (tid >> 3);
  int h0 = (tid & 7) * 16;
  const __bf16* Y = blockIdx.y == 0 ? yq : (blockIdx.y == 1 ? yk : yv);
  int cnt = tok_cnt[tt];
  float acc[16];
#pragma unroll
  for (int i = 0; i < 16; i++) acc[i] = 0.f;
  for (int j = 0; j < cnt; j++) {
    int s = tok_slots[tt * 16 + j];
    if (s < CAP) {
      float w = slot_w[s];
      bf16x8 v0 = *(const bf16x8*)(Y + (size_t)s * NH + h0);
      bf16x8 v1 = *(const bf16x8*)(Y + (size_t)s * NH + h0 + 8);
#pragma unroll
      for (int i = 0; i < 8; i++) { acc[i] += w * (float)v0[i]; acc[8 + i] += w * (float)v1[i]; }
    }
  }
  if (blockIdx.y == 2) {
    // V: LDS transpose tile [h][t], write VT [b][h][t] coalesced
#pragma unroll
    for (int i = 0; i < 16; i++) vtile[h0 + i][tid >> 3] = f2bf(acc[i]);
    __syncthreads();
    int h = tid >> 1, tp = (tid & 1) * 16;
    int b = tok0 >> 11, trow = tok0 & 2047;
    __bf16* dst = vt + ((size_t)b * NH + h) * NT + trow + tp;
    bf16x8 o0, o1;
#pragma unroll
    for (int i = 0; i < 8; i++) { o0[i] = vtile[h][tp + i]; o1[i] = vtile[h][tp + 8 + i]; }
    *(bf16x8*)dst = o0;
    *(bf16x8*)(dst + 8) = o1;
  } else {
    float sc = blockIdx.y == 0 ? 0.12751744458115337f : 1.0f;  // (1/sqrt(128))*log2(e)
    __bf16* D = blockIdx.y == 0 ? qb : kb;
    bf16x8 o0, o1;
#pragma unroll
    for (int i = 0; i < 8; i++) { o0[i] = f2bf(acc[i] * sc); o1[i] = f2bf(acc[8 + i] * sc); }
    __bf16* d = D + (size_t)tt * NH + h0;
    *(bf16x8*)d = o0;
    *(bf16x8*)(d + 8) = o1;
  }
}

// ---------------- flash attention: QK^T -> exp2-domain online softmax -> PV ----------------
// grid 512 = 4 b x 4 splits x 32 t-blocks (XCD-chunked). LDS: K 32K + V 32K + P 16K.
__global__ __launch_bounds__(256) void k_flash(const __bf16* __restrict__ q,
                                               const __bf16* __restrict__ k,
                                               const __bf16* __restrict__ vt,
                                               float* __restrict__ opart,
                                               float2* __restrict__ ml) {
  int id = blockIdx.x;
  int w = (id & 7) * 64 + (id >> 3);     // chunked bijective over 512
  int b = w >> 7;
  int rem = w & 127;
  int spl = rem >> 5;
  int t0 = (rem & 31) * 64;
  const __bf16* qb = q + (size_t)b * NT * NH;
  const __bf16* kb = k + (size_t)b * NT * NH;
  const __bf16* vtb = vt + (size_t)b * NH * NT;

  __shared__ __bf16 Ks[2][128 * 64];   // [d-chunk][s-row][64]
  __shared__ __bf16 Vs[2][128 * 64];   // [s-chunk][d-row][64]
  __shared__ __bf16 Ps[2][64 * 64];    // [s-chunk][t-row][64]
  int tid = threadIdx.x, lane = tid & 63, wid = tid >> 6, wrow = wid * 16;
  int colq = lane & 15, quad = lane >> 4;

  // Q fragments in registers (force-resolved before staging starts)
  bf16x8 qf[4];
  {
    const __bf16* qr = qb + (size_t)(t0 + wrow + colq) * NH + quad * 8;
#pragma unroll
    for (int kk = 0; kk < 4; kk++) qf[kk] = *(const bf16x8*)(qr + kk * 32);
  }
  asm volatile("" :: "v"(qf[0]), "v"(qf[1]), "v"(qf[2]), "v"(qf[3]));
  SFENCE();

  auto stage_K = [&](int s0) {
#pragma unroll
    for (int c = 0; c < 2; c++)
#pragma unroll
      for (int i = 0; i < 4; i++)
        gl_lds16(swz_src(kb + (size_t)s0 * NH + c * 64, NH, tid, i),
                 (char*)Ks[c] + wid * 1024 + i * 4096);
  };
  auto stage_V = [&](int s0) {
#pragma unroll
    for (int c = 0; c < 2; c++)
#pragma unroll
      for (int i = 0; i < 4; i++)
        gl_lds16(swz_src(vtb + s0 + c * 64, NT, tid, i),
                 (char*)Vs[c] + wid * 1024 + i * 4096);
  };

  f32x4 oacc[8];
#pragma unroll
  for (int i = 0; i < 8; i++) { f32x4 z = {0.f, 0.f, 0.f, 0.f}; oacc[i] = z; }
  float mr[4], lr[4];
#pragma unroll
  for (int r = 0; r < 4; r++) { mr[r] = -1e30f; lr[r] = 0.f; }

  const int sbase = spl * 512;
  stage_K(sbase);
  stage_V(sbase);
  VMWAIT(8); BARRIER(); SFENCE();        // K(0) resident; V(0) 8 loads in flight

  for (int t = 0; t < 4; t++) {
    // ---- QK^T for s-tile t (already in log2 domain via pre-scaled Q) ----
    f32x4 sacc[8];
#pragma unroll
    for (int i = 0; i < 8; i++) { f32x4 z = {0.f, 0.f, 0.f, 0.f}; sacc[i] = z; }
    __builtin_amdgcn_s_setprio(1);
    mfma_regA(qf[0], qf[1], Ks[0], lane, sacc);
    mfma_regA(qf[2], qf[3], Ks[1], lane, sacc);
    __builtin_amdgcn_s_setprio(0);
    SFENCE();
    BARRIER();                           // all waves done reading Ks
    if (t < 3) stage_K(sbase + (t + 1) * 128);   // +8 in flight

    // ---- online softmax (base 2); P -> LDS (own wave's rows only) ----
    float tm[4];
#pragma unroll
    for (int r = 0; r < 4; r++) {
      float v = sacc[0][r];
#pragma unroll
      for (int nt = 1; nt < 8; nt++) v = fmaxf(v, sacc[nt][r]);
      tm[r] = v;
    }
#pragma unroll
    for (int off = 1; off < 16; off <<= 1)
#pragma unroll
      for (int r = 0; r < 4; r++) tm[r] = fmaxf(tm[r], __shfl_xor(tm[r], off));
    float alpha[4], rs[4];
#pragma unroll
    for (int r = 0; r < 4; r++) {
      float mn = fmaxf(mr[r], tm[r]);
      alpha[r] = exp2f(mr[r] - mn);
      mr[r] = mn;
      rs[r] = 0.f;
    }
#pragma unroll
    for (int nt = 0; nt < 8; nt++) {
      char* pc = (char*)Ps[nt >> 2];
      int colb = ((nt & 3) * 16 + colq) * 2;
#pragma unroll
      for (int r = 0; r < 4; r++) {
        int row = wrow + quad * 4 + r;
        float p = exp2f(sacc[nt][r] - mr[r]);
        rs[r] += p;
        *(__bf16*)(pc + row * 128 + (colb ^ ((row & 7) << 4))) = f2bf(p);
      }
    }
#pragma unroll
    for (int off = 1; off < 16; off <<= 1)
#pragma unroll
      for (int r = 0; r < 4; r++) rs[r] += __shfl_xor(rs[r], off);
#pragma unroll
    for (int r = 0; r < 4; r++) lr[r] = alpha[r] * lr[r] + rs[r];
#pragma unroll
    for (int nt = 0; nt < 8; nt++)
#pragma unroll
      for (int r = 0; r < 4; r++) oacc[nt][r] *= alpha[r];

    LGKMWAIT0();                         // P writes done
    if (t < 3) { VMWAIT(8); } else { VMWAIT(0); }   // V(t) resident (own loads)
    BARRIER(); SFENCE();                 // everyone's V(t) + P ready

    // ---- PV ----
    __builtin_amdgcn_s_setprio(1);
    mfma_block(Ps[0], Vs[0], lane, wrow, oacc);
    mfma_block(Ps[1], Vs[1], lane, wrow, oacc);
    __builtin_amdgcn_s_setprio(0);
    SFENCE();
    BARRIER();                           // all done reading Vs, Ps
    if (t < 3) {
      stage_V(sbase + (t + 1) * 128);    // +8 -> 16 in flight
      VMWAIT(8); BARRIER(); SFENCE();    // K(t+1) resident
    }
  }

  // epilogue: unnormalized partial O + (m,l) in log2 domain
  size_t base = (size_t)(b * 4 + spl) * NT + t0;
#pragma unroll
  for (int r = 0; r < 4; r++) {
    size_t row = base + wrow + quad * 4 + r;
#pragma unroll
    for (int nt = 0; nt < 8; nt++)
      opart[row * NH + nt * 16 + colq] = oacc[nt][r];
  }
  if (colq == 0) {
#pragma unroll
    for (int r = 0; r < 4; r++) {
      float2 v; v.x = mr[r]; v.y = lr[r];
      ml[base + wrow + quad * 4 + r] = v;
    }
  }
}

// ---------------- gather o: merge 4 split partials (base-2 LSE) -> slot-major bf16 ----------------
__global__ __launch_bounds__(256) void k_gather_o(const float* __restrict__ opart,
                                                  const float2* __restrict__ ml,
                                                  const int* __restrict__ slot_token,
                                                  const int* __restrict__ counts,
                                                  __bf16* __restrict__ og) {
  int slot = blockIdx.x * 2 + (threadIdx.x >> 7);
  int h = threadIdx.x & 127;
  int total = 0;
#pragma unroll
  for (int e = 0; e < NE; e++) total += counts[e];
  if (total > CAP) total = CAP;
  if (slot >= total) return;
  int n = slot_token[slot];
  int b = n >> 11, trow = n & 2047;
  size_t rb = (size_t)b * 4 * NT + trow;
  float2 m0 = ml[rb], m1 = ml[rb + NT], m2 = ml[rb + 2 * NT], m3 = ml[rb + 3 * NT];
  float M = fmaxf(fmaxf(m0.x, m1.x), fmaxf(m2.x, m3.x));
  float e0 = exp2f(m0.x - M), e1 = exp2f(m1.x - M), e2 = exp2f(m2.x - M), e3 = exp2f(m3.x - M);
  float den = m0.y * e0 + m1.y * e1 + m2.y * e2 + m3.y * e3;
  float num = opart[rb * NH + h] * e0 + opart[(rb + NT) * NH + h] * e1 +
              opart[(rb + 2 * NT) * NH + h] * e2 + opart[(rb + 3 * NT) * NH + h] * e3;
  og[(size_t)slot * NH + h] = f2bf(num / den);
}

// ------- grouped GEMM: out-proj, BM=128, 2 N-chunks/block (A staged once) -------
__global__ __launch_bounds__(256) void k_out2(
    const __bf16* __restrict__ og, const __bf16* __restrict__ pot,
    const int* __restrict__ counts, __bf16* __restrict__ zy) {
  int id = blockIdx.x;
  int w = (id & 7) * (4 * NT2_MAX / 8) + (id >> 3);  // chunked bijective (608)
  int ti = w >> 2, p = w & 3;                        // p = 256-wide nc chunk 0..3
  int e, s0, seg_end;
  if (!locate_tile(counts, ti, e, s0, seg_end)) return;
  int nc0 = p * 256;
  const __bf16* Bt = pot + (size_t)e * NC * NH;

  __shared__ __bf16 As[2][128 * 64];
  __shared__ __bf16 Bs[2][128 * 64];
  int tid = threadIdx.x, lane = tid & 63, wid = tid >> 6, wrow2 = wid * 32;
  const __bf16* asrc[4];
  const __bf16* bsrc[4];
#pragma unroll
  for (int i = 0; i < 4; i++) asrc[i] = swz_src(og + (size_t)s0 * NH, NH, tid, i);
#pragma unroll
  for (int i = 0; i < 4; i++) bsrc[i] = swz_src(Bt + (size_t)nc0 * NH, NH, tid, i);
  auto stageA = [&](int buf, int k0) {
#pragma unroll
    for (int i = 0; i < 4; i++)
      gl_lds16(asrc[i] + k0, (char*)As[buf] + tid * 16 + i * 4096);
  };
  auto stageB = [&](int buf, int k0, int noff) {
#pragma unroll
    for (int i = 0; i < 4; i++)
      gl_lds16(bsrc[i] + (size_t)noff * NH + k0, (char*)Bs[buf] + tid * 16 + i * 4096);
  };
  f32x4 acc[2][8];
  int col = lane & 15, quad = lane >> 4;
  auto store_acc = [&](int nco) {
#pragma unroll
    for (int rf = 0; rf < 2; rf++)
#pragma unroll
      for (int r = 0; r < 4; r++) {
        int s = s0 + wrow2 + rf * 16 + quad * 4 + r;
        if (s < seg_end) {
#pragma unroll
          for (int nt = 0; nt < 8; nt++)
            zy[(size_t)s * NC + nco + nt * 16 + col] = f2bf(acc[rf][nt][r]);
        }
      }
  };

#pragma unroll
  for (int rf = 0; rf < 2; rf++)
#pragma unroll
    for (int i = 0; i < 8; i++) { f32x4 z = {0.f, 0.f, 0.f, 0.f}; acc[rf][i] = z; }

  // A (full K=128) staged once; B re-staged per 128-wide n-chunk.
  stageA(0, 0); stageB(0, 0, 0);        // first 8: As[0] + Bs[0] (chunk 0)
  stageA(1, 64); stageB(1, 64, 0);
  VMWAIT(8); BARRIER(); SFENCE();
  __builtin_amdgcn_s_setprio(1);
  mfma_block128(As[0], Bs[0], lane, wrow2, acc);
  __builtin_amdgcn_s_setprio(0);
  SFENCE();
  VMWAIT(0); BARRIER(); SFENCE();
  __builtin_amdgcn_s_setprio(1);
  mfma_block128(As[1], Bs[1], lane, wrow2, acc);
  __builtin_amdgcn_s_setprio(0);
  SFENCE();
  store_acc(nc0);
  BARRIER();                            // all waves done reading Bs
  stageB(0, 0, 128); stageB(1, 64, 128);   // B for chunk 1; As untouched
#pragma unroll
  for (int rf = 0; rf < 2; rf++)
#pragma unroll
    for (int i = 0; i < 8; i++) { f32x4 z = {0.f, 0.f, 0.f, 0.f}; acc[rf][i] = z; }
  VMWAIT(0); BARRIER(); SFENCE();
  __builtin_amdgcn_s_setprio(1);
  mfma_block128(As[0], Bs[0], lane, wrow2, acc);
  mfma_block128(As[1], Bs[1], lane, wrow2, acc);
  __builtin_amdgcn_s_setprio(0);
  store_acc(nc0 + 128);
}

// ---------------- combine ZY slots -> dense fp32 out ----------------
__global__ __launch_bounds__(256) void k_combine_out(
    const __bf16* __restrict__ zy, const int* __restrict__ tok_slots,
    const int* __restrict__ tok_cnt, const float* __restrict__ slot_w,
    float* __restrict__ out) {
  int token = blockIdx.x;
  int c = threadIdx.x * 4;
  int cnt = tok_cnt[token];
  float a0 = 0.f, a1 = 0.f, a2 = 0.f, a3 = 0.f;
  for (int j = 0; j < cnt; j++) {
    int s = tok_slots[token * 16 + j];
    if (s < CAP) {
      float w = slot_w[s];
      bf16x4 z = *(const bf16x4*)&zy[(size_t)s * NC + c];
      a0 += w * (float)z[0];
      a1 += w * (float)z[1];
      a2 += w * (float)z[2];
      a3 += w * (float)z[3];
    }
  }
  float4 o = {a0, a1, a2, a3};
  *(float4*)&out[(size_t)token * NC + c] = o;
}

extern "C" void kernel_launch(void* const* d_in, const int* in_sizes, int n_in,
                              void* d_out, int out_size, void* d_ws, size_t ws_size,
                              hipStream_t stream) {
  const float* hs    = (const float*)d_in[0];  // [4,2048,1024]
  const float* sim   = (const float*)d_in[1];  // [1024,16]
  const float* gates = (const float*)d_in[2];  // [16]
  const float* qp    = (const float*)d_in[3];  // [16,1024,128]
  const float* kp    = (const float*)d_in[4];
  const float* vp    = (const float*)d_in[5];
  const float* op    = (const float*)d_in[6];  // [16,128,1024]
  float* out = (float*)d_out;
  char* ws = (char*)d_ws;

  // ---- workspace arena (aliased by lifetime) ----
  const size_t M = 1048576;
  __bf16* PQT = (__bf16*)(ws + 0 * M);         // 4 MiB each
  __bf16* PKT = (__bf16*)(ws + 4 * M);
  __bf16* PVT = (__bf16*)(ws + 8 * M);
  __bf16* POT = (__bf16*)(ws + 12 * M);
  __bf16* Qb  = (__bf16*)(ws + 16 * M);        // 2 MiB each, token-major bf16
  __bf16* Kb  = (__bf16*)(ws + 18 * M);
  __bf16* VT  = (__bf16*)(ws + 22 * M);        // 2 MiB [b][h][t]
  float*  WALL = (float*)(ws + 28 * M);        // 512 KiB
  int*    STOK = (int*)(ws + 28 * M + 524288); // 512 KiB
  float*  SW   = (float*)(ws + 28 * M + 1048576);
  int*    TSL  = (int*)(ws + 28 * M + 1572864);  // tok_slots 512 KiB
  int*    TCN  = (int*)(ws + 28 * M + 2097152);  // tok_cnt 32 KiB
  int* CNT = (int*)(ws + 28 * M + 2130432);    // control block (memset below)
  int* CUR = CNT + 40;
  // R region (32M..96M), aliased by lifetime:
  __bf16* XBF = (__bf16*)(ws + 32 * M);        // 16.8 MiB dense bf16 x (dies after qkv2)
  __bf16* YQ = (__bf16*)(ws + 72 * M);         // 4.5 MiB each (die before flash)
  __bf16* YK = (__bf16*)(ws + 77 * M);
  __bf16* YV = (__bf16*)(ws + 82 * M);
  float*  OP2 = (float*)(ws + 32 * M);         // 16.8 MiB partial O (after XBF dead)
  float2* MLB = (float2*)(ws + 50 * M);        // 256 KiB (m,l) per split-row
  __bf16* OG = (__bf16*)(ws + 52 * M);         // 4.5 MiB
  __bf16* ZY = (__bf16*)(ws + 60 * M);         // 36.1 MiB

  hipMemsetAsync(CNT, 0, 512, stream);

  k_gating3<<<NTOK / 16, 256, 0, stream>>>(hs, sim, gates, WALL, CNT, XBF);
  k_assign_tr<<<32 + 64 * 128, 256, 0, stream>>>(WALL, CNT, CUR, STOK, SW, TSL, TCN,
                                                 qp, kp, vp, op, PQT, PKT, PVT, POT);
  k_moe_qkv2<<<3 * NT2_MAX, 256, 0, stream>>>(XBF, STOK, PQT, PKT, PVT, CNT, YQ, YK, YV);
  k_combine_qkv<<<dim3(NTOK / 32, 3), 256, 0, stream>>>(YQ, YK, YV, TSL, TCN, SW, Qb, Kb, VT);
  k_flash<<<512, 256, 0, stream>>>(Qb, Kb, VT, OP2, MLB);
  k_gather_o<<<CAP / 2, 256, 0, stream>>>(OP2, MLB, STOK, CNT, OG);
  k_out2<<<4 * NT2_MAX, 256, 0, stream>>>(OG, POT, CNT, ZY);
  k_combine_out<<<NTOK, 256, 0, stream>>>(ZY, TSL, TCN, SW, out);
}